// Round 13
// baseline (140.530 us; speedup 1.0000x reference)
//
#include <hip/hip_runtime.h>

#define DEV __device__ __forceinline__

typedef unsigned short u16;
typedef unsigned int u32;
typedef __attribute__((ext_vector_type(4))) float f32x4;
typedef __attribute__((ext_vector_type(8))) short s16x8;
typedef __attribute__((ext_vector_type(8))) _Float16 f16x8;
typedef __attribute__((ext_vector_type(4))) unsigned short u16x4;
typedef __attribute__((ext_vector_type(4))) unsigned int u32x4;

#define BATCH 2
#define SEQ 2048
#define HID 1024
#define NH 16
#define HD 64

// scaling scheme:  X' = 64*X, W' = 64*W -> proj = acc/4096
//  q stored = proj_q * 8*log2e*4, k stored = proj_k * 16
//  scores_mfma = 64 * (s * log2e); softmax uses sc*1/64 (FMA-fused w/ mask)
#define SCALE_XW 64.0f
#define INV_PROJ (1.0f / 4096.0f)
#define SCALE_Q 46.16624130844683f
#define SCALE_K 16.0f
#define SC_TO_LOG2 0.015625f
#define DEFER_THR 10.0f

DEV f32x4 mfmah(s16x8 a, s16x8 b, f32x4 c) {
    return __builtin_amdgcn_mfma_f32_16x16x32_f16(
        __builtin_bit_cast(f16x8, a), __builtin_bit_cast(f16x8, b), c, 0, 0, 0);
}

DEV u16 f2h(float x) { return __builtin_bit_cast(u16, (_Float16)x); }
DEV float h2f(u16 h) { return (float)__builtin_bit_cast(_Float16, h); }

DEV u32 pkh(float a, float b) {
#if __has_builtin(__builtin_amdgcn_cvt_pkrtz)
    auto r = __builtin_amdgcn_cvt_pkrtz(a, b);
    return __builtin_bit_cast(u32, r);
#else
    return (u32)f2h(a) | ((u32)f2h(b) << 16);
#endif
}

DEV float fexp2(float x) {
#if __has_builtin(__builtin_amdgcn_exp2f)
    return __builtin_amdgcn_exp2f(x);
#else
    return exp2f(x);
#endif
}

DEV void swap32(int lane, u32 a, u32 b, u32& o0, u32& o1) {
#if __has_builtin(__builtin_amdgcn_permlane32_swap)
    auto r = __builtin_amdgcn_permlane32_swap((int)a, (int)b, false, false);
    o0 = (u32)r[0]; o1 = (u32)r[1];
#else
    u32 ax = (u32)__shfl_xor((int)a, 32);
    u32 bx = (u32)__shfl_xor((int)b, 32);
    bool hi = (lane & 32) != 0;
    o0 = hi ? bx : a;
    o1 = hi ? b : ax;
#endif
}
DEV void swap16(int lane, u32 a, u32 b, u32& o0, u32& o1) {
#if __has_builtin(__builtin_amdgcn_permlane16_swap)
    auto r = __builtin_amdgcn_permlane16_swap((int)a, (int)b, false, false);
    o0 = (u32)r[0]; o1 = (u32)r[1];
#else
    u32 ax = (u32)__shfl_xor((int)a, 16);
    u32 bx = (u32)__shfl_xor((int)b, 16);
    bool hi = (lane & 16) != 0;
    o0 = hi ? bx : a;
    o1 = hi ? b : ax;
#endif
}

DEV void gl_lds16(const void* g, void* l) {
    __builtin_amdgcn_global_load_lds(
        (__attribute__((address_space(1))) void*)(void*)g,
        (__attribute__((address_space(3))) void*)l, 16, 0, 0);
}

// rows of 128B, 16B slots XOR-swizzled by row&7
DEV s16x8 lds_ld16(const u16* base, int row, int kbyte) {
    return *(const s16x8*)((const char*)base + row * 128 + (kbyte ^ ((row & 7) << 4)));
}
// rows of 64B, 16B slots XOR-swizzled by row&3
DEV s16x8 lds_ld32r(const u16* base, int row, int g) {
    return *(const s16x8*)((const char*)base + row * 64 + ((g * 16) ^ ((row & 3) << 4)));
}

// ------- mask: sniff dtype, build key compaction (pack_idx/cnt) + packed bias -------
__global__ void detect_mask(const unsigned char* __restrict__ m, float* __restrict__ pbias,
                            int* __restrict__ pack_idx, int* __restrict__ cnt) {
    __shared__ int sb, sf;
    __shared__ int scan[256];
    int tid = threadIdx.x;
    if (tid == 0) { sb = 0; sf = 0; }
    __syncthreads();
    int lb = 0, lf = 0;
    for (int i = tid * 16; i < tid * 16 + 16; i++) {
        unsigned char v = m[i];
        int pos = i & 3;
        if (pos == 3 && v == 0x3f) lf = 1;
        if (pos != 0 && v != 0) lb = 1;
    }
    if (lb) atomicOr(&sb, 1);
    if (lf) atomicOr(&sf, 1);
    __syncthreads();
    int f = sf ? 2 : (sb ? 1 : 0);
#pragma unroll
    for (int b = 0; b < BATCH; b++) {
        int base = b * SEQ;
        int keep[8], lc = 0;
#pragma unroll
        for (int e = 0; e < 8; e++) {
            int i = base + tid * 8 + e;
            int mv;
            if (f == 0) mv = ((const int*)m)[i] != 0;
            else if (f == 1) mv = m[i] != 0;
            else mv = ((const float*)m)[i] != 0.0f;
            keep[e] = !mv;
            lc += keep[e];
        }
        scan[tid] = lc;
        __syncthreads();
        for (int s = 1; s < 256; s <<= 1) {
            int v = (tid >= s) ? scan[tid - s] : 0;
            __syncthreads();
            scan[tid] += v;
            __syncthreads();
        }
        int off = scan[tid] - lc;
        int total = scan[255];
        __syncthreads();  // scan reused next batch
#pragma unroll
        for (int e = 0; e < 8; e++)
            if (keep[e]) pack_idx[base + off++] = base + tid * 8 + e;
        if (tid == 0) cnt[b] = total;
        for (int j = tid; j < SEQ; j += 256)
            pbias[base + j] = (j < total) ? 0.0f : -1e30f;
    }
}

// ---------------- prep: scale+convert fp32 -> fp16 (single plane) ----------------
__global__ __launch_bounds__(256) void split_x(const float* __restrict__ in,
                                               u16* __restrict__ oh) {
    int i = (blockIdx.x * 256 + threadIdx.x) * 4;
    f32x4 v = *(const f32x4*)&in[i];
    u16x4 h;
#pragma unroll
    for (int e = 0; e < 4; e++) h[e] = f2h(v[e] * SCALE_XW);
    *(u16x4*)&oh[i] = h;
}

// in[K][N] fp32 -> out_hi(/lo)[N][K] fp16 (transposed, scaled)
__global__ __launch_bounds__(256) void transpose_split(const float* __restrict__ in,
                                                       u16* __restrict__ oh, u16* __restrict__ ol,
                                                       int K, int N, float scale, int wlo) {
    __shared__ float t[32][33];
    int tx = threadIdx.x, ty = threadIdx.y;
    int n0 = blockIdx.x * 32, k0 = blockIdx.y * 32;
#pragma unroll
    for (int i = 0; i < 4; i++)
        t[ty + 8 * i][tx] = in[(size_t)(k0 + ty + 8 * i) * N + n0 + tx];
    __syncthreads();
#pragma unroll
    for (int i = 0; i < 4; i++) {
        float v = t[tx][ty + 8 * i] * scale;
        size_t o = (size_t)(n0 + ty + 8 * i) * K + k0 + tx;
        u16 hi = f2h(v);
        oh[o] = hi;
        if (wlo) ol[o] = f2h(v - h2f(hi));
    }
}

// ------- GEMM1: Xh @ (Wh+Wl) fp16 2-pass, BK=32 DOUBLE-buffered 48KB -------
// R12: dbuf (R3-attn-proven 2-phase: STAGE(kt+1) at top -> full iter of latency),
// 3 blocks/CU (144KB LDS); XCD-chunked bid swizzle (each XCD: 4 m-rows x all n
// -> X-tiles L2-resident). K/V parts in PACKED key space (pack_idx/cnt).
__global__ __launch_bounds__(256, 3) void gemm_qkv(
    const u16* __restrict__ Xh,
    const u16* __restrict__ Wth, const u16* __restrict__ Wtl,
    const float* __restrict__ bqkv,
    const int* __restrict__ pack_idx, const int* __restrict__ cnt,
    u16* __restrict__ qh,
    u16* __restrict__ kh,
    u16* __restrict__ vt) {
    __shared__ __align__(16) u16 SM[2][3][128 * 32];  // 48 KB double buffer
    int tid = threadIdx.x, lane = tid & 63, w = tid >> 6;
    int g = lane >> 4, q15 = lane & 15;
    int wm = w >> 1, wn = w & 1;
    // XCD swizzle: 768 blocks, 768%8==0 -> bijective; each XCD gets 96 consecutive
    // swz = 4 m-rows x 24 n -> X working set 1MB, L2-resident.
    int flat = blockIdx.x;
    int swz = (flat & 7) * 96 + (flat >> 3);
    int m0 = (swz / 24) * 128, n0 = (swz % 24) * 128;
    int part = n0 >> 10;
    int bb = m0 >> 11;
    int cb = cnt[bb];
    if (part != 0 && (m0 & 2047) >= cb) return;  // packed rows all beyond count

    // fixed per-thread source-row map (2 rows/thread, constant across kt)
    int srcrow[2];
#pragma unroll
    for (int i = 0; i < 2; i++) {
        int r = m0 + ((i * 256 + tid) >> 2);
        srcrow[i] = (part == 0) ? r : (((r & 2047) < cb) ? pack_idx[r] : (bb << 11));
    }

    f32x4 acc[4][4];
#pragma unroll
    for (int i = 0; i < 4; i++)
#pragma unroll
        for (int j = 0; j < 4; j++) acc[i][j] = (f32x4){0.f, 0.f, 0.f, 0.f};

    auto STAGE = [&](int db, int kt) {
        int k0 = kt * 32;
#pragma unroll
        for (int i = 0; i < 2; i++) {
            int c = i * 256 + tid;
            int row = c >> 2, slot = c & 3;
            int sg = slot ^ (row & 3);
            int dst = (c & ~63) * 8;
            size_t ga = (size_t)srcrow[i] * 1024 + k0 + sg * 8;
            size_t gb = (size_t)(n0 + row) * 1024 + k0 + sg * 8;
            gl_lds16(&Xh[ga], &SM[db][0][dst]);
            gl_lds16(&Wth[gb], &SM[db][1][dst]);
            gl_lds16(&Wtl[gb], &SM[db][2][dst]);
        }
    };

    STAGE(0, 0);
    __syncthreads();  // implicit vmcnt(0): buf0 ready
    for (int kt = 0; kt < 32; kt++) {
        int cur = kt & 1;
        if (kt < 31) STAGE(cur ^ 1, kt + 1);  // flies under compute + barrier
        s16x8 a_h[4], b_h[4], b_l[4];
#pragma unroll
        for (int i = 0; i < 4; i++) {
            a_h[i] = lds_ld32r(SM[cur][0], wm * 64 + i * 16 + q15, g);
            b_h[i] = lds_ld32r(SM[cur][1], wn * 64 + i * 16 + q15, g);
            b_l[i] = lds_ld32r(SM[cur][2], wn * 64 + i * 16 + q15, g);
        }
#pragma unroll
        for (int mi = 0; mi < 4; mi++)
#pragma unroll
            for (int ni = 0; ni < 4; ni++) {
                acc[mi][ni] = mfmah(a_h[mi], b_h[ni], acc[mi][ni]);
                acc[mi][ni] = mfmah(a_h[mi], b_l[ni], acc[mi][ni]);
            }
        __syncthreads();  // drains next stage + retires this buf's reads
    }

    if (part == 2) {
        u16* T = (u16*)SM;
        const int TP = 140;  // pad: read-phase starting banks spread (2-way = free)
        // two 64-column half-passes; rows are PACKED s (tail garbage masked in attn)
#pragma unroll
        for (int h2 = 0; h2 < 2; h2++) {
            __syncthreads();
            if (wn == h2) {
#pragma unroll
                for (int mi = 0; mi < 4; mi++)
#pragma unroll
                    for (int ni = 0; ni < 4; ni++) {
                        int lcol = ni * 16 + q15;  // 0..63 within half
#pragma unroll
                        for (int j = 0; j < 4; j++) {
                            int lrow = wm * 64 + mi * 16 + g * 4 + j;
                            T[lcol * TP + lrow] =
                                f2h(acc[mi][ni][j] * INV_PROJ + bqkv[n0 + h2 * 64 + lcol]);
                        }
                    }
            }
            __syncthreads();
            int lcol = tid >> 2;  // 0..63
            int seg = tid & 3;
            int c = n0 - 2048 + h2 * 64 + lcol;
            int h = c >> 6, d = c & 63;
            int b = m0 >> 11, sbase = m0 & 2047;
            size_t rowbase = ((size_t)(b * NH + h) * HD + d) * SEQ + sbase;
#pragma unroll
            for (int k = 0; k < 2; k++) {
                int slot = seg * 2 + k;  // 8 slots x 16 rows = 128
                *(s16x8*)&vt[rowbase + slot * 16 + 0] = *(const s16x8*)&T[lcol * TP + slot * 16 + 0];
                *(s16x8*)&vt[rowbase + slot * 16 + 8] = *(const s16x8*)&T[lcol * TP + slot * 16 + 8];
            }
        }
    } else {
#pragma unroll
        for (int mi = 0; mi < 4; mi++)
#pragma unroll
            for (int ni = 0; ni < 4; ni++) {
                int col = n0 + wn * 64 + ni * 16 + q15;
                float bias = bqkv[col];
                int cc = col & 1023, h = cc >> 6, d = cc & 63;
#pragma unroll
                for (int j = 0; j < 4; j++) {
                    int row = m0 + wm * 64 + mi * 16 + g * 4 + j;
                    int b = row >> 11, s = row & 2047;  // s: packed for K, true for Q
                    float v = acc[mi][ni][j] * INV_PROJ + bias;
                    v *= (part == 0) ? SCALE_Q : SCALE_K;
                    size_t o = (size_t)(b * NH + h) * SEQ * HD + (size_t)s * HD + d;
                    if (part == 0) qh[o] = f2h(v);
                    else kh[o] = f2h(v);
                }
            }
    }
}

// ------ flash attention over PACKED keys: NT = ceil(cnt[b]/64) tiles ------
// 64-row q-tiles, 4 blocks/CU, 2-phase dbuf (R3-proven schedule).
__global__ __launch_bounds__(256, 4) void attn_kernel(
    const u16* __restrict__ qh,
    const u16* __restrict__ kh,
    const u16* __restrict__ vt, const float* __restrict__ pbias,
    const int* __restrict__ cnt,
    u16* __restrict__ att) {
    __shared__ __align__(16) u16 Kh[2][4096], Vt[2][4096];  // 32 KB
    __shared__ __align__(16) float MskB[2][64];
    int tid = threadIdx.x, lane = tid & 63, w = tid >> 6;
    int g = lane >> 4, q15 = lane & 15;
    int bid = blockIdx.y * 32 + blockIdx.x;
    int swz = (bid & 7) * 128 + (bid >> 3);  // bijective: 1024 % 8 == 0
    int qt = swz & 31, bh = swz >> 5;        // 4 bh per XCD -> L2-resident K/V
    int b = bh >> 4, h = bh & 15;
    int q0 = qt * 64;
    int NT = (cnt[b] + 63) >> 6;  // packed key tiles
    size_t base = (size_t)bh * SEQ * HD;
    const u16* vbase = vt + (size_t)bh * HD * SEQ;
    const float* mrow = pbias + b * SEQ;

    // Q fragments, 16 rows per wave (k-map: k = k2*32 + g*8 + e)
    s16x8 aq[2];
#pragma unroll
    for (int k2 = 0; k2 < 2; k2++) {
        size_t o = base + (size_t)(q0 + w * 16 + q15) * HD + k2 * 32 + g * 8;
        aq[k2] = *(const s16x8*)&qh[o];
    }

    float m_ = -1e30f, l_ = 0.f;  // l_ lane-partial
    f32x4 o_[4];
#pragma unroll
    for (int df = 0; df < 4; df++) o_[df] = (f32x4){0.f, 0.f, 0.f, 0.f};

    auto STAGE = [&](int buf, int k0) {
#pragma unroll
        for (int i = 0; i < 2; i++) {
            int c = i * 256 + tid;
            int row = c >> 3, slot = c & 7;
            int sg = slot ^ (row & 7);
            int dst = (c & ~63) * 8;
            size_t gK = base + (size_t)(k0 + row) * HD + sg * 8;
            gl_lds16(&kh[gK], &Kh[buf][dst]);
            size_t gV = (size_t)row * SEQ + k0 + sg * 8;
            gl_lds16(&vbase[gV], &Vt[buf][dst]);
        }
        if (tid < 16) gl_lds16(&mrow[k0 + tid * 4], &MskB[buf][0]);
    };

    STAGE(0, 0);
    __syncthreads();

    for (int kt = 0; kt < NT; kt++) {
        int cur = kt & 1;
        if (kt < NT - 1) STAGE(cur ^ 1, (kt + 1) * 64);

        // swapped QK^T: D[k][q], k = nf*16 + g*4 + j, q = q15
        f32x4 sc[4];
#pragma unroll
        for (int nf = 0; nf < 4; nf++) sc[nf] = (f32x4){0.f, 0.f, 0.f, 0.f};
#pragma unroll
        for (int nf = 0; nf < 4; nf++) {
#pragma unroll
            for (int k2 = 0; k2 < 2; k2++) {
                int kb = k2 * 64 + g * 16;
                s16x8 kbh = lds_ld16(Kh[cur], nf * 16 + q15, kb);
                sc[nf] = mfmah(kbh, aq[k2], sc[nf]);
            }
            f32x4 mb = *(const f32x4*)&MskB[cur][nf * 16 + g * 4];
            sc[nf] = sc[nf] * SC_TO_LOG2 + mb;
        }

        // per-lane softmax (row q = q15) with defer-max
        float pml = -1e30f;
#pragma unroll
        for (int nf = 0; nf < 4; nf++)
#pragma unroll
            for (int j = 0; j < 4; j++) pml = fmaxf(pml, sc[nf][j]);
        if (!__all(pml - m_ <= DEFER_THR)) {
            float pm = fmaxf(pml, __shfl_xor(pml, 16));
            pm = fmaxf(pm, __shfl_xor(pm, 32));
            float mn = fmaxf(m_, pm);
            float scl = fexp2(m_ - mn);
            m_ = mn;
            l_ *= scl;
#pragma unroll
            for (int j = 0; j < 4; j++) {
                float sb = __shfl(scl, g * 4 + j);
#pragma unroll
                for (int df = 0; df < 4; df++) o_[df][j] *= sb;
            }
        }
        float p[4][4];
        float rs = 0.f;
#pragma unroll
        for (int nf = 0; nf < 4; nf++)
#pragma unroll
            for (int j = 0; j < 4; j++) {
                float pv = fexp2(sc[nf][j] - m_);
                p[nf][j] = pv;
                rs += pv;
            }
        l_ += rs;  // lane-partial
        // in-register P repack: pa[k2] elem e = P[q15][k2*32 + g*8 + e]
        s16x8 pa[2];
#pragma unroll
        for (int k2 = 0; k2 < 2; k2++) {
            u32 A0 = pkh(p[2 * k2][0], p[2 * k2][1]);
            u32 A1 = pkh(p[2 * k2][2], p[2 * k2][3]);
            u32 B0 = pkh(p[2 * k2 + 1][0], p[2 * k2 + 1][1]);
            u32 B1 = pkh(p[2 * k2 + 1][2], p[2 * k2 + 1][3]);
            u32 s0, s1, t0, t1, w0, w1, w2, w3;
            swap32(lane, A0, B0, s0, s1);
            swap16(lane, s0, s1, w0, w2);
            swap32(lane, A1, B1, t0, t1);
            swap16(lane, t0, t1, w1, w3);
            u32x4 words = {w0, w1, w2, w3};
            pa[k2] = __builtin_bit_cast(s16x8, words);
        }

        // PV: O[q][d] += P[q][k] * V^T[d][k]
#pragma unroll
        for (int k2 = 0; k2 < 2; k2++) {
            int kb = k2 * 64 + g * 16;
#pragma unroll
            for (int df = 0; df < 4; df++) {
                s16x8 vb = lds_ld16(Vt[cur], df * 16 + q15, kb);
                o_[df] = mfmah(pa[k2], vb, o_[df]);
            }
        }
        __syncthreads();
    }

    float lt = l_;
    lt += __shfl_xor(lt, 16);
    lt += __shfl_xor(lt, 32);
#pragma unroll
    for (int j = 0; j < 4; j++) {
        float lb = __shfl(lt, g * 4 + j);
        float linv = __builtin_amdgcn_rcpf(lb);
        int qrow = q0 + w * 16 + g * 4 + j;
        size_t srow = (size_t)(b * SEQ + qrow);
#pragma unroll
        for (int df = 0; df < 4; df++) {
            int col = h * HD + df * 16 + q15;
            att[srow * HID + col] = f2h(o_[df][j] * linv);
        }
    }
}

// ---------------- GEMM2: att fp16 @ Wo fp16 (1 pass), 64x128 tiles, BK=32 dbuf -----
__global__ __launch_bounds__(256, 4) void gemm_out(
    const u16* __restrict__ A, const u16* __restrict__ Bh0,
    const float* __restrict__ bo, float* __restrict__ out) {
    __shared__ __align__(16) u16 SMa[2][64 * 32], SMb[2][128 * 32];  // 24 KB
    int tid = threadIdx.x, lane = tid & 63, w = tid >> 6;
    int g = lane >> 4, q15 = lane & 15;
    int wm = w >> 1, wn = w & 1;
    int m0 = blockIdx.y * 64, n0 = blockIdx.x * 128;
    f32x4 acc[2][4];
#pragma unroll
    for (int i = 0; i < 2; i++)
#pragma unroll
        for (int j = 0; j < 4; j++) acc[i][j] = (f32x4){0.f, 0.f, 0.f, 0.f};

    auto STAGE = [&](int db, int kt) {
        int k0 = kt * 32;
        {
            int c = tid;
            int row = c >> 2, slot = c & 3;
            int sg = slot ^ (row & 3);
            int dst = (c & ~63) * 8;
            gl_lds16(&A[(size_t)(m0 + row) * 1024 + k0 + sg * 8], &SMa[db][dst]);
        }
#pragma unroll
        for (int i = 0; i < 2; i++) {
            int c = i * 256 + tid;
            int row = c >> 2, slot = c & 3;
            int sg = slot ^ (row & 3);
            int dst = (c & ~63) * 8;
            gl_lds16(&Bh0[(size_t)(n0 + row) * 1024 + k0 + sg * 8], &SMb[db][dst]);
        }
    };

    STAGE(0, 0);
    for (int kt = 0; kt < 32; kt++) {
        int cur = kt & 1;
        __syncthreads();
        if (kt < 31) STAGE(cur ^ 1, kt + 1);
        s16x8 a_[2], b_[4];
#pragma unroll
        for (int i = 0; i < 2; i++)
            a_[i] = lds_ld32r(SMa[cur], wm * 32 + i * 16 + q15, g);
#pragma unroll
        for (int i = 0; i < 4; i++)
            b_[i] = lds_ld32r(SMb[cur], wn * 64 + i * 16 + q15, g);
#pragma unroll
        for (int mi = 0; mi < 2; mi++)
#pragma unroll
            for (int ni = 0; ni < 4; ni++)
                acc[mi][ni] = mfmah(a_[mi], b_[ni], acc[mi][ni]);
    }
#pragma unroll
    for (int mi = 0; mi < 2; mi++)
#pragma unroll
        for (int ni = 0; ni < 4; ni++) {
            int col = n0 + wn * 64 + ni * 16 + q15;
            float bias = bo[col];
#pragma unroll
            for (int j = 0; j < 4; j++) {
                int row = m0 + wm * 32 + mi * 16 + g * 4 + j;
                out[(size_t)row * 1024 + col] = acc[mi][ni][j] + bias;
            }
        }
}

extern "C" void kernel_launch(void* const* d_in, const int* in_sizes, int n_in,
                              void* d_out, int out_size, void* d_ws, size_t ws_size,
                              hipStream_t stream) {
    const float* qkv = (const float*)d_in[0];
    const void* mask = d_in[1];
    const float* Wqkv = (const float*)d_in[2];
    const float* bqkv = (const float*)d_in[3];
    const float* Wo = (const float*)d_in[4];
    const float* bo = (const float*)d_in[5];
    float* out = (float*)d_out;

    const size_t SZ_X = (size_t)4096 * 1024 * 2;       // 8 MB
    const size_t SZ_W = (size_t)3072 * 1024 * 2;       // 6 MB
    const size_t SZ_WO = (size_t)1024 * 1024 * 2;      // 2 MB
    const size_t SZ_QKV = (size_t)32 * 2048 * 64 * 2;  // 8 MB
    const size_t SZ_ATT = (size_t)4096 * 1024 * 2;     // 8 MB

    char* p = (char*)d_ws;
    u16* Xh = (u16*)p; p += SZ_X;
    u16* Wth = (u16*)p; p += SZ_W;
    u16* Wtl = (u16*)p; p += SZ_W;
    u16* Woth = (u16*)p; p += SZ_WO;
    u16* qh = (u16*)p; p += SZ_QKV;
    u16* kh = (u16*)p; p += SZ_QKV;
    u16* vt = (u16*)p; p += SZ_QKV;  // [bh][d][s_packed]
    u16* att = (u16*)p; p += SZ_ATT;
    float* pbias = (float*)p; p += BATCH * SEQ * 4;
    int* pack_idx = (int*)p; p += BATCH * SEQ * 4;
    int* cnt = (int*)p; p += 256;

    detect_mask<<<1, 256, 0, stream>>>((const unsigned char*)mask, pbias, pack_idx, cnt);
    split_x<<<4096, 256, 0, stream>>>(qkv, Xh);
    transpose_split<<<dim3(96, 32), dim3(32, 8), 0, stream>>>(Wqkv, Wth, Wtl, 1024, 3072,
                                                              SCALE_XW, 1);
    transpose_split<<<dim3(32, 32), dim3(32, 8), 0, stream>>>(Wo, Woth, nullptr, 1024, 1024,
                                                              1.0f, 0);
    gemm_qkv<<<768, 256, 0, stream>>>(Xh, Wth, Wtl, bqkv, pack_idx, cnt, qh, kh, vt);
    attn_kernel<<<dim3(32, 32), 256, 0, stream>>>(qh, kh, vt, pbias, cnt, att);
    gemm_out<<<dim3(8, 64), 256, 0, stream>>>(att, Woth, bo, out);
}

// Round 14
// 133.315 us; speedup vs baseline: 1.0541x; 1.0541x over previous
//
#include <hip/hip_runtime.h>

#define DEV __device__ __forceinline__

typedef unsigned short u16;
typedef unsigned int u32;
typedef __attribute__((ext_vector_type(4))) float f32x4;
typedef __attribute__((ext_vector_type(8))) short s16x8;
typedef __attribute__((ext_vector_type(8))) _Float16 f16x8;
typedef __attribute__((ext_vector_type(4))) unsigned short u16x4;
typedef __attribute__((ext_vector_type(4))) unsigned int u32x4;

#define BATCH 2
#define SEQ 2048
#define HID 1024
#define NH 16
#define HD 64

// scaling scheme:  X' = 64*X, W' = 64*W -> proj = acc/4096
//  q stored = proj_q * 8*log2e*4, k stored = proj_k * 16
//  scores_mfma = 64 * (s * log2e); softmax uses sc*1/64 (FMA-fused w/ mask)
#define SCALE_XW 64.0f
#define INV_PROJ (1.0f / 4096.0f)
#define SCALE_Q 46.16624130844683f
#define SCALE_K 16.0f
#define SC_TO_LOG2 0.015625f
#define DEFER_THR 10.0f

DEV f32x4 mfmah(s16x8 a, s16x8 b, f32x4 c) {
    return __builtin_amdgcn_mfma_f32_16x16x32_f16(
        __builtin_bit_cast(f16x8, a), __builtin_bit_cast(f16x8, b), c, 0, 0, 0);
}

DEV u16 f2h(float x) { return __builtin_bit_cast(u16, (_Float16)x); }
DEV float h2f(u16 h) { return (float)__builtin_bit_cast(_Float16, h); }

DEV u32 pkh(float a, float b) {
#if __has_builtin(__builtin_amdgcn_cvt_pkrtz)
    auto r = __builtin_amdgcn_cvt_pkrtz(a, b);
    return __builtin_bit_cast(u32, r);
#else
    return (u32)f2h(a) | ((u32)f2h(b) << 16);
#endif
}

DEV float fexp2(float x) {
#if __has_builtin(__builtin_amdgcn_exp2f)
    return __builtin_amdgcn_exp2f(x);
#else
    return exp2f(x);
#endif
}

DEV void swap32(int lane, u32 a, u32 b, u32& o0, u32& o1) {
#if __has_builtin(__builtin_amdgcn_permlane32_swap)
    auto r = __builtin_amdgcn_permlane32_swap((int)a, (int)b, false, false);
    o0 = (u32)r[0]; o1 = (u32)r[1];
#else
    u32 ax = (u32)__shfl_xor((int)a, 32);
    u32 bx = (u32)__shfl_xor((int)b, 32);
    bool hi = (lane & 32) != 0;
    o0 = hi ? bx : a;
    o1 = hi ? b : ax;
#endif
}
DEV void swap16(int lane, u32 a, u32 b, u32& o0, u32& o1) {
#if __has_builtin(__builtin_amdgcn_permlane16_swap)
    auto r = __builtin_amdgcn_permlane16_swap((int)a, (int)b, false, false);
    o0 = (u32)r[0]; o1 = (u32)r[1];
#else
    u32 ax = (u32)__shfl_xor((int)a, 16);
    u32 bx = (u32)__shfl_xor((int)b, 16);
    bool hi = (lane & 16) != 0;
    o0 = hi ? bx : a;
    o1 = hi ? b : ax;
#endif
}

DEV void gl_lds16(const void* g, void* l) {
    __builtin_amdgcn_global_load_lds(
        (__attribute__((address_space(1))) void*)(void*)g,
        (__attribute__((address_space(3))) void*)l, 16, 0, 0);
}

// rows of 128B, 16B slots XOR-swizzled by row&7
DEV s16x8 lds_ld16(const u16* base, int row, int kbyte) {
    return *(const s16x8*)((const char*)base + row * 128 + (kbyte ^ ((row & 7) << 4)));
}
// rows of 64B, 16B slots XOR-swizzled by row&3
DEV s16x8 lds_ld32r(const u16* base, int row, int g) {
    return *(const s16x8*)((const char*)base + row * 64 + ((g * 16) ^ ((row & 3) << 4)));
}

// ------- mask: sniff dtype, build key compaction (pack_idx/cnt) + packed bias -------
__global__ void detect_mask(const unsigned char* __restrict__ m, float* __restrict__ pbias,
                            int* __restrict__ pack_idx, int* __restrict__ cnt) {
    __shared__ int sb, sf;
    __shared__ int scan[256];
    int tid = threadIdx.x;
    if (tid == 0) { sb = 0; sf = 0; }
    __syncthreads();
    int lb = 0, lf = 0;
    for (int i = tid * 16; i < tid * 16 + 16; i++) {
        unsigned char v = m[i];
        int pos = i & 3;
        if (pos == 3 && v == 0x3f) lf = 1;
        if (pos != 0 && v != 0) lb = 1;
    }
    if (lb) atomicOr(&sb, 1);
    if (lf) atomicOr(&sf, 1);
    __syncthreads();
    int f = sf ? 2 : (sb ? 1 : 0);
#pragma unroll
    for (int b = 0; b < BATCH; b++) {
        int base = b * SEQ;
        int keep[8], lc = 0;
#pragma unroll
        for (int e = 0; e < 8; e++) {
            int i = base + tid * 8 + e;
            int mv;
            if (f == 0) mv = ((const int*)m)[i] != 0;
            else if (f == 1) mv = m[i] != 0;
            else mv = ((const float*)m)[i] != 0.0f;
            keep[e] = !mv;
            lc += keep[e];
        }
        scan[tid] = lc;
        __syncthreads();
        for (int s = 1; s < 256; s <<= 1) {
            int v = (tid >= s) ? scan[tid - s] : 0;
            __syncthreads();
            scan[tid] += v;
            __syncthreads();
        }
        int off = scan[tid] - lc;
        int total = scan[255];
        __syncthreads();  // scan reused next batch
#pragma unroll
        for (int e = 0; e < 8; e++)
            if (keep[e]) pack_idx[base + off++] = base + tid * 8 + e;
        if (tid == 0) cnt[b] = total;
        for (int j = tid; j < SEQ; j += 256)
            pbias[base + j] = (j < total) ? 0.0f : -1e30f;
    }
}

// ---------------- prep: scale+convert fp32 -> fp16 (single plane) ----------------
__global__ __launch_bounds__(256) void split_x(const float* __restrict__ in,
                                               u16* __restrict__ oh) {
    int i = (blockIdx.x * 256 + threadIdx.x) * 4;
    f32x4 v = *(const f32x4*)&in[i];
    u16x4 h;
#pragma unroll
    for (int e = 0; e < 4; e++) h[e] = f2h(v[e] * SCALE_XW);
    *(u16x4*)&oh[i] = h;
}

// in[K][N] fp32 -> out_hi(/lo)[N][K] fp16 (transposed, scaled)
__global__ __launch_bounds__(256) void transpose_split(const float* __restrict__ in,
                                                       u16* __restrict__ oh, u16* __restrict__ ol,
                                                       int K, int N, float scale, int wlo) {
    __shared__ float t[32][33];
    int tx = threadIdx.x, ty = threadIdx.y;
    int n0 = blockIdx.x * 32, k0 = blockIdx.y * 32;
#pragma unroll
    for (int i = 0; i < 4; i++)
        t[ty + 8 * i][tx] = in[(size_t)(k0 + ty + 8 * i) * N + n0 + tx];
    __syncthreads();
#pragma unroll
    for (int i = 0; i < 4; i++) {
        float v = t[tx][ty + 8 * i] * scale;
        size_t o = (size_t)(n0 + ty + 8 * i) * K + k0 + tx;
        u16 hi = f2h(v);
        oh[o] = hi;
        if (wlo) ol[o] = f2h(v - h2f(hi));
    }
}

// ------- GEMM1: Xh @ (Wh+Wl) fp16 2-pass, BK=32, DOUBLE-buffered 48KB -------
// R13: R11's grid/dispatch (dim3(24,32), default order — W L2-locality proven,
// 39MB FETCH) + dbuf as the ONLY change (gemm_out-proven top-barrier pattern).
// K/V parts in PACKED key space (pack_idx/cnt).
__global__ __launch_bounds__(256, 3) void gemm_qkv(
    const u16* __restrict__ Xh,
    const u16* __restrict__ Wth, const u16* __restrict__ Wtl,
    const float* __restrict__ bqkv,
    const int* __restrict__ pack_idx, const int* __restrict__ cnt,
    u16* __restrict__ qh,
    u16* __restrict__ kh,
    u16* __restrict__ vt) {
    __shared__ __align__(16) u16 SM[2][3][128 * 32];  // 48 KB double buffer
    int tid = threadIdx.x, lane = tid & 63, w = tid >> 6;
    int g = lane >> 4, q15 = lane & 15;
    int wm = w >> 1, wn = w & 1;
    int m0 = blockIdx.y * 128, n0 = blockIdx.x * 128;
    int part = n0 >> 10;
    int bb = m0 >> 11;
    int cb = cnt[bb];
    if (part != 0 && (m0 & 2047) >= cb) return;  // packed rows all beyond count

    // fixed per-thread source-row map (2 rows/thread, constant across kt)
    int srcrow[2];
#pragma unroll
    for (int i = 0; i < 2; i++) {
        int r = m0 + ((i * 256 + tid) >> 2);
        srcrow[i] = (part == 0) ? r : (((r & 2047) < cb) ? pack_idx[r] : (bb << 11));
    }

    f32x4 acc[4][4];
#pragma unroll
    for (int i = 0; i < 4; i++)
#pragma unroll
        for (int j = 0; j < 4; j++) acc[i][j] = (f32x4){0.f, 0.f, 0.f, 0.f};

    auto STAGE = [&](int db, int kt) {
        int k0 = kt * 32;
#pragma unroll
        for (int i = 0; i < 2; i++) {
            int c = i * 256 + tid;
            int row = c >> 2, slot = c & 3;
            int sg = slot ^ (row & 3);
            int dst = (c & ~63) * 8;
            size_t ga = (size_t)srcrow[i] * 1024 + k0 + sg * 8;
            size_t gb = (size_t)(n0 + row) * 1024 + k0 + sg * 8;
            gl_lds16(&Xh[ga], &SM[db][0][dst]);
            gl_lds16(&Wth[gb], &SM[db][1][dst]);
            gl_lds16(&Wtl[gb], &SM[db][2][dst]);
        }
    };

    STAGE(0, 0);
    for (int kt = 0; kt < 32; kt++) {
        int cur = kt & 1;
        __syncthreads();  // drains stage(kt) (vmcnt0+lgkm0), retires prior reads
        if (kt < 31) STAGE(cur ^ 1, kt + 1);  // flies under reads+MFMA+next barrier
        s16x8 a_h[4], b_h[4], b_l[4];
#pragma unroll
        for (int i = 0; i < 4; i++) {
            a_h[i] = lds_ld32r(SM[cur][0], wm * 64 + i * 16 + q15, g);
            b_h[i] = lds_ld32r(SM[cur][1], wn * 64 + i * 16 + q15, g);
            b_l[i] = lds_ld32r(SM[cur][2], wn * 64 + i * 16 + q15, g);
        }
#pragma unroll
        for (int mi = 0; mi < 4; mi++)
#pragma unroll
            for (int ni = 0; ni < 4; ni++) {
                acc[mi][ni] = mfmah(a_h[mi], b_h[ni], acc[mi][ni]);
                acc[mi][ni] = mfmah(a_h[mi], b_l[ni], acc[mi][ni]);
            }
    }

    if (part == 2) {
        u16* T = (u16*)SM;
        const int TP = 140;
        // two 64-column half-passes; rows are PACKED s (tail garbage masked in attn)
#pragma unroll
        for (int h2 = 0; h2 < 2; h2++) {
            __syncthreads();  // first iter: covers kt=31 LDS reads before T reuse
            if (wn == h2) {
#pragma unroll
                for (int mi = 0; mi < 4; mi++)
#pragma unroll
                    for (int ni = 0; ni < 4; ni++) {
                        int lcol = ni * 16 + q15;  // 0..63 within half
#pragma unroll
                        for (int j = 0; j < 4; j++) {
                            int lrow = wm * 64 + mi * 16 + g * 4 + j;
                            T[lcol * TP + lrow] =
                                f2h(acc[mi][ni][j] * INV_PROJ + bqkv[n0 + h2 * 64 + lcol]);
                        }
                    }
            }
            __syncthreads();
            int lcol = tid >> 2;  // 0..63
            int seg = tid & 3;
            int c = n0 - 2048 + h2 * 64 + lcol;
            int h = c >> 6, d = c & 63;
            int b = m0 >> 11, sbase = m0 & 2047;
            size_t rowbase = ((size_t)(b * NH + h) * HD + d) * SEQ + sbase;
#pragma unroll
            for (int k = 0; k < 2; k++) {
                int slot = seg * 2 + k;  // 8 slots x 16 rows = 128
                *(s16x8*)&vt[rowbase + slot * 16 + 0] = *(const s16x8*)&T[lcol * TP + slot * 16 + 0];
                *(s16x8*)&vt[rowbase + slot * 16 + 8] = *(const s16x8*)&T[lcol * TP + slot * 16 + 8];
            }
        }
    } else {
#pragma unroll
        for (int mi = 0; mi < 4; mi++)
#pragma unroll
            for (int ni = 0; ni < 4; ni++) {
                int col = n0 + wn * 64 + ni * 16 + q15;
                float bias = bqkv[col];
                int cc = col & 1023, h = cc >> 6, d = cc & 63;
#pragma unroll
                for (int j = 0; j < 4; j++) {
                    int row = m0 + wm * 64 + mi * 16 + g * 4 + j;
                    int b = row >> 11, s = row & 2047;  // s: packed for K, true for Q
                    float v = acc[mi][ni][j] * INV_PROJ + bias;
                    v *= (part == 0) ? SCALE_Q : SCALE_K;
                    size_t o = (size_t)(b * NH + h) * SEQ * HD + (size_t)s * HD + d;
                    if (part == 0) qh[o] = f2h(v);
                    else kh[o] = f2h(v);
                }
            }
    }
}

// ------ flash attention over PACKED keys: NT = ceil(cnt[b]/64) tiles ------
// 64-row q-tiles, 4 blocks/CU, 2-phase dbuf (R3-proven schedule).
__global__ __launch_bounds__(256, 4) void attn_kernel(
    const u16* __restrict__ qh,
    const u16* __restrict__ kh,
    const u16* __restrict__ vt, const float* __restrict__ pbias,
    const int* __restrict__ cnt,
    u16* __restrict__ att) {
    __shared__ __align__(16) u16 Kh[2][4096], Vt[2][4096];  // 32 KB
    __shared__ __align__(16) float MskB[2][64];
    int tid = threadIdx.x, lane = tid & 63, w = tid >> 6;
    int g = lane >> 4, q15 = lane & 15;
    int bid = blockIdx.y * 32 + blockIdx.x;
    int swz = (bid & 7) * 128 + (bid >> 3);  // bijective: 1024 % 8 == 0
    int qt = swz & 31, bh = swz >> 5;        // 4 bh per XCD -> L2-resident K/V
    int b = bh >> 4, h = bh & 15;
    int q0 = qt * 64;
    int NT = (cnt[b] + 63) >> 6;  // packed key tiles
    size_t base = (size_t)bh * SEQ * HD;
    const u16* vbase = vt + (size_t)bh * HD * SEQ;
    const float* mrow = pbias + b * SEQ;

    // Q fragments, 16 rows per wave (k-map: k = k2*32 + g*8 + e)
    s16x8 aq[2];
#pragma unroll
    for (int k2 = 0; k2 < 2; k2++) {
        size_t o = base + (size_t)(q0 + w * 16 + q15) * HD + k2 * 32 + g * 8;
        aq[k2] = *(const s16x8*)&qh[o];
    }

    float m_ = -1e30f, l_ = 0.f;  // l_ lane-partial
    f32x4 o_[4];
#pragma unroll
    for (int df = 0; df < 4; df++) o_[df] = (f32x4){0.f, 0.f, 0.f, 0.f};

    auto STAGE = [&](int buf, int k0) {
#pragma unroll
        for (int i = 0; i < 2; i++) {
            int c = i * 256 + tid;
            int row = c >> 3, slot = c & 7;
            int sg = slot ^ (row & 7);
            int dst = (c & ~63) * 8;
            size_t gK = base + (size_t)(k0 + row) * HD + sg * 8;
            gl_lds16(&kh[gK], &Kh[buf][dst]);
            size_t gV = (size_t)row * SEQ + k0 + sg * 8;
            gl_lds16(&vbase[gV], &Vt[buf][dst]);
        }
        if (tid < 16) gl_lds16(&mrow[k0 + tid * 4], &MskB[buf][0]);
    };

    STAGE(0, 0);
    __syncthreads();

    for (int kt = 0; kt < NT; kt++) {
        int cur = kt & 1;
        if (kt < NT - 1) STAGE(cur ^ 1, (kt + 1) * 64);

        // swapped QK^T: D[k][q], k = nf*16 + g*4 + j, q = q15
        f32x4 sc[4];
#pragma unroll
        for (int nf = 0; nf < 4; nf++) sc[nf] = (f32x4){0.f, 0.f, 0.f, 0.f};
#pragma unroll
        for (int nf = 0; nf < 4; nf++) {
#pragma unroll
            for (int k2 = 0; k2 < 2; k2++) {
                int kb = k2 * 64 + g * 16;
                s16x8 kbh = lds_ld16(Kh[cur], nf * 16 + q15, kb);
                sc[nf] = mfmah(kbh, aq[k2], sc[nf]);
            }
            f32x4 mb = *(const f32x4*)&MskB[cur][nf * 16 + g * 4];
            sc[nf] = sc[nf] * SC_TO_LOG2 + mb;
        }

        // per-lane softmax (row q = q15) with defer-max
        float pml = -1e30f;
#pragma unroll
        for (int nf = 0; nf < 4; nf++)
#pragma unroll
            for (int j = 0; j < 4; j++) pml = fmaxf(pml, sc[nf][j]);
        if (!__all(pml - m_ <= DEFER_THR)) {
            float pm = fmaxf(pml, __shfl_xor(pml, 16));
            pm = fmaxf(pm, __shfl_xor(pm, 32));
            float mn = fmaxf(m_, pm);
            float scl = fexp2(m_ - mn);
            m_ = mn;
            l_ *= scl;
#pragma unroll
            for (int j = 0; j < 4; j++) {
                float sb = __shfl(scl, g * 4 + j);
#pragma unroll
                for (int df = 0; df < 4; df++) o_[df][j] *= sb;
            }
        }
        float p[4][4];
        float rs = 0.f;
#pragma unroll
        for (int nf = 0; nf < 4; nf++)
#pragma unroll
            for (int j = 0; j < 4; j++) {
                float pv = fexp2(sc[nf][j] - m_);
                p[nf][j] = pv;
                rs += pv;
            }
        l_ += rs;  // lane-partial
        // in-register P repack: pa[k2] elem e = P[q15][k2*32 + g*8 + e]
        s16x8 pa[2];
#pragma unroll
        for (int k2 = 0; k2 < 2; k2++) {
            u32 A0 = pkh(p[2 * k2][0], p[2 * k2][1]);
            u32 A1 = pkh(p[2 * k2][2], p[2 * k2][3]);
            u32 B0 = pkh(p[2 * k2 + 1][0], p[2 * k2 + 1][1]);
            u32 B1 = pkh(p[2 * k2 + 1][2], p[2 * k2 + 1][3]);
            u32 s0, s1, t0, t1, w0, w1, w2, w3;
            swap32(lane, A0, B0, s0, s1);
            swap16(lane, s0, s1, w0, w2);
            swap32(lane, A1, B1, t0, t1);
            swap16(lane, t0, t1, w1, w3);
            u32x4 words = {w0, w1, w2, w3};
            pa[k2] = __builtin_bit_cast(s16x8, words);
        }

        // PV: O[q][d] += P[q][k] * V^T[d][k]
#pragma unroll
        for (int k2 = 0; k2 < 2; k2++) {
            int kb = k2 * 64 + g * 16;
#pragma unroll
            for (int df = 0; df < 4; df++) {
                s16x8 vb = lds_ld16(Vt[cur], df * 16 + q15, kb);
                o_[df] = mfmah(pa[k2], vb, o_[df]);
            }
        }
        __syncthreads();
    }

    float lt = l_;
    lt += __shfl_xor(lt, 16);
    lt += __shfl_xor(lt, 32);
#pragma unroll
    for (int j = 0; j < 4; j++) {
        float lb = __shfl(lt, g * 4 + j);
        float linv = __builtin_amdgcn_rcpf(lb);
        int qrow = q0 + w * 16 + g * 4 + j;
        size_t srow = (size_t)(b * SEQ + qrow);
#pragma unroll
        for (int df = 0; df < 4; df++) {
            int col = h * HD + df * 16 + q15;
            att[srow * HID + col] = f2h(o_[df][j] * linv);
        }
    }
}

// ---------------- GEMM2: att fp16 @ Wo fp16 (1 pass), 64x128 tiles, BK=32 dbuf -----
__global__ __launch_bounds__(256, 4) void gemm_out(
    const u16* __restrict__ A, const u16* __restrict__ Bh0,
    const float* __restrict__ bo, float* __restrict__ out) {
    __shared__ __align__(16) u16 SMa[2][64 * 32], SMb[2][128 * 32];  // 24 KB
    int tid = threadIdx.x, lane = tid & 63, w = tid >> 6;
    int g = lane >> 4, q15 = lane & 15;
    int wm = w >> 1, wn = w & 1;
    int m0 = blockIdx.y * 64, n0 = blockIdx.x * 128;
    f32x4 acc[2][4];
#pragma unroll
    for (int i = 0; i < 2; i++)
#pragma unroll
        for (int j = 0; j < 4; j++) acc[i][j] = (f32x4){0.f, 0.f, 0.f, 0.f};

    auto STAGE = [&](int db, int kt) {
        int k0 = kt * 32;
        {
            int c = tid;
            int row = c >> 2, slot = c & 3;
            int sg = slot ^ (row & 3);
            int dst = (c & ~63) * 8;
            gl_lds16(&A[(size_t)(m0 + row) * 1024 + k0 + sg * 8], &SMa[db][dst]);
        }
#pragma unroll
        for (int i = 0; i < 2; i++) {
            int c = i * 256 + tid;
            int row = c >> 2, slot = c & 3;
            int sg = slot ^ (row & 3);
            int dst = (c & ~63) * 8;
            gl_lds16(&Bh0[(size_t)(n0 + row) * 1024 + k0 + sg * 8], &SMb[db][dst]);
        }
    };

    STAGE(0, 0);
    for (int kt = 0; kt < 32; kt++) {
        int cur = kt & 1;
        __syncthreads();
        if (kt < 31) STAGE(cur ^ 1, kt + 1);
        s16x8 a_[2], b_[4];
#pragma unroll
        for (int i = 0; i < 2; i++)
            a_[i] = lds_ld32r(SMa[cur], wm * 32 + i * 16 + q15, g);
#pragma unroll
        for (int i = 0; i < 4; i++)
            b_[i] = lds_ld32r(SMb[cur], wn * 64 + i * 16 + q15, g);
#pragma unroll
        for (int mi = 0; mi < 2; mi++)
#pragma unroll
            for (int ni = 0; ni < 4; ni++)
                acc[mi][ni] = mfmah(a_[mi], b_[ni], acc[mi][ni]);
    }
#pragma unroll
    for (int mi = 0; mi < 2; mi++)
#pragma unroll
        for (int ni = 0; ni < 4; ni++) {
            int col = n0 + wn * 64 + ni * 16 + q15;
            float bias = bo[col];
#pragma unroll
            for (int j = 0; j < 4; j++) {
                int row = m0 + wm * 32 + mi * 16 + g * 4 + j;
                out[(size_t)row * 1024 + col] = acc[mi][ni][j] + bias;
            }
        }
}

extern "C" void kernel_launch(void* const* d_in, const int* in_sizes, int n_in,
                              void* d_out, int out_size, void* d_ws, size_t ws_size,
                              hipStream_t stream) {
    const float* qkv = (const float*)d_in[0];
    const void* mask = d_in[1];
    const float* Wqkv = (const float*)d_in[2];
    const float* bqkv = (const float*)d_in[3];
    const float* Wo = (const float*)d_in[4];
    const float* bo = (const float*)d_in[5];
    float* out = (float*)d_out;

    const size_t SZ_X = (size_t)4096 * 1024 * 2;       // 8 MB
    const size_t SZ_W = (size_t)3072 * 1024 * 2;       // 6 MB
    const size_t SZ_WO = (size_t)1024 * 1024 * 2;      // 2 MB
    const size_t SZ_QKV = (size_t)32 * 2048 * 64 * 2;  // 8 MB
    const size_t SZ_ATT = (size_t)4096 * 1024 * 2;     // 8 MB

    char* p = (char*)d_ws;
    u16* Xh = (u16*)p; p += SZ_X;
    u16* Wth = (u16*)p; p += SZ_W;
    u16* Wtl = (u16*)p; p += SZ_W;
    u16* Woth = (u16*)p; p += SZ_WO;
    u16* qh = (u16*)p; p += SZ_QKV;
    u16* kh = (u16*)p; p += SZ_QKV;
    u16* vt = (u16*)p; p += SZ_QKV;  // [bh][d][s_packed]
    u16* att = (u16*)p; p += SZ_ATT;
    float* pbias = (float*)p; p += BATCH * SEQ * 4;
    int* pack_idx = (int*)p; p += BATCH * SEQ * 4;
    int* cnt = (int*)p; p += 256;

    detect_mask<<<1, 256, 0, stream>>>((const unsigned char*)mask, pbias, pack_idx, cnt);
    split_x<<<4096, 256, 0, stream>>>(qkv, Xh);
    transpose_split<<<dim3(96, 32), dim3(32, 8), 0, stream>>>(Wqkv, Wth, Wtl, 1024, 3072,
                                                              SCALE_XW, 1);
    transpose_split<<<dim3(32, 32), dim3(32, 8), 0, stream>>>(Wo, Woth, nullptr, 1024, 1024,
                                                              1.0f, 0);
    gemm_qkv<<<dim3(24, 32), 256, 0, stream>>>(Xh, Wth, Wtl, bqkv, pack_idx, cnt, qh, kh, vt);
    attn_kernel<<<dim3(32, 32), 256, 0, stream>>>(qh, kh, vt, pbias, cnt, att);
    gemm_out<<<dim3(8, 64), 256, 0, stream>>>(att, Woth, bo, out);
}

// Round 15
// 110.215 us; speedup vs baseline: 1.2751x; 1.2096x over previous
//
#include <hip/hip_runtime.h>

#define DEV __device__ __forceinline__

typedef unsigned short u16;
typedef unsigned int u32;
typedef __attribute__((ext_vector_type(4))) float f32x4;
typedef __attribute__((ext_vector_type(8))) short s16x8;
typedef __attribute__((ext_vector_type(8))) _Float16 f16x8;
typedef __attribute__((ext_vector_type(4))) unsigned short u16x4;
typedef __attribute__((ext_vector_type(4))) unsigned int u32x4;

#define BATCH 2
#define SEQ 2048
#define HID 1024
#define NH 16
#define HD 64

// scaling scheme:  X' = 64*X, W' = 64*W -> proj = acc/4096
//  q stored = proj_q * 8*log2e*4, k stored = proj_k * 16
//  scores_mfma = 64 * (s * log2e); softmax uses sc*1/64 (FMA-fused w/ mask)
// R14: W single fp16 plane too (1-pass GEMM1): Wl corrected ~2^-12 rel, below the
// fp16 storage rounding (2^-11.5) already accepted on q/k/V outputs.
#define SCALE_XW 64.0f
#define INV_PROJ (1.0f / 4096.0f)
#define SCALE_Q 46.16624130844683f
#define SCALE_K 16.0f
#define SC_TO_LOG2 0.015625f
#define DEFER_THR 10.0f

DEV f32x4 mfmah(s16x8 a, s16x8 b, f32x4 c) {
    return __builtin_amdgcn_mfma_f32_16x16x32_f16(
        __builtin_bit_cast(f16x8, a), __builtin_bit_cast(f16x8, b), c, 0, 0, 0);
}

DEV u16 f2h(float x) { return __builtin_bit_cast(u16, (_Float16)x); }
DEV float h2f(u16 h) { return (float)__builtin_bit_cast(_Float16, h); }

DEV u32 pkh(float a, float b) {
#if __has_builtin(__builtin_amdgcn_cvt_pkrtz)
    auto r = __builtin_amdgcn_cvt_pkrtz(a, b);
    return __builtin_bit_cast(u32, r);
#else
    return (u32)f2h(a) | ((u32)f2h(b) << 16);
#endif
}

DEV float fexp2(float x) {
#if __has_builtin(__builtin_amdgcn_exp2f)
    return __builtin_amdgcn_exp2f(x);
#else
    return exp2f(x);
#endif
}

DEV void swap32(int lane, u32 a, u32 b, u32& o0, u32& o1) {
#if __has_builtin(__builtin_amdgcn_permlane32_swap)
    auto r = __builtin_amdgcn_permlane32_swap((int)a, (int)b, false, false);
    o0 = (u32)r[0]; o1 = (u32)r[1];
#else
    u32 ax = (u32)__shfl_xor((int)a, 32);
    u32 bx = (u32)__shfl_xor((int)b, 32);
    bool hi = (lane & 32) != 0;
    o0 = hi ? bx : a;
    o1 = hi ? b : ax;
#endif
}
DEV void swap16(int lane, u32 a, u32 b, u32& o0, u32& o1) {
#if __has_builtin(__builtin_amdgcn_permlane16_swap)
    auto r = __builtin_amdgcn_permlane16_swap((int)a, (int)b, false, false);
    o0 = (u32)r[0]; o1 = (u32)r[1];
#else
    u32 ax = (u32)__shfl_xor((int)a, 16);
    u32 bx = (u32)__shfl_xor((int)b, 16);
    bool hi = (lane & 16) != 0;
    o0 = hi ? bx : a;
    o1 = hi ? b : ax;
#endif
}

DEV void gl_lds16(const void* g, void* l) {
    __builtin_amdgcn_global_load_lds(
        (__attribute__((address_space(1))) void*)(void*)g,
        (__attribute__((address_space(3))) void*)l, 16, 0, 0);
}

// raw barrier pair (rule #18: sched_barrier fences around inline-asm waits)
DEV void vm0_bar() {
    __builtin_amdgcn_sched_barrier(0);
    asm volatile("s_waitcnt vmcnt(0)" ::: "memory");
    __builtin_amdgcn_s_barrier();
    __builtin_amdgcn_sched_barrier(0);
}

// rows of 128B, 16B slots XOR-swizzled by row&7
DEV s16x8 lds_ld16(const u16* base, int row, int kbyte) {
    return *(const s16x8*)((const char*)base + row * 128 + (kbyte ^ ((row & 7) << 4)));
}
// rows of 64B, 16B slots XOR-swizzled by row&3
DEV s16x8 lds_ld32r(const u16* base, int row, int g) {
    return *(const s16x8*)((const char*)base + row * 64 + ((g * 16) ^ ((row & 3) << 4)));
}

// ------- mask: sniff dtype, build key compaction (pack_idx/cnt) + packed bias -------
__global__ void detect_mask(const unsigned char* __restrict__ m, float* __restrict__ pbias,
                            int* __restrict__ pack_idx, int* __restrict__ cnt) {
    __shared__ int sb, sf;
    __shared__ int scan[256];
    int tid = threadIdx.x;
    if (tid == 0) { sb = 0; sf = 0; }
    __syncthreads();
    int lb = 0, lf = 0;
    for (int i = tid * 16; i < tid * 16 + 16; i++) {
        unsigned char v = m[i];
        int pos = i & 3;
        if (pos == 3 && v == 0x3f) lf = 1;
        if (pos != 0 && v != 0) lb = 1;
    }
    if (lb) atomicOr(&sb, 1);
    if (lf) atomicOr(&sf, 1);
    __syncthreads();
    int f = sf ? 2 : (sb ? 1 : 0);
#pragma unroll
    for (int b = 0; b < BATCH; b++) {
        int base = b * SEQ;
        int keep[8], lc = 0;
#pragma unroll
        for (int e = 0; e < 8; e++) {
            int i = base + tid * 8 + e;
            int mv;
            if (f == 0) mv = ((const int*)m)[i] != 0;
            else if (f == 1) mv = m[i] != 0;
            else mv = ((const float*)m)[i] != 0.0f;
            keep[e] = !mv;
            lc += keep[e];
        }
        scan[tid] = lc;
        __syncthreads();
        for (int s = 1; s < 256; s <<= 1) {
            int v = (tid >= s) ? scan[tid - s] : 0;
            __syncthreads();
            scan[tid] += v;
            __syncthreads();
        }
        int off = scan[tid] - lc;
        int total = scan[255];
        __syncthreads();  // scan reused next batch
#pragma unroll
        for (int e = 0; e < 8; e++)
            if (keep[e]) pack_idx[base + off++] = base + tid * 8 + e;
        if (tid == 0) cnt[b] = total;
        for (int j = tid; j < SEQ; j += 256)
            pbias[base + j] = (j < total) ? 0.0f : -1e30f;
    }
}

// ---------------- prep: scale+convert fp32 -> fp16 (single plane) ----------------
__global__ __launch_bounds__(256) void split_x(const float* __restrict__ in,
                                               u16* __restrict__ oh) {
    int i = (blockIdx.x * 256 + threadIdx.x) * 4;
    f32x4 v = *(const f32x4*)&in[i];
    u16x4 h;
#pragma unroll
    for (int e = 0; e < 4; e++) h[e] = f2h(v[e] * SCALE_XW);
    *(u16x4*)&oh[i] = h;
}

// in[K][N] fp32 -> out[N][K] fp16 (transposed, scaled, single plane)
__global__ __launch_bounds__(256) void transpose_split(const float* __restrict__ in,
                                                       u16* __restrict__ oh,
                                                       int K, int N, float scale) {
    __shared__ float t[32][33];
    int tx = threadIdx.x, ty = threadIdx.y;
    int n0 = blockIdx.x * 32, k0 = blockIdx.y * 32;
#pragma unroll
    for (int i = 0; i < 4; i++)
        t[ty + 8 * i][tx] = in[(size_t)(k0 + ty + 8 * i) * N + n0 + tx];
    __syncthreads();
#pragma unroll
    for (int i = 0; i < 4; i++) {
        float v = t[tx][ty + 8 * i] * scale;
        size_t o = (size_t)(n0 + ty + 8 * i) * K + k0 + tx;
        oh[o] = f2h(v);
    }
}

// ------- GEMM1: Xh @ Wh fp16 1-PASS, BK=32, single-buf 16KB (R11-proven schedule) -------
// K/V parts in PACKED key space (pack_idx/cnt); V-transpose scratch in separate LDS.
__global__ __launch_bounds__(256, 3) void gemm_qkv(
    const u16* __restrict__ Xh,
    const u16* __restrict__ Wth,
    const float* __restrict__ bqkv,
    const int* __restrict__ pack_idx, const int* __restrict__ cnt,
    u16* __restrict__ qh,
    u16* __restrict__ kh,
    u16* __restrict__ vt) {
    __shared__ __align__(16) u16 SM[2][128 * 32];  // 16 KB single buffer (X, W)
    __shared__ __align__(16) u16 T[64 * 140];      // 17.5 KB V-transpose scratch
    int tid = threadIdx.x, lane = tid & 63, w = tid >> 6;
    int g = lane >> 4, q15 = lane & 15;
    int wm = w >> 1, wn = w & 1;
    int m0 = blockIdx.y * 128, n0 = blockIdx.x * 128;
    int part = n0 >> 10;
    int bb = m0 >> 11;
    int cb = cnt[bb];
    if (part != 0 && (m0 & 2047) >= cb) return;  // packed rows all beyond count

    // fixed per-thread source-row map (2 rows/thread, constant across kt)
    int srcrow[2];
#pragma unroll
    for (int i = 0; i < 2; i++) {
        int r = m0 + ((i * 256 + tid) >> 2);
        srcrow[i] = (part == 0) ? r : (((r & 2047) < cb) ? pack_idx[r] : (bb << 11));
    }

    f32x4 acc[4][4];
#pragma unroll
    for (int i = 0; i < 4; i++)
#pragma unroll
        for (int j = 0; j < 4; j++) acc[i][j] = (f32x4){0.f, 0.f, 0.f, 0.f};

    auto STAGE = [&](int kt) {
        int k0 = kt * 32;
#pragma unroll
        for (int i = 0; i < 2; i++) {
            int c = i * 256 + tid;
            int row = c >> 2, slot = c & 3;
            int sg = slot ^ (row & 3);
            int dst = (c & ~63) * 8;
            size_t ga = (size_t)srcrow[i] * 1024 + k0 + sg * 8;
            size_t gb = (size_t)(n0 + row) * 1024 + k0 + sg * 8;
            gl_lds16(&Xh[ga], &SM[0][dst]);
            gl_lds16(&Wth[gb], &SM[1][dst]);
        }
    };

    STAGE(0);
    for (int kt = 0; kt < 32; kt++) {
        vm0_bar();  // stage for kt complete on all waves
        s16x8 a_h[4], b_h[4];
#pragma unroll
        for (int i = 0; i < 4; i++) {
            a_h[i] = lds_ld32r(SM[0], wm * 64 + i * 16 + q15, g);
            b_h[i] = lds_ld32r(SM[1], wn * 64 + i * 16 + q15, g);
        }
        __syncthreads();  // all waves' reads retired -> buffer reusable
        if (kt < 31) STAGE(kt + 1);
#pragma unroll
        for (int mi = 0; mi < 4; mi++)
#pragma unroll
            for (int ni = 0; ni < 4; ni++)
                acc[mi][ni] = mfmah(a_h[mi], b_h[ni], acc[mi][ni]);
    }

    if (part == 2) {
        const int TP = 140;
        // two 64-column half-passes; rows are PACKED s (tail garbage masked in attn)
#pragma unroll
        for (int h2 = 0; h2 < 2; h2++) {
            __syncthreads();
            if (wn == h2) {
#pragma unroll
                for (int mi = 0; mi < 4; mi++)
#pragma unroll
                    for (int ni = 0; ni < 4; ni++) {
                        int lcol = ni * 16 + q15;  // 0..63 within half
#pragma unroll
                        for (int j = 0; j < 4; j++) {
                            int lrow = wm * 64 + mi * 16 + g * 4 + j;
                            T[lcol * TP + lrow] =
                                f2h(acc[mi][ni][j] * INV_PROJ + bqkv[n0 + h2 * 64 + lcol]);
                        }
                    }
            }
            __syncthreads();
            int lcol = tid >> 2;  // 0..63
            int seg = tid & 3;
            int c = n0 - 2048 + h2 * 64 + lcol;
            int h = c >> 6, d = c & 63;
            int b = m0 >> 11, sbase = m0 & 2047;
            size_t rowbase = ((size_t)(b * NH + h) * HD + d) * SEQ + sbase;
#pragma unroll
            for (int k = 0; k < 2; k++) {
                int slot = seg * 2 + k;  // 8 slots x 16 rows = 128
                *(s16x8*)&vt[rowbase + slot * 16 + 0] = *(const s16x8*)&T[lcol * TP + slot * 16 + 0];
                *(s16x8*)&vt[rowbase + slot * 16 + 8] = *(const s16x8*)&T[lcol * TP + slot * 16 + 8];
            }
        }
    } else {
#pragma unroll
        for (int mi = 0; mi < 4; mi++)
#pragma unroll
            for (int ni = 0; ni < 4; ni++) {
                int col = n0 + wn * 64 + ni * 16 + q15;
                float bias = bqkv[col];
                int cc = col & 1023, h = cc >> 6, d = cc & 63;
#pragma unroll
                for (int j = 0; j < 4; j++) {
                    int row = m0 + wm * 64 + mi * 16 + g * 4 + j;
                    int b = row >> 11, s = row & 2047;  // s: packed for K, true for Q
                    float v = acc[mi][ni][j] * INV_PROJ + bias;
                    v *= (part == 0) ? SCALE_Q : SCALE_K;
                    size_t o = (size_t)(b * NH + h) * SEQ * HD + (size_t)s * HD + d;
                    if (part == 0) qh[o] = f2h(v);
                    else kh[o] = f2h(v);
                }
            }
    }
}

// ------ flash attention over PACKED keys: NT = ceil(cnt[b]/64) tiles ------
// 64-row q-tiles, 4 blocks/CU, 2-phase dbuf (R3-proven schedule).
__global__ __launch_bounds__(256, 4) void attn_kernel(
    const u16* __restrict__ qh,
    const u16* __restrict__ kh,
    const u16* __restrict__ vt, const float* __restrict__ pbias,
    const int* __restrict__ cnt,
    u16* __restrict__ att) {
    __shared__ __align__(16) u16 Kh[2][4096], Vt[2][4096];  // 32 KB
    __shared__ __align__(16) float MskB[2][64];
    int tid = threadIdx.x, lane = tid & 63, w = tid >> 6;
    int g = lane >> 4, q15 = lane & 15;
    int bid = blockIdx.y * 32 + blockIdx.x;
    int swz = (bid & 7) * 128 + (bid >> 3);  // bijective: 1024 % 8 == 0
    int qt = swz & 31, bh = swz >> 5;        // 4 bh per XCD -> L2-resident K/V
    int b = bh >> 4, h = bh & 15;
    int q0 = qt * 64;
    int NT = (cnt[b] + 63) >> 6;  // packed key tiles
    size_t base = (size_t)bh * SEQ * HD;
    const u16* vbase = vt + (size_t)bh * HD * SEQ;
    const float* mrow = pbias + b * SEQ;

    // Q fragments, 16 rows per wave (k-map: k = k2*32 + g*8 + e)
    s16x8 aq[2];
#pragma unroll
    for (int k2 = 0; k2 < 2; k2++) {
        size_t o = base + (size_t)(q0 + w * 16 + q15) * HD + k2 * 32 + g * 8;
        aq[k2] = *(const s16x8*)&qh[o];
    }

    float m_ = -1e30f, l_ = 0.f;  // l_ lane-partial
    f32x4 o_[4];
#pragma unroll
    for (int df = 0; df < 4; df++) o_[df] = (f32x4){0.f, 0.f, 0.f, 0.f};

    auto STAGE = [&](int buf, int k0) {
#pragma unroll
        for (int i = 0; i < 2; i++) {
            int c = i * 256 + tid;
            int row = c >> 3, slot = c & 7;
            int sg = slot ^ (row & 7);
            int dst = (c & ~63) * 8;
            size_t gK = base + (size_t)(k0 + row) * HD + sg * 8;
            gl_lds16(&kh[gK], &Kh[buf][dst]);
            size_t gV = (size_t)row * SEQ + k0 + sg * 8;
            gl_lds16(&vbase[gV], &Vt[buf][dst]);
        }
        if (tid < 16) gl_lds16(&mrow[k0 + tid * 4], &MskB[buf][0]);
    };

    STAGE(0, 0);
    __syncthreads();

    for (int kt = 0; kt < NT; kt++) {
        int cur = kt & 1;
        if (kt < NT - 1) STAGE(cur ^ 1, (kt + 1) * 64);

        // swapped QK^T: D[k][q], k = nf*16 + g*4 + j, q = q15
        f32x4 sc[4];
#pragma unroll
        for (int nf = 0; nf < 4; nf++) sc[nf] = (f32x4){0.f, 0.f, 0.f, 0.f};
#pragma unroll
        for (int nf = 0; nf < 4; nf++) {
#pragma unroll
            for (int k2 = 0; k2 < 2; k2++) {
                int kb = k2 * 64 + g * 16;
                s16x8 kbh = lds_ld16(Kh[cur], nf * 16 + q15, kb);
                sc[nf] = mfmah(kbh, aq[k2], sc[nf]);
            }
            f32x4 mb = *(const f32x4*)&MskB[cur][nf * 16 + g * 4];
            sc[nf] = sc[nf] * SC_TO_LOG2 + mb;
        }

        // per-lane softmax (row q = q15) with defer-max
        float pml = -1e30f;
#pragma unroll
        for (int nf = 0; nf < 4; nf++)
#pragma unroll
            for (int j = 0; j < 4; j++) pml = fmaxf(pml, sc[nf][j]);
        if (!__all(pml - m_ <= DEFER_THR)) {
            float pm = fmaxf(pml, __shfl_xor(pml, 16));
            pm = fmaxf(pm, __shfl_xor(pm, 32));
            float mn = fmaxf(m_, pm);
            float scl = fexp2(m_ - mn);
            m_ = mn;
            l_ *= scl;
#pragma unroll
            for (int j = 0; j < 4; j++) {
                float sb = __shfl(scl, g * 4 + j);
#pragma unroll
                for (int df = 0; df < 4; df++) o_[df][j] *= sb;
            }
        }
        float p[4][4];
        float rs = 0.f;
#pragma unroll
        for (int nf = 0; nf < 4; nf++)
#pragma unroll
            for (int j = 0; j < 4; j++) {
                float pv = fexp2(sc[nf][j] - m_);
                p[nf][j] = pv;
                rs += pv;
            }
        l_ += rs;  // lane-partial
        // in-register P repack: pa[k2] elem e = P[q15][k2*32 + g*8 + e]
        s16x8 pa[2];
#pragma unroll
        for (int k2 = 0; k2 < 2; k2++) {
            u32 A0 = pkh(p[2 * k2][0], p[2 * k2][1]);
            u32 A1 = pkh(p[2 * k2][2], p[2 * k2][3]);
            u32 B0 = pkh(p[2 * k2 + 1][0], p[2 * k2 + 1][1]);
            u32 B1 = pkh(p[2 * k2 + 1][2], p[2 * k2 + 1][3]);
            u32 s0, s1, t0, t1, w0, w1, w2, w3;
            swap32(lane, A0, B0, s0, s1);
            swap16(lane, s0, s1, w0, w2);
            swap32(lane, A1, B1, t0, t1);
            swap16(lane, t0, t1, w1, w3);
            u32x4 words = {w0, w1, w2, w3};
            pa[k2] = __builtin_bit_cast(s16x8, words);
        }

        // PV: O[q][d] += P[q][k] * V^T[d][k]
#pragma unroll
        for (int k2 = 0; k2 < 2; k2++) {
            int kb = k2 * 64 + g * 16;
#pragma unroll
            for (int df = 0; df < 4; df++) {
                s16x8 vb = lds_ld16(Vt[cur], df * 16 + q15, kb);
                o_[df] = mfmah(pa[k2], vb, o_[df]);
            }
        }
        __syncthreads();
    }

    float lt = l_;
    lt += __shfl_xor(lt, 16);
    lt += __shfl_xor(lt, 32);
#pragma unroll
    for (int j = 0; j < 4; j++) {
        float lb = __shfl(lt, g * 4 + j);
        float linv = __builtin_amdgcn_rcpf(lb);
        int qrow = q0 + w * 16 + g * 4 + j;
        size_t srow = (size_t)(b * SEQ + qrow);
#pragma unroll
        for (int df = 0; df < 4; df++) {
            int col = h * HD + df * 16 + q15;
            att[srow * HID + col] = f2h(o_[df][j] * linv);
        }
    }
}

// ---------------- GEMM2: att fp16 @ Wo fp16 (1 pass), 64x128 tiles, BK=32 dbuf -----
__global__ __launch_bounds__(256, 4) void gemm_out(
    const u16* __restrict__ A, const u16* __restrict__ Bh0,
    const float* __restrict__ bo, float* __restrict__ out) {
    __shared__ __align__(16) u16 SMa[2][64 * 32], SMb[2][128 * 32];  // 24 KB
    int tid = threadIdx.x, lane = tid & 63, w = tid >> 6;
    int g = lane >> 4, q15 = lane & 15;
    int wm = w >> 1, wn = w & 1;
    int m0 = blockIdx.y * 64, n0 = blockIdx.x * 128;
    f32x4 acc[2][4];
#pragma unroll
    for (int i = 0; i < 2; i++)
#pragma unroll
        for (int j = 0; j < 4; j++) acc[i][j] = (f32x4){0.f, 0.f, 0.f, 0.f};

    auto STAGE = [&](int db, int kt) {
        int k0 = kt * 32;
        {
            int c = tid;
            int row = c >> 2, slot = c & 3;
            int sg = slot ^ (row & 3);
            int dst = (c & ~63) * 8;
            gl_lds16(&A[(size_t)(m0 + row) * 1024 + k0 + sg * 8], &SMa[db][dst]);
        }
#pragma unroll
        for (int i = 0; i < 2; i++) {
            int c = i * 256 + tid;
            int row = c >> 2, slot = c & 3;
            int sg = slot ^ (row & 3);
            int dst = (c & ~63) * 8;
            gl_lds16(&Bh0[(size_t)(n0 + row) * 1024 + k0 + sg * 8], &SMb[db][dst]);
        }
    };

    STAGE(0, 0);
    for (int kt = 0; kt < 32; kt++) {
        int cur = kt & 1;
        __syncthreads();
        if (kt < 31) STAGE(cur ^ 1, kt + 1);
        s16x8 a_[2], b_[4];
#pragma unroll
        for (int i = 0; i < 2; i++)
            a_[i] = lds_ld32r(SMa[cur], wm * 32 + i * 16 + q15, g);
#pragma unroll
        for (int i = 0; i < 4; i++)
            b_[i] = lds_ld32r(SMb[cur], wn * 64 + i * 16 + q15, g);
#pragma unroll
        for (int mi = 0; mi < 2; mi++)
#pragma unroll
            for (int ni = 0; ni < 4; ni++)
                acc[mi][ni] = mfmah(a_[mi], b_[ni], acc[mi][ni]);
    }
#pragma unroll
    for (int mi = 0; mi < 2; mi++)
#pragma unroll
        for (int ni = 0; ni < 4; ni++) {
            int col = n0 + wn * 64 + ni * 16 + q15;
            float bias = bo[col];
#pragma unroll
            for (int j = 0; j < 4; j++) {
                int row = m0 + wm * 32 + mi * 16 + g * 4 + j;
                out[(size_t)row * 1024 + col] = acc[mi][ni][j] + bias;
            }
        }
}

extern "C" void kernel_launch(void* const* d_in, const int* in_sizes, int n_in,
                              void* d_out, int out_size, void* d_ws, size_t ws_size,
                              hipStream_t stream) {
    const float* qkv = (const float*)d_in[0];
    const void* mask = d_in[1];
    const float* Wqkv = (const float*)d_in[2];
    const float* bqkv = (const float*)d_in[3];
    const float* Wo = (const float*)d_in[4];
    const float* bo = (const float*)d_in[5];
    float* out = (float*)d_out;

    const size_t SZ_X = (size_t)4096 * 1024 * 2;       // 8 MB
    const size_t SZ_W = (size_t)3072 * 1024 * 2;       // 6 MB
    const size_t SZ_WO = (size_t)1024 * 1024 * 2;      // 2 MB
    const size_t SZ_QKV = (size_t)32 * 2048 * 64 * 2;  // 8 MB
    const size_t SZ_ATT = (size_t)4096 * 1024 * 2;     // 8 MB

    char* p = (char*)d_ws;
    u16* Xh = (u16*)p; p += SZ_X;
    u16* Wth = (u16*)p; p += SZ_W;
    u16* Woth = (u16*)p; p += SZ_WO;
    u16* qh = (u16*)p; p += SZ_QKV;
    u16* kh = (u16*)p; p += SZ_QKV;
    u16* vt = (u16*)p; p += SZ_QKV;  // [bh][d][s_packed]
    u16* att = (u16*)p; p += SZ_ATT;
    float* pbias = (float*)p; p += BATCH * SEQ * 4;
    int* pack_idx = (int*)p; p += BATCH * SEQ * 4;
    int* cnt = (int*)p; p += 256;

    detect_mask<<<1, 256, 0, stream>>>((const unsigned char*)mask, pbias, pack_idx, cnt);
    split_x<<<4096, 256, 0, stream>>>(qkv, Xh);
    transpose_split<<<dim3(96, 32), dim3(32, 8), 0, stream>>>(Wqkv, Wth, 1024, 3072, SCALE_XW);
    transpose_split<<<dim3(32, 32), dim3(32, 8), 0, stream>>>(Wo, Woth, 1024, 1024, 1.0f);
    gemm_qkv<<<dim3(24, 32), 256, 0, stream>>>(Xh, Wth, bqkv, pack_idx, cnt, qh, kh, vt);
    attn_kernel<<<dim3(32, 32), 256, 0, stream>>>(qh, kh, vt, pbias, cnt, att);
    gemm_out<<<dim3(8, 64), 256, 0, stream>>>(att, Woth, bo, out);
}

// Round 16
// 109.894 us; speedup vs baseline: 1.2788x; 1.0029x over previous
//
#include <hip/hip_runtime.h>

#define DEV __device__ __forceinline__

typedef unsigned short u16;
typedef unsigned int u32;
typedef __attribute__((ext_vector_type(4))) float f32x4;
typedef __attribute__((ext_vector_type(8))) short s16x8;
typedef __attribute__((ext_vector_type(8))) _Float16 f16x8;
typedef __attribute__((ext_vector_type(4))) unsigned short u16x4;
typedef __attribute__((ext_vector_type(4))) unsigned int u32x4;

#define BATCH 2
#define SEQ 2048
#define HID 1024
#define NH 16
#define HD 64

// scaling scheme:  X' = 64*X, W' = 64*W -> proj = acc/4096
//  q stored = proj_q * 8*log2e*4, k stored = proj_k * 16
//  scores_mfma = 64 * (s * log2e); softmax uses sc*1/64 (FMA-fused w/ mask)
#define SCALE_XW 64.0f
#define INV_PROJ (1.0f / 4096.0f)
#define SCALE_Q 46.16624130844683f
#define SCALE_K 16.0f
#define SC_TO_LOG2 0.015625f
#define DEFER_THR 10.0f

DEV f32x4 mfmah(s16x8 a, s16x8 b, f32x4 c) {
    return __builtin_amdgcn_mfma_f32_16x16x32_f16(
        __builtin_bit_cast(f16x8, a), __builtin_bit_cast(f16x8, b), c, 0, 0, 0);
}

DEV u16 f2h(float x) { return __builtin_bit_cast(u16, (_Float16)x); }
DEV float h2f(u16 h) { return (float)__builtin_bit_cast(_Float16, h); }

DEV u32 pkh(float a, float b) {
#if __has_builtin(__builtin_amdgcn_cvt_pkrtz)
    auto r = __builtin_amdgcn_cvt_pkrtz(a, b);
    return __builtin_bit_cast(u32, r);
#else
    return (u32)f2h(a) | ((u32)f2h(b) << 16);
#endif
}

DEV float fexp2(float x) {
#if __has_builtin(__builtin_amdgcn_exp2f)
    return __builtin_amdgcn_exp2f(x);
#else
    return exp2f(x);
#endif
}

DEV void swap32(int lane, u32 a, u32 b, u32& o0, u32& o1) {
#if __has_builtin(__builtin_amdgcn_permlane32_swap)
    auto r = __builtin_amdgcn_permlane32_swap((int)a, (int)b, false, false);
    o0 = (u32)r[0]; o1 = (u32)r[1];
#else
    u32 ax = (u32)__shfl_xor((int)a, 32);
    u32 bx = (u32)__shfl_xor((int)b, 32);
    bool hi = (lane & 32) != 0;
    o0 = hi ? bx : a;
    o1 = hi ? b : ax;
#endif
}
DEV void swap16(int lane, u32 a, u32 b, u32& o0, u32& o1) {
#if __has_builtin(__builtin_amdgcn_permlane16_swap)
    auto r = __builtin_amdgcn_permlane16_swap((int)a, (int)b, false, false);
    o0 = (u32)r[0]; o1 = (u32)r[1];
#else
    u32 ax = (u32)__shfl_xor((int)a, 16);
    u32 bx = (u32)__shfl_xor((int)b, 16);
    bool hi = (lane & 16) != 0;
    o0 = hi ? bx : a;
    o1 = hi ? b : ax;
#endif
}

DEV void gl_lds16(const void* g, void* l) {
    __builtin_amdgcn_global_load_lds(
        (__attribute__((address_space(1))) void*)(void*)g,
        (__attribute__((address_space(3))) void*)l, 16, 0, 0);
}

// raw barrier pair (rule #18: sched_barrier fences around inline-asm waits)
DEV void vm0_bar() {
    __builtin_amdgcn_sched_barrier(0);
    asm volatile("s_waitcnt vmcnt(0)" ::: "memory");
    __builtin_amdgcn_s_barrier();
    __builtin_amdgcn_sched_barrier(0);
}

// rows of 128B, 16B slots XOR-swizzled by row&7
DEV s16x8 lds_ld16(const u16* base, int row, int kbyte) {
    return *(const s16x8*)((const char*)base + row * 128 + (kbyte ^ ((row & 7) << 4)));
}
// rows of 64B, 16B slots XOR-swizzled by row&3
DEV s16x8 lds_ld32r(const u16* base, int row, int g) {
    return *(const s16x8*)((const char*)base + row * 64 + ((g * 16) ^ ((row & 3) << 4)));
}

// ------- mask: sniff dtype, build key compaction (pack_idx/cnt) + packed bias -------
__global__ void detect_mask(const unsigned char* __restrict__ m, float* __restrict__ pbias,
                            int* __restrict__ pack_idx, int* __restrict__ cnt) {
    __shared__ int sb, sf;
    __shared__ int scan[256];
    int tid = threadIdx.x;
    if (tid == 0) { sb = 0; sf = 0; }
    __syncthreads();
    int lb = 0, lf = 0;
    for (int i = tid * 16; i < tid * 16 + 16; i++) {
        unsigned char v = m[i];
        int pos = i & 3;
        if (pos == 3 && v == 0x3f) lf = 1;
        if (pos != 0 && v != 0) lb = 1;
    }
    if (lb) atomicOr(&sb, 1);
    if (lf) atomicOr(&sf, 1);
    __syncthreads();
    int f = sf ? 2 : (sb ? 1 : 0);
#pragma unroll
    for (int b = 0; b < BATCH; b++) {
        int base = b * SEQ;
        int keep[8], lc = 0;
#pragma unroll
        for (int e = 0; e < 8; e++) {
            int i = base + tid * 8 + e;
            int mv;
            if (f == 0) mv = ((const int*)m)[i] != 0;
            else if (f == 1) mv = m[i] != 0;
            else mv = ((const float*)m)[i] != 0.0f;
            keep[e] = !mv;
            lc += keep[e];
        }
        scan[tid] = lc;
        __syncthreads();
        for (int s = 1; s < 256; s <<= 1) {
            int v = (tid >= s) ? scan[tid - s] : 0;
            __syncthreads();
            scan[tid] += v;
            __syncthreads();
        }
        int off = scan[tid] - lc;
        int total = scan[255];
        __syncthreads();  // scan reused next batch
#pragma unroll
        for (int e = 0; e < 8; e++)
            if (keep[e]) pack_idx[base + off++] = base + tid * 8 + e;
        if (tid == 0) cnt[b] = total;
        for (int j = tid; j < SEQ; j += 256)
            pbias[base + j] = (j < total) ? 0.0f : -1e30f;
    }
}

// ---------------- prep: scale+convert fp32 -> fp16 (single plane) ----------------
__global__ __launch_bounds__(256) void split_x(const float* __restrict__ in,
                                               u16* __restrict__ oh) {
    int i = (blockIdx.x * 256 + threadIdx.x) * 4;
    f32x4 v = *(const f32x4*)&in[i];
    u16x4 h;
#pragma unroll
    for (int e = 0; e < 4; e++) h[e] = f2h(v[e] * SCALE_XW);
    *(u16x4*)&oh[i] = h;
}

// in[K][N] fp32 -> out[N][K] fp16 (transposed, scaled, single plane)
__global__ __launch_bounds__(256) void transpose_split(const float* __restrict__ in,
                                                       u16* __restrict__ oh,
                                                       int K, int N, float scale) {
    __shared__ float t[32][33];
    int tx = threadIdx.x, ty = threadIdx.y;
    int n0 = blockIdx.x * 32, k0 = blockIdx.y * 32;
#pragma unroll
    for (int i = 0; i < 4; i++)
        t[ty + 8 * i][tx] = in[(size_t)(k0 + ty + 8 * i) * N + n0 + tx];
    __syncthreads();
#pragma unroll
    for (int i = 0; i < 4; i++) {
        float v = t[tx][ty + 8 * i] * scale;
        size_t o = (size_t)(n0 + ty + 8 * i) * K + k0 + tx;
        oh[o] = f2h(v);
    }
}

// ------- GEMM1: Xh @ Wh fp16 1-PASS, BK=32, single-buf 16KB (R11-proven schedule) -------
__global__ __launch_bounds__(256, 3) void gemm_qkv(
    const u16* __restrict__ Xh,
    const u16* __restrict__ Wth,
    const float* __restrict__ bqkv,
    const int* __restrict__ pack_idx, const int* __restrict__ cnt,
    u16* __restrict__ qh,
    u16* __restrict__ kh,
    u16* __restrict__ vt) {
    __shared__ __align__(16) u16 SM[2][128 * 32];  // 16 KB single buffer (X, W)
    __shared__ __align__(16) u16 T[64 * 140];      // 17.5 KB V-transpose scratch
    int tid = threadIdx.x, lane = tid & 63, w = tid >> 6;
    int g = lane >> 4, q15 = lane & 15;
    int wm = w >> 1, wn = w & 1;
    int m0 = blockIdx.y * 128, n0 = blockIdx.x * 128;
    int part = n0 >> 10;
    int bb = m0 >> 11;
    int cb = cnt[bb];
    if (part != 0 && (m0 & 2047) >= cb) return;  // packed rows all beyond count

    int srcrow[2];
#pragma unroll
    for (int i = 0; i < 2; i++) {
        int r = m0 + ((i * 256 + tid) >> 2);
        srcrow[i] = (part == 0) ? r : (((r & 2047) < cb) ? pack_idx[r] : (bb << 11));
    }

    f32x4 acc[4][4];
#pragma unroll
    for (int i = 0; i < 4; i++)
#pragma unroll
        for (int j = 0; j < 4; j++) acc[i][j] = (f32x4){0.f, 0.f, 0.f, 0.f};

    auto STAGE = [&](int kt) {
        int k0 = kt * 32;
#pragma unroll
        for (int i = 0; i < 2; i++) {
            int c = i * 256 + tid;
            int row = c >> 2, slot = c & 3;
            int sg = slot ^ (row & 3);
            int dst = (c & ~63) * 8;
            size_t ga = (size_t)srcrow[i] * 1024 + k0 + sg * 8;
            size_t gb = (size_t)(n0 + row) * 1024 + k0 + sg * 8;
            gl_lds16(&Xh[ga], &SM[0][dst]);
            gl_lds16(&Wth[gb], &SM[1][dst]);
        }
    };

    STAGE(0);
    for (int kt = 0; kt < 32; kt++) {
        vm0_bar();  // stage for kt complete on all waves
        s16x8 a_h[4], b_h[4];
#pragma unroll
        for (int i = 0; i < 4; i++) {
            a_h[i] = lds_ld32r(SM[0], wm * 64 + i * 16 + q15, g);
            b_h[i] = lds_ld32r(SM[1], wn * 64 + i * 16 + q15, g);
        }
        __syncthreads();  // all waves' reads retired -> buffer reusable
        if (kt < 31) STAGE(kt + 1);
#pragma unroll
        for (int mi = 0; mi < 4; mi++)
#pragma unroll
            for (int ni = 0; ni < 4; ni++)
                acc[mi][ni] = mfmah(a_h[mi], b_h[ni], acc[mi][ni]);
    }

    if (part == 2) {
        const int TP = 140;
#pragma unroll
        for (int h2 = 0; h2 < 2; h2++) {
            __syncthreads();
            if (wn == h2) {
#pragma unroll
                for (int mi = 0; mi < 4; mi++)
#pragma unroll
                    for (int ni = 0; ni < 4; ni++) {
                        int lcol = ni * 16 + q15;  // 0..63 within half
#pragma unroll
                        for (int j = 0; j < 4; j++) {
                            int lrow = wm * 64 + mi * 16 + g * 4 + j;
                            T[lcol * TP + lrow] =
                                f2h(acc[mi][ni][j] * INV_PROJ + bqkv[n0 + h2 * 64 + lcol]);
                        }
                    }
            }
            __syncthreads();
            int lcol = tid >> 2;  // 0..63
            int seg = tid & 3;
            int c = n0 - 2048 + h2 * 64 + lcol;
            int h = c >> 6, d = c & 63;
            int b = m0 >> 11, sbase = m0 & 2047;
            size_t rowbase = ((size_t)(b * NH + h) * HD + d) * SEQ + sbase;
#pragma unroll
            for (int k = 0; k < 2; k++) {
                int slot = seg * 2 + k;  // 8 slots x 16 rows = 128
                *(s16x8*)&vt[rowbase + slot * 16 + 0] = *(const s16x8*)&T[lcol * TP + slot * 16 + 0];
                *(s16x8*)&vt[rowbase + slot * 16 + 8] = *(const s16x8*)&T[lcol * TP + slot * 16 + 8];
            }
        }
    } else {
#pragma unroll
        for (int mi = 0; mi < 4; mi++)
#pragma unroll
            for (int ni = 0; ni < 4; ni++) {
                int col = n0 + wn * 64 + ni * 16 + q15;
                float bias = bqkv[col];
                int cc = col & 1023, h = cc >> 6, d = cc & 63;
#pragma unroll
                for (int j = 0; j < 4; j++) {
                    int row = m0 + wm * 64 + mi * 16 + g * 4 + j;
                    int b = row >> 11, s = row & 2047;  // s: packed for K, true for Q
                    float v = acc[mi][ni][j] * INV_PROJ + bias;
                    v *= (part == 0) ? SCALE_Q : SCALE_K;
                    size_t o = (size_t)(b * NH + h) * SEQ * HD + (size_t)s * HD + d;
                    if (part == 0) qh[o] = f2h(v);
                    else kh[o] = f2h(v);
                }
            }
    }
}

// ------ flash attention over PACKED keys, 2 q-groups/wave (R15) ------
// 4 waves x 32 q-rows (q-tile 128), grid (16,32)=512; 16 K/V ds_reads serve
// 32 MFMA per wave-iter (DS reads per unit work halved vs R14). Math per
// q-row identical to R14 (same key order).
__global__ __launch_bounds__(256, 2) void attn_kernel(
    const u16* __restrict__ qh,
    const u16* __restrict__ kh,
    const u16* __restrict__ vt, const float* __restrict__ pbias,
    const int* __restrict__ cnt,
    u16* __restrict__ att) {
    __shared__ __align__(16) u16 Kh[2][4096], Vt[2][4096];  // 32 KB
    __shared__ __align__(16) float MskB[2][64];
    int tid = threadIdx.x, lane = tid & 63, w = tid >> 6;
    int g = lane >> 4, q15 = lane & 15;
    int bid = blockIdx.y * 16 + blockIdx.x;
    int swz = (bid & 7) * 64 + (bid >> 3);  // bijective: 512 % 8 == 0
    int qt = swz & 15, bh = swz >> 4;
    int b = bh >> 4, h = bh & 15;
    int q0 = qt * 128;
    int NT = (cnt[b] + 63) >> 6;  // packed key tiles
    size_t base = (size_t)bh * SEQ * HD;
    const u16* vbase = vt + (size_t)bh * HD * SEQ;
    const float* mrow = pbias + b * SEQ;

    // Q fragments, 2 groups of 16 rows (k-map: k = k2*32 + g*8 + e)
    s16x8 aq[2][2];
#pragma unroll
    for (int grp = 0; grp < 2; grp++)
#pragma unroll
        for (int k2 = 0; k2 < 2; k2++) {
            size_t o = base + (size_t)(q0 + w * 32 + grp * 16 + q15) * HD + k2 * 32 + g * 8;
            aq[grp][k2] = *(const s16x8*)&qh[o];
        }

    float m_[2] = {-1e30f, -1e30f}, l_[2] = {0.f, 0.f};  // lane-partial l
    f32x4 o_[2][4];
#pragma unroll
    for (int grp = 0; grp < 2; grp++)
#pragma unroll
        for (int df = 0; df < 4; df++) o_[grp][df] = (f32x4){0.f, 0.f, 0.f, 0.f};

    auto STAGE = [&](int buf, int k0) {
#pragma unroll
        for (int i = 0; i < 2; i++) {
            int c = i * 256 + tid;
            int row = c >> 3, slot = c & 7;
            int sg = slot ^ (row & 7);
            int dst = (c & ~63) * 8;
            size_t gK = base + (size_t)(k0 + row) * HD + sg * 8;
            gl_lds16(&kh[gK], &Kh[buf][dst]);
            size_t gV = (size_t)row * SEQ + k0 + sg * 8;
            gl_lds16(&vbase[gV], &Vt[buf][dst]);
        }
        if (tid < 16) gl_lds16(&mrow[k0 + tid * 4], &MskB[buf][0]);
    };

    STAGE(0, 0);
    __syncthreads();

    for (int kt = 0; kt < NT; kt++) {
        int cur = kt & 1;
        if (kt < NT - 1) STAGE(cur ^ 1, (kt + 1) * 64);

        // swapped QK^T both groups: D[k][q], k = nf*16 + g*4 + j, q = q15
        f32x4 sc0[4], sc1[4];
#pragma unroll
        for (int nf = 0; nf < 4; nf++) {
            sc0[nf] = (f32x4){0.f, 0.f, 0.f, 0.f};
            sc1[nf] = (f32x4){0.f, 0.f, 0.f, 0.f};
        }
#pragma unroll
        for (int nf = 0; nf < 4; nf++) {
#pragma unroll
            for (int k2 = 0; k2 < 2; k2++) {
                int kb = k2 * 64 + g * 16;
                s16x8 kbh = lds_ld16(Kh[cur], nf * 16 + q15, kb);
                sc0[nf] = mfmah(kbh, aq[0][k2], sc0[nf]);
                sc1[nf] = mfmah(kbh, aq[1][k2], sc1[nf]);
            }
            f32x4 mb = *(const f32x4*)&MskB[cur][nf * 16 + g * 4];
            sc0[nf] = sc0[nf] * SC_TO_LOG2 + mb;
            sc1[nf] = sc1[nf] * SC_TO_LOG2 + mb;
        }

        s16x8 pa[2][2];
#pragma unroll
        for (int grp = 0; grp < 2; grp++) {
            f32x4* sc = grp ? sc1 : sc0;
            float pml = -1e30f;
#pragma unroll
            for (int nf = 0; nf < 4; nf++)
#pragma unroll
                for (int j = 0; j < 4; j++) pml = fmaxf(pml, sc[nf][j]);
            // defer-max: skip rescale while tile max stays within THR of running max
            if (!__all(pml - m_[grp] <= DEFER_THR)) {
                float pm = fmaxf(pml, __shfl_xor(pml, 16));
                pm = fmaxf(pm, __shfl_xor(pm, 32));
                float mn = fmaxf(m_[grp], pm);
                float scl = fexp2(m_[grp] - mn);
                m_[grp] = mn;
                l_[grp] *= scl;
#pragma unroll
                for (int j = 0; j < 4; j++) {
                    float sb = __shfl(scl, g * 4 + j);
#pragma unroll
                    for (int df = 0; df < 4; df++) o_[grp][df][j] *= sb;
                }
            }
            float p[4][4];
            float rs = 0.f;
#pragma unroll
            for (int nf = 0; nf < 4; nf++)
#pragma unroll
                for (int j = 0; j < 4; j++) {
                    float pv = fexp2(sc[nf][j] - m_[grp]);
                    p[nf][j] = pv;
                    rs += pv;
                }
            l_[grp] += rs;  // lane-partial
            // in-register P repack: pa[k2] elem e = P[q15][k2*32 + g*8 + e]
#pragma unroll
            for (int k2 = 0; k2 < 2; k2++) {
                u32 A0 = pkh(p[2 * k2][0], p[2 * k2][1]);
                u32 A1 = pkh(p[2 * k2][2], p[2 * k2][3]);
                u32 B0 = pkh(p[2 * k2 + 1][0], p[2 * k2 + 1][1]);
                u32 B1 = pkh(p[2 * k2 + 1][2], p[2 * k2 + 1][3]);
                u32 s0, s1, t0, t1, w0, w1, w2, w3;
                swap32(lane, A0, B0, s0, s1);
                swap16(lane, s0, s1, w0, w2);
                swap32(lane, A1, B1, t0, t1);
                swap16(lane, t0, t1, w1, w3);
                u32x4 words = {w0, w1, w2, w3};
                pa[grp][k2] = __builtin_bit_cast(s16x8, words);
            }
        }

        // PV: O[q][d] += P[q][k] * V^T[d][k]  (vb shared by both groups)
#pragma unroll
        for (int k2 = 0; k2 < 2; k2++) {
            int kb = k2 * 64 + g * 16;
#pragma unroll
            for (int df = 0; df < 4; df++) {
                s16x8 vb = lds_ld16(Vt[cur], df * 16 + q15, kb);
                o_[0][df] = mfmah(pa[0][k2], vb, o_[0][df]);
                o_[1][df] = mfmah(pa[1][k2], vb, o_[1][df]);
            }
        }
        __syncthreads();
    }

#pragma unroll
    for (int grp = 0; grp < 2; grp++) {
        float lt = l_[grp];
        lt += __shfl_xor(lt, 16);
        lt += __shfl_xor(lt, 32);
#pragma unroll
        for (int j = 0; j < 4; j++) {
            float lb = __shfl(lt, g * 4 + j);
            float linv = __builtin_amdgcn_rcpf(lb);
            int qrow = q0 + w * 32 + grp * 16 + g * 4 + j;
            size_t srow = (size_t)(b * SEQ + qrow);
#pragma unroll
            for (int df = 0; df < 4; df++) {
                int col = h * HD + df * 16 + q15;
                att[srow * HID + col] = f2h(o_[grp][df][j] * linv);
            }
        }
    }
}

// ---------------- GEMM2: att fp16 @ Wo fp16 (1 pass), 64x128 tiles, BK=32 dbuf -----
__global__ __launch_bounds__(256, 4) void gemm_out(
    const u16* __restrict__ A, const u16* __restrict__ Bh0,
    const float* __restrict__ bo, float* __restrict__ out) {
    __shared__ __align__(16) u16 SMa[2][64 * 32], SMb[2][128 * 32];  // 24 KB
    int tid = threadIdx.x, lane = tid & 63, w = tid >> 6;
    int g = lane >> 4, q15 = lane & 15;
    int wm = w >> 1, wn = w & 1;
    int m0 = blockIdx.y * 64, n0 = blockIdx.x * 128;
    f32x4 acc[2][4];
#pragma unroll
    for (int i = 0; i < 2; i++)
#pragma unroll
        for (int j = 0; j < 4; j++) acc[i][j] = (f32x4){0.f, 0.f, 0.f, 0.f};

    auto STAGE = [&](int db, int kt) {
        int k0 = kt * 32;
        {
            int c = tid;
            int row = c >> 2, slot = c & 3;
            int sg = slot ^ (row & 3);
            int dst = (c & ~63) * 8;
            gl_lds16(&A[(size_t)(m0 + row) * 1024 + k0 + sg * 8], &SMa[db][dst]);
        }
#pragma unroll
        for (int i = 0; i < 2; i++) {
            int c = i * 256 + tid;
            int row = c >> 2, slot = c & 3;
            int sg = slot ^ (row & 3);
            int dst = (c & ~63) * 8;
            gl_lds16(&Bh0[(size_t)(n0 + row) * 1024 + k0 + sg * 8], &SMb[db][dst]);
        }
    };

    STAGE(0, 0);
    for (int kt = 0; kt < 32; kt++) {
        int cur = kt & 1;
        __syncthreads();
        if (kt < 31) STAGE(cur ^ 1, kt + 1);
        s16x8 a_[2], b_[4];
#pragma unroll
        for (int i = 0; i < 2; i++)
            a_[i] = lds_ld32r(SMa[cur], wm * 32 + i * 16 + q15, g);
#pragma unroll
        for (int i = 0; i < 4; i++)
            b_[i] = lds_ld32r(SMb[cur], wn * 64 + i * 16 + q15, g);
#pragma unroll
        for (int mi = 0; mi < 2; mi++)
#pragma unroll
            for (int ni = 0; ni < 4; ni++)
                acc[mi][ni] = mfmah(a_[mi], b_[ni], acc[mi][ni]);
    }
#pragma unroll
    for (int mi = 0; mi < 2; mi++)
#pragma unroll
        for (int ni = 0; ni < 4; ni++) {
            int col = n0 + wn * 64 + ni * 16 + q15;
            float bias = bo[col];
#pragma unroll
            for (int j = 0; j < 4; j++) {
                int row = m0 + wm * 32 + mi * 16 + g * 4 + j;
                out[(size_t)row * 1024 + col] = acc[mi][ni][j] + bias;
            }
        }
}

extern "C" void kernel_launch(void* const* d_in, const int* in_sizes, int n_in,
                              void* d_out, int out_size, void* d_ws, size_t ws_size,
                              hipStream_t stream) {
    const float* qkv = (const float*)d_in[0];
    const void* mask = d_in[1];
    const float* Wqkv = (const float*)d_in[2];
    const float* bqkv = (const float*)d_in[3];
    const float* Wo = (const float*)d_in[4];
    const float* bo = (const float*)d_in[5];
    float* out = (float*)d_out;

    const size_t SZ_X = (size_t)4096 * 1024 * 2;       // 8 MB
    const size_t SZ_W = (size_t)3072 * 1024 * 2;       // 6 MB
    const size_t SZ_WO = (size_t)1024 * 1024 * 2;      // 2 MB
    const size_t SZ_QKV = (size_t)32 * 2048 * 64 * 2;  // 8 MB
    const size_t SZ_ATT = (size_t)4096 * 1024 * 2;     // 8 MB

    char* p = (char*)d_ws;
    u16* Xh = (u16*)p; p += SZ_X;
    u16* Wth = (u16*)p; p += SZ_W;
    u16* Woth = (u16*)p; p += SZ_WO;
    u16* qh = (u16*)p; p += SZ_QKV;
    u16* kh = (u16*)p; p += SZ_QKV;
    u16* vt = (u16*)p; p += SZ_QKV;  // [bh][d][s_packed]
    u16* att = (u16*)p; p += SZ_ATT;
    float* pbias = (float*)p; p += BATCH * SEQ * 4;
    int* pack_idx = (int*)p; p += BATCH * SEQ * 4;
    int* cnt = (int*)p; p += 256;

    detect_mask<<<1, 256, 0, stream>>>((const unsigned char*)mask, pbias, pack_idx, cnt);
    split_x<<<4096, 256, 0, stream>>>(qkv, Xh);
    transpose_split<<<dim3(96, 32), dim3(32, 8), 0, stream>>>(Wqkv, Wth, 1024, 3072, SCALE_XW);
    transpose_split<<<dim3(32, 32), dim3(32, 8), 0, stream>>>(Wo, Woth, 1024, 1024, 1.0f);
    gemm_qkv<<<dim3(24, 32), 256, 0, stream>>>(Xh, Wth, bqkv, pack_idx, cnt, qh, kh, vt);
    attn_kernel<<<dim3(16, 32), 256, 0, stream>>>(qh, kh, vt, pbias, cnt, att);
    gemm_out<<<dim3(8, 64), 256, 0, stream>>>(att, Woth, bo, out);
}

// Round 17
// 103.130 us; speedup vs baseline: 1.3627x; 1.0656x over previous
//
#include <hip/hip_runtime.h>

#define DEV __device__ __forceinline__

typedef unsigned short u16;
typedef unsigned int u32;
typedef __attribute__((ext_vector_type(4))) float f32x4;
typedef __attribute__((ext_vector_type(8))) short s16x8;
typedef __attribute__((ext_vector_type(8))) _Float16 f16x8;
typedef __attribute__((ext_vector_type(4))) unsigned short u16x4;
typedef __attribute__((ext_vector_type(4))) unsigned int u32x4;

#define BATCH 2
#define SEQ 2048
#define HID 1024
#define NH 16
#define HD 64

// scaling:  X' = 64*X, W' = 64*W -> proj = acc/4096
//  q stored = proj_q * 8*log2e (log2-domain scores direct from MFMA), k stored = proj_k
//  mask bias enters as the QK MFMA C-in (no post-FMA pass)
#define SCALE_XW 64.0f
#define INV_PROJ (1.0f / 4096.0f)
#define SCALE_Q 11.541560327111707f
#define SCALE_K 1.0f
#define DEFER_THR 10.0f

DEV f32x4 mfmah(s16x8 a, s16x8 b, f32x4 c) {
    return __builtin_amdgcn_mfma_f32_16x16x32_f16(
        __builtin_bit_cast(f16x8, a), __builtin_bit_cast(f16x8, b), c, 0, 0, 0);
}

DEV u16 f2h(float x) { return __builtin_bit_cast(u16, (_Float16)x); }
DEV float h2f(u16 h) { return (float)__builtin_bit_cast(_Float16, h); }

DEV u32 pkh(float a, float b) {
#if __has_builtin(__builtin_amdgcn_cvt_pkrtz)
    auto r = __builtin_amdgcn_cvt_pkrtz(a, b);
    return __builtin_bit_cast(u32, r);
#else
    return (u32)f2h(a) | ((u32)f2h(b) << 16);
#endif
}

DEV float fexp2(float x) {
#if __has_builtin(__builtin_amdgcn_exp2f)
    return __builtin_amdgcn_exp2f(x);
#else
    return exp2f(x);
#endif
}

DEV void swap32(int lane, u32 a, u32 b, u32& o0, u32& o1) {
#if __has_builtin(__builtin_amdgcn_permlane32_swap)
    auto r = __builtin_amdgcn_permlane32_swap((int)a, (int)b, false, false);
    o0 = (u32)r[0]; o1 = (u32)r[1];
#else
    u32 ax = (u32)__shfl_xor((int)a, 32);
    u32 bx = (u32)__shfl_xor((int)b, 32);
    bool hi = (lane & 32) != 0;
    o0 = hi ? bx : a;
    o1 = hi ? b : ax;
#endif
}
DEV void swap16(int lane, u32 a, u32 b, u32& o0, u32& o1) {
#if __has_builtin(__builtin_amdgcn_permlane16_swap)
    auto r = __builtin_amdgcn_permlane16_swap((int)a, (int)b, false, false);
    o0 = (u32)r[0]; o1 = (u32)r[1];
#else
    u32 ax = (u32)__shfl_xor((int)a, 16);
    u32 bx = (u32)__shfl_xor((int)b, 16);
    bool hi = (lane & 16) != 0;
    o0 = hi ? bx : a;
    o1 = hi ? b : ax;
#endif
}

DEV void gl_lds16(const void* g, void* l) {
    __builtin_amdgcn_global_load_lds(
        (__attribute__((address_space(1))) void*)(void*)g,
        (__attribute__((address_space(3))) void*)l, 16, 0, 0);
}

// raw barrier pair (rule #18: sched_barrier fences around inline-asm waits)
DEV void vm0_bar() {
    __builtin_amdgcn_sched_barrier(0);
    asm volatile("s_waitcnt vmcnt(0)" ::: "memory");
    __builtin_amdgcn_s_barrier();
    __builtin_amdgcn_sched_barrier(0);
}

// rows of 128B, 16B slots XOR-swizzled by row&7
DEV s16x8 lds_ld16(const u16* base, int row, int kbyte) {
    return *(const s16x8*)((const char*)base + row * 128 + (kbyte ^ ((row & 7) << 4)));
}
// rows of 64B, 16B slots XOR-swizzled by row&3
DEV s16x8 lds_ld32r(const u16* base, int row, int g) {
    return *(const s16x8*)((const char*)base + row * 64 + ((g * 16) ^ ((row & 3) << 4)));
}

// ------- fused prep: mask scan/compaction + W transposes + X convert -------
// block 0: detect_mask; blocks [1,3072]: Wqkv^T tiles; [3073,4096]: Wo^T tiles;
// [4097,5120]: X scale+convert (grid-stride x4). All independent.
__global__ __launch_bounds__(256) void prep_all(
    const float* __restrict__ qkv, const unsigned char* __restrict__ m,
    const float* __restrict__ Wqkv, const float* __restrict__ Wo,
    u16* __restrict__ Xh, u16* __restrict__ Wth, u16* __restrict__ Woth,
    float* __restrict__ pbias, int* __restrict__ pack_idx, int* __restrict__ cnt) {
    int bid = blockIdx.x;
    int tid = threadIdx.x;
    if (bid == 0) {
        // ---- mask: sniff dtype, build pack_idx/cnt + packed bias ----
        __shared__ int sb, sf;
        __shared__ int scan[256];
        if (tid == 0) { sb = 0; sf = 0; }
        __syncthreads();
        int lb = 0, lf = 0;
        for (int i = tid * 16; i < tid * 16 + 16; i++) {
            unsigned char v = m[i];
            int pos = i & 3;
            if (pos == 3 && v == 0x3f) lf = 1;
            if (pos != 0 && v != 0) lb = 1;
        }
        if (lb) atomicOr(&sb, 1);
        if (lf) atomicOr(&sf, 1);
        __syncthreads();
        int f = sf ? 2 : (sb ? 1 : 0);
#pragma unroll
        for (int b = 0; b < BATCH; b++) {
            int base = b * SEQ;
            int keep[8], lc = 0;
#pragma unroll
            for (int e = 0; e < 8; e++) {
                int i = base + tid * 8 + e;
                int mv;
                if (f == 0) mv = ((const int*)m)[i] != 0;
                else if (f == 1) mv = m[i] != 0;
                else mv = ((const float*)m)[i] != 0.0f;
                keep[e] = !mv;
                lc += keep[e];
            }
            scan[tid] = lc;
            __syncthreads();
            for (int s = 1; s < 256; s <<= 1) {
                int v = (tid >= s) ? scan[tid - s] : 0;
                __syncthreads();
                scan[tid] += v;
                __syncthreads();
            }
            int off = scan[tid] - lc;
            int total = scan[255];
            __syncthreads();  // scan reused next batch
#pragma unroll
            for (int e = 0; e < 8; e++)
                if (keep[e]) pack_idx[base + off++] = base + tid * 8 + e;
            if (tid == 0) cnt[b] = total;
            for (int j = tid; j < SEQ; j += 256)
                pbias[base + j] = (j < total) ? 0.0f : -1e30f;
        }
    } else if (bid <= 3072 + 1024) {
        // ---- transpose tile: in[K][N] fp32 -> out[N][K] fp16 (scaled) ----
        const float* in;
        u16* oh;
        int N, t;
        float scale;
        if (bid <= 3072) { in = Wqkv; oh = Wth; N = 3072; t = bid - 1; scale = SCALE_XW; }
        else { in = Wo; oh = Woth; N = 1024; t = bid - 3073; scale = 1.0f; }
        const int K = 1024;
        int ntiles = N >> 5;
        int n0 = (t % ntiles) * 32, k0 = (t / ntiles) * 32;
        __shared__ float tt[32][33];
        int tx = tid & 31, ty = tid >> 5;
#pragma unroll
        for (int i = 0; i < 4; i++)
            tt[ty + 8 * i][tx] = in[(size_t)(k0 + ty + 8 * i) * N + n0 + tx];
        __syncthreads();
#pragma unroll
        for (int i = 0; i < 4; i++) {
            float v = tt[tx][ty + 8 * i] * scale;
            size_t o = (size_t)(n0 + ty + 8 * i) * K + k0 + tx;
            oh[o] = f2h(v);
        }
    } else {
        // ---- X: scale+convert fp32 -> fp16, 4 chunks grid-stride ----
        int cb = bid - 3073 - 1024;  // 0..1023
#pragma unroll
        for (int it = 0; it < 4; it++) {
            int i = ((cb + it * 1024) * 256 + tid) * 4;
            f32x4 v = *(const f32x4*)&qkv[i];
            u16x4 h;
#pragma unroll
            for (int e = 0; e < 4; e++) h[e] = f2h(v[e] * SCALE_XW);
            *(u16x4*)&Xh[i] = h;
        }
    }
}

// ------- GEMM1: Xh @ Wh fp16 1-PASS, BK=32, single-buf 16KB (R11-proven schedule) -------
__global__ __launch_bounds__(256, 3) void gemm_qkv(
    const u16* __restrict__ Xh,
    const u16* __restrict__ Wth,
    const float* __restrict__ bqkv,
    const int* __restrict__ pack_idx, const int* __restrict__ cnt,
    u16* __restrict__ qh,
    u16* __restrict__ kh,
    u16* __restrict__ vt) {
    __shared__ __align__(16) u16 SM[2][128 * 32];  // 16 KB single buffer (X, W)
    __shared__ __align__(16) u16 T[64 * 140];      // 17.5 KB V-transpose scratch
    int tid = threadIdx.x, lane = tid & 63, w = tid >> 6;
    int g = lane >> 4, q15 = lane & 15;
    int wm = w >> 1, wn = w & 1;
    int m0 = blockIdx.y * 128, n0 = blockIdx.x * 128;
    int part = n0 >> 10;
    int bb = m0 >> 11;
    int cb = cnt[bb];
    if (part != 0 && (m0 & 2047) >= cb) return;  // packed rows all beyond count

    int srcrow[2];
#pragma unroll
    for (int i = 0; i < 2; i++) {
        int r = m0 + ((i * 256 + tid) >> 2);
        srcrow[i] = (part == 0) ? r : (((r & 2047) < cb) ? pack_idx[r] : (bb << 11));
    }

    f32x4 acc[4][4];
#pragma unroll
    for (int i = 0; i < 4; i++)
#pragma unroll
        for (int j = 0; j < 4; j++) acc[i][j] = (f32x4){0.f, 0.f, 0.f, 0.f};

    auto STAGE = [&](int kt) {
        int k0 = kt * 32;
#pragma unroll
        for (int i = 0; i < 2; i++) {
            int c = i * 256 + tid;
            int row = c >> 2, slot = c & 3;
            int sg = slot ^ (row & 3);
            int dst = (c & ~63) * 8;
            size_t ga = (size_t)srcrow[i] * 1024 + k0 + sg * 8;
            size_t gb = (size_t)(n0 + row) * 1024 + k0 + sg * 8;
            gl_lds16(&Xh[ga], &SM[0][dst]);
            gl_lds16(&Wth[gb], &SM[1][dst]);
        }
    };

    STAGE(0);
    for (int kt = 0; kt < 32; kt++) {
        vm0_bar();  // stage for kt complete on all waves
        s16x8 a_h[4], b_h[4];
#pragma unroll
        for (int i = 0; i < 4; i++) {
            a_h[i] = lds_ld32r(SM[0], wm * 64 + i * 16 + q15, g);
            b_h[i] = lds_ld32r(SM[1], wn * 64 + i * 16 + q15, g);
        }
        __syncthreads();  // all waves' reads retired -> buffer reusable
        if (kt < 31) STAGE(kt + 1);
#pragma unroll
        for (int mi = 0; mi < 4; mi++)
#pragma unroll
            for (int ni = 0; ni < 4; ni++)
                acc[mi][ni] = mfmah(a_h[mi], b_h[ni], acc[mi][ni]);
    }

    if (part == 2) {
        const int TP = 140;
#pragma unroll
        for (int h2 = 0; h2 < 2; h2++) {
            __syncthreads();
            if (wn == h2) {
#pragma unroll
                for (int mi = 0; mi < 4; mi++)
#pragma unroll
                    for (int ni = 0; ni < 4; ni++) {
                        int lcol = ni * 16 + q15;  // 0..63 within half
#pragma unroll
                        for (int j = 0; j < 4; j++) {
                            int lrow = wm * 64 + mi * 16 + g * 4 + j;
                            T[lcol * TP + lrow] =
                                f2h(acc[mi][ni][j] * INV_PROJ + bqkv[n0 + h2 * 64 + lcol]);
                        }
                    }
            }
            __syncthreads();
            int lcol = tid >> 2;  // 0..63
            int seg = tid & 3;
            int c = n0 - 2048 + h2 * 64 + lcol;
            int h = c >> 6, d = c & 63;
            int b = m0 >> 11, sbase = m0 & 2047;
            size_t rowbase = ((size_t)(b * NH + h) * HD + d) * SEQ + sbase;
#pragma unroll
            for (int k = 0; k < 2; k++) {
                int slot = seg * 2 + k;  // 8 slots x 16 rows = 128
                *(s16x8*)&vt[rowbase + slot * 16 + 0] = *(const s16x8*)&T[lcol * TP + slot * 16 + 0];
                *(s16x8*)&vt[rowbase + slot * 16 + 8] = *(const s16x8*)&T[lcol * TP + slot * 16 + 8];
            }
        }
    } else {
#pragma unroll
        for (int mi = 0; mi < 4; mi++)
#pragma unroll
            for (int ni = 0; ni < 4; ni++) {
                int col = n0 + wn * 64 + ni * 16 + q15;
                float bias = bqkv[col];
                int cc = col & 1023, h = cc >> 6, d = cc & 63;
#pragma unroll
                for (int j = 0; j < 4; j++) {
                    int row = m0 + wm * 64 + mi * 16 + g * 4 + j;
                    int b = row >> 11, s = row & 2047;  // s: packed for K, true for Q
                    float v = acc[mi][ni][j] * INV_PROJ + bias;
                    v *= (part == 0) ? SCALE_Q : SCALE_K;
                    size_t o = (size_t)(b * NH + h) * SEQ * HD + (size_t)s * HD + d;
                    if (part == 0) qh[o] = f2h(v);
                    else kh[o] = f2h(v);
                }
            }
    }
}

// ------ flash attention over PACKED keys, 2 q-groups/wave ------
// R16: log2-domain scores direct from MFMA (scale folded into q); mask bias
// enters as MFMA C-in — the 32-FMA rescale pass per iter is deleted.
__global__ __launch_bounds__(256, 2) void attn_kernel(
    const u16* __restrict__ qh,
    const u16* __restrict__ kh,
    const u16* __restrict__ vt, const float* __restrict__ pbias,
    const int* __restrict__ cnt,
    u16* __restrict__ att) {
    __shared__ __align__(16) u16 Kh[2][4096], Vt[2][4096];  // 32 KB
    __shared__ __align__(16) float MskB[2][64];
    int tid = threadIdx.x, lane = tid & 63, w = tid >> 6;
    int g = lane >> 4, q15 = lane & 15;
    int bid = blockIdx.y * 16 + blockIdx.x;
    int swz = (bid & 7) * 64 + (bid >> 3);  // bijective: 512 % 8 == 0
    int qt = swz & 15, bh = swz >> 4;
    int b = bh >> 4, h = bh & 15;
    int q0 = qt * 128;
    int NT = (cnt[b] + 63) >> 6;  // packed key tiles
    size_t base = (size_t)bh * SEQ * HD;
    const u16* vbase = vt + (size_t)bh * HD * SEQ;
    const float* mrow = pbias + b * SEQ;

    // Q fragments, 2 groups of 16 rows (k-map: k = k2*32 + g*8 + e)
    s16x8 aq[2][2];
#pragma unroll
    for (int grp = 0; grp < 2; grp++)
#pragma unroll
        for (int k2 = 0; k2 < 2; k2++) {
            size_t o = base + (size_t)(q0 + w * 32 + grp * 16 + q15) * HD + k2 * 32 + g * 8;
            aq[grp][k2] = *(const s16x8*)&qh[o];
        }

    float m_[2] = {-1e30f, -1e30f}, l_[2] = {0.f, 0.f};  // lane-partial l
    f32x4 o_[2][4];
#pragma unroll
    for (int grp = 0; grp < 2; grp++)
#pragma unroll
        for (int df = 0; df < 4; df++) o_[grp][df] = (f32x4){0.f, 0.f, 0.f, 0.f};

    auto STAGE = [&](int buf, int k0) {
#pragma unroll
        for (int i = 0; i < 2; i++) {
            int c = i * 256 + tid;
            int row = c >> 3, slot = c & 7;
            int sg = slot ^ (row & 7);
            int dst = (c & ~63) * 8;
            size_t gK = base + (size_t)(k0 + row) * HD + sg * 8;
            gl_lds16(&kh[gK], &Kh[buf][dst]);
            size_t gV = (size_t)row * SEQ + k0 + sg * 8;
            gl_lds16(&vbase[gV], &Vt[buf][dst]);
        }
        if (tid < 16) gl_lds16(&mrow[k0 + tid * 4], &MskB[buf][0]);
    };

    STAGE(0, 0);
    __syncthreads();

    for (int kt = 0; kt < NT; kt++) {
        int cur = kt & 1;
        if (kt < NT - 1) STAGE(cur ^ 1, (kt + 1) * 64);

        // swapped QK^T both groups: D[k][q], k = nf*16 + g*4 + j, q = q15.
        // C-in = mask bias (log2-domain scores come out of the MFMA directly).
        f32x4 sc0[4], sc1[4];
#pragma unroll
        for (int nf = 0; nf < 4; nf++) {
            f32x4 mb = *(const f32x4*)&MskB[cur][nf * 16 + g * 4];
            sc0[nf] = mb;
            sc1[nf] = mb;
        }
#pragma unroll
        for (int nf = 0; nf < 4; nf++) {
#pragma unroll
            for (int k2 = 0; k2 < 2; k2++) {
                int kb = k2 * 64 + g * 16;
                s16x8 kbh = lds_ld16(Kh[cur], nf * 16 + q15, kb);
                sc0[nf] = mfmah(kbh, aq[0][k2], sc0[nf]);
                sc1[nf] = mfmah(kbh, aq[1][k2], sc1[nf]);
            }
        }

        s16x8 pa[2][2];
#pragma unroll
        for (int grp = 0; grp < 2; grp++) {
            f32x4* sc = grp ? sc1 : sc0;
            float pml = -1e30f;
#pragma unroll
            for (int nf = 0; nf < 4; nf++) {
                float a = fmaxf(sc[nf][0], sc[nf][1]);
                float bmx = fmaxf(sc[nf][2], sc[nf][3]);
                pml = fmaxf(pml, fmaxf(a, bmx));
            }
            // defer-max: skip rescale while tile max stays within THR of running max
            if (!__all(pml - m_[grp] <= DEFER_THR)) {
                float pm = fmaxf(pml, __shfl_xor(pml, 16));
                pm = fmaxf(pm, __shfl_xor(pm, 32));
                float mn = fmaxf(m_[grp], pm);
                float scl = fexp2(m_[grp] - mn);
                m_[grp] = mn;
                l_[grp] *= scl;
#pragma unroll
                for (int j = 0; j < 4; j++) {
                    float sb = __shfl(scl, g * 4 + j);
#pragma unroll
                    for (int df = 0; df < 4; df++) o_[grp][df][j] *= sb;
                }
            }
            float p[4][4];
            float rs = 0.f;
#pragma unroll
            for (int nf = 0; nf < 4; nf++)
#pragma unroll
                for (int j = 0; j < 4; j++) {
                    float pv = fexp2(sc[nf][j] - m_[grp]);
                    p[nf][j] = pv;
                    rs += pv;
                }
            l_[grp] += rs;  // lane-partial
            // in-register P repack: pa[k2] elem e = P[q15][k2*32 + g*8 + e]
#pragma unroll
            for (int k2 = 0; k2 < 2; k2++) {
                u32 A0 = pkh(p[2 * k2][0], p[2 * k2][1]);
                u32 A1 = pkh(p[2 * k2][2], p[2 * k2][3]);
                u32 B0 = pkh(p[2 * k2 + 1][0], p[2 * k2 + 1][1]);
                u32 B1 = pkh(p[2 * k2 + 1][2], p[2 * k2 + 1][3]);
                u32 s0, s1, t0, t1, w0, w1, w2, w3;
                swap32(lane, A0, B0, s0, s1);
                swap16(lane, s0, s1, w0, w2);
                swap32(lane, A1, B1, t0, t1);
                swap16(lane, t0, t1, w1, w3);
                u32x4 words = {w0, w1, w2, w3};
                pa[grp][k2] = __builtin_bit_cast(s16x8, words);
            }
        }

        // PV: O[q][d] += P[q][k] * V^T[d][k]  (vb shared by both groups)
#pragma unroll
        for (int k2 = 0; k2 < 2; k2++) {
            int kb = k2 * 64 + g * 16;
#pragma unroll
            for (int df = 0; df < 4; df++) {
                s16x8 vb = lds_ld16(Vt[cur], df * 16 + q15, kb);
                o_[0][df] = mfmah(pa[0][k2], vb, o_[0][df]);
                o_[1][df] = mfmah(pa[1][k2], vb, o_[1][df]);
            }
        }
        __syncthreads();
    }

#pragma unroll
    for (int grp = 0; grp < 2; grp++) {
        float lt = l_[grp];
        lt += __shfl_xor(lt, 16);
        lt += __shfl_xor(lt, 32);
#pragma unroll
        for (int j = 0; j < 4; j++) {
            float lb = __shfl(lt, g * 4 + j);
            float linv = __builtin_amdgcn_rcpf(lb);
            int qrow = q0 + w * 32 + grp * 16 + g * 4 + j;
            size_t srow = (size_t)(b * SEQ + qrow);
#pragma unroll
            for (int df = 0; df < 4; df++) {
                int col = h * HD + df * 16 + q15;
                att[srow * HID + col] = f2h(o_[grp][df][j] * linv);
            }
        }
    }
}

// ---------------- GEMM2: att fp16 @ Wo fp16 (1 pass), 64x128 tiles, BK=32 dbuf -----
__global__ __launch_bounds__(256, 4) void gemm_out(
    const u16* __restrict__ A, const u16* __restrict__ Bh0,
    const float* __restrict__ bo, float* __restrict__ out) {
    __shared__ __align__(16) u16 SMa[2][64 * 32], SMb[2][128 * 32];  // 24 KB
    int tid = threadIdx.x, lane = tid & 63, w = tid >> 6;
    int g = lane >> 4, q15 = lane & 15;
    int wm = w >> 1, wn = w & 1;
    int m0 = blockIdx.y * 64, n0 = blockIdx.x * 128;
    f32x4 acc[2][4];
#pragma unroll
    for (int i = 0; i < 2; i++)
#pragma unroll
        for (int j = 0; j < 4; j++) acc[i][j] = (f32x4){0.f, 0.f, 0.f, 0.f};

    auto STAGE = [&](int db, int kt) {
        int k0 = kt * 32;
        {
            int c = tid;
            int row = c >> 2, slot = c & 3;
            int sg = slot ^ (row & 3);
            int dst = (c & ~63) * 8;
            gl_lds16(&A[(size_t)(m0 + row) * 1024 + k0 + sg * 8], &SMa[db][dst]);
        }
#pragma unroll
        for (int i = 0; i < 2; i++) {
            int c = i * 256 + tid;
            int row = c >> 2, slot = c & 3;
            int sg = slot ^ (row & 3);
            int dst = (c & ~63) * 8;
            gl_lds16(&Bh0[(size_t)(n0 + row) * 1024 + k0 + sg * 8], &SMb[db][dst]);
        }
    };

    STAGE(0, 0);
    for (int kt = 0; kt < 32; kt++) {
        int cur = kt & 1;
        __syncthreads();
        if (kt < 31) STAGE(cur ^ 1, kt + 1);
        s16x8 a_[2], b_[4];
#pragma unroll
        for (int i = 0; i < 2; i++)
            a_[i] = lds_ld32r(SMa[cur], wm * 32 + i * 16 + q15, g);
#pragma unroll
        for (int i = 0; i < 4; i++)
            b_[i] = lds_ld32r(SMb[cur], wn * 64 + i * 16 + q15, g);
#pragma unroll
        for (int mi = 0; mi < 2; mi++)
#pragma unroll
            for (int ni = 0; ni < 4; ni++)
                acc[mi][ni] = mfmah(a_[mi], b_[ni], acc[mi][ni]);
    }
#pragma unroll
    for (int mi = 0; mi < 2; mi++)
#pragma unroll
        for (int ni = 0; ni < 4; ni++) {
            int col = n0 + wn * 64 + ni * 16 + q15;
            float bias = bo[col];
#pragma unroll
            for (int j = 0; j < 4; j++) {
                int row = m0 + wm * 32 + mi * 16 + g * 4 + j;
                out[(size_t)row * 1024 + col] = acc[mi][ni][j] + bias;
            }
        }
}

extern "C" void kernel_launch(void* const* d_in, const int* in_sizes, int n_in,
                              void* d_out, int out_size, void* d_ws, size_t ws_size,
                              hipStream_t stream) {
    const float* qkv = (const float*)d_in[0];
    const void* mask = d_in[1];
    const float* Wqkv = (const float*)d_in[2];
    const float* bqkv = (const float*)d_in[3];
    const float* Wo = (const float*)d_in[4];
    const float* bo = (const float*)d_in[5];
    float* out = (float*)d_out;

    const size_t SZ_X = (size_t)4096 * 1024 * 2;       // 8 MB
    const size_t SZ_W = (size_t)3072 * 1024 * 2;       // 6 MB
    const size_t SZ_WO = (size_t)1024 * 1024 * 2;      // 2 MB
    const size_t SZ_QKV = (size_t)32 * 2048 * 64 * 2;  // 8 MB
    const size_t SZ_ATT = (size_t)4096 * 1024 * 2;     // 8 MB

    char* p = (char*)d_ws;
    u16* Xh = (u16*)p; p += SZ_X;
    u16* Wth = (u16*)p; p += SZ_W;
    u16* Woth = (u16*)p; p += SZ_WO;
    u16* qh = (u16*)p; p += SZ_QKV;
    u16* kh = (u16*)p; p += SZ_QKV;
    u16* vt = (u16*)p; p += SZ_QKV;  // [bh][d][s_packed]
    u16* att = (u16*)p; p += SZ_ATT;
    float* pbias = (float*)p; p += BATCH * SEQ * 4;
    int* pack_idx = (int*)p; p += BATCH * SEQ * 4;
    int* cnt = (int*)p; p += 256;

    prep_all<<<1 + 3072 + 1024 + 1024, 256, 0, stream>>>(
        qkv, (const unsigned char*)mask, Wqkv, Wo, Xh, Wth, Woth, pbias, pack_idx, cnt);
    gemm_qkv<<<dim3(24, 32), 256, 0, stream>>>(Xh, Wth, bqkv, pack_idx, cnt, qh, kh, vt);
    attn_kernel<<<dim3(16, 32), 256, 0, stream>>>(qh, kh, vt, pbias, cnt, att);
    gemm_out<<<dim3(8, 64), 256, 0, stream>>>(att, Woth, bo, out);
}

// Round 18
// 99.660 us; speedup vs baseline: 1.4101x; 1.0348x over previous
//
#include <hip/hip_runtime.h>

#define DEV __device__ __forceinline__

typedef unsigned short u16;
typedef unsigned int u32;
typedef __attribute__((ext_vector_type(4))) float f32x4;
typedef __attribute__((ext_vector_type(8))) short s16x8;
typedef __attribute__((ext_vector_type(8))) _Float16 f16x8;
typedef __attribute__((ext_vector_type(4))) unsigned short u16x4;
typedef __attribute__((ext_vector_type(4))) unsigned int u32x4;

#define BATCH 2
#define SEQ 2048
#define HID 1024
#define NH 16
#define HD 64

// scaling:  X' = 64*X, W' = 64*W -> proj = acc/4096
//  q stored = proj_q * 8*log2e (log2-domain scores direct from MFMA), k stored = proj_k
//  mask bias enters as the QK MFMA C-in (no post-FMA pass)
#define SCALE_XW 64.0f
#define INV_PROJ (1.0f / 4096.0f)
#define SCALE_Q 11.541560327111707f
#define SCALE_K 1.0f
#define DEFER_THR 10.0f

DEV f32x4 mfmah(s16x8 a, s16x8 b, f32x4 c) {
    return __builtin_amdgcn_mfma_f32_16x16x32_f16(
        __builtin_bit_cast(f16x8, a), __builtin_bit_cast(f16x8, b), c, 0, 0, 0);
}

DEV u16 f2h(float x) { return __builtin_bit_cast(u16, (_Float16)x); }
DEV float h2f(u16 h) { return (float)__builtin_bit_cast(_Float16, h); }

DEV u32 pkh(float a, float b) {
#if __has_builtin(__builtin_amdgcn_cvt_pkrtz)
    auto r = __builtin_amdgcn_cvt_pkrtz(a, b);
    return __builtin_bit_cast(u32, r);
#else
    return (u32)f2h(a) | ((u32)f2h(b) << 16);
#endif
}

DEV float fexp2(float x) {
#if __has_builtin(__builtin_amdgcn_exp2f)
    return __builtin_amdgcn_exp2f(x);
#else
    return exp2f(x);
#endif
}

DEV void swap32(int lane, u32 a, u32 b, u32& o0, u32& o1) {
#if __has_builtin(__builtin_amdgcn_permlane32_swap)
    auto r = __builtin_amdgcn_permlane32_swap((int)a, (int)b, false, false);
    o0 = (u32)r[0]; o1 = (u32)r[1];
#else
    u32 ax = (u32)__shfl_xor((int)a, 32);
    u32 bx = (u32)__shfl_xor((int)b, 32);
    bool hi = (lane & 32) != 0;
    o0 = hi ? bx : a;
    o1 = hi ? b : ax;
#endif
}
DEV void swap16(int lane, u32 a, u32 b, u32& o0, u32& o1) {
#if __has_builtin(__builtin_amdgcn_permlane16_swap)
    auto r = __builtin_amdgcn_permlane16_swap((int)a, (int)b, false, false);
    o0 = (u32)r[0]; o1 = (u32)r[1];
#else
    u32 ax = (u32)__shfl_xor((int)a, 16);
    u32 bx = (u32)__shfl_xor((int)b, 16);
    bool hi = (lane & 16) != 0;
    o0 = hi ? bx : a;
    o1 = hi ? b : ax;
#endif
}

DEV void gl_lds16(const void* g, void* l) {
    __builtin_amdgcn_global_load_lds(
        (__attribute__((address_space(1))) void*)(void*)g,
        (__attribute__((address_space(3))) void*)l, 16, 0, 0);
}

// raw barrier pair (rule #18: sched_barrier fences around inline-asm waits)
DEV void vm0_bar() {
    __builtin_amdgcn_sched_barrier(0);
    asm volatile("s_waitcnt vmcnt(0)" ::: "memory");
    __builtin_amdgcn_s_barrier();
    __builtin_amdgcn_sched_barrier(0);
}

// rows of 128B, 16B slots XOR-swizzled by row&7
DEV s16x8 lds_ld16(const u16* base, int row, int kbyte) {
    return *(const s16x8*)((const char*)base + row * 128 + (kbyte ^ ((row & 7) << 4)));
}
// rows of 64B, 16B slots XOR-swizzled by row&3
DEV s16x8 lds_ld32r(const u16* base, int row, int g) {
    return *(const s16x8*)((const char*)base + row * 64 + ((g * 16) ^ ((row & 3) << 4)));
}

// ------- fused prep: mask scan/compaction + W transposes + X convert -------
__global__ __launch_bounds__(256) void prep_all(
    const float* __restrict__ qkv, const unsigned char* __restrict__ m,
    const float* __restrict__ Wqkv, const float* __restrict__ Wo,
    u16* __restrict__ Xh, u16* __restrict__ Wth, u16* __restrict__ Woth,
    float* __restrict__ pbias, int* __restrict__ pack_idx, int* __restrict__ cnt) {
    int bid = blockIdx.x;
    int tid = threadIdx.x;
    if (bid == 0) {
        __shared__ int sb, sf;
        __shared__ int scan[256];
        if (tid == 0) { sb = 0; sf = 0; }
        __syncthreads();
        int lb = 0, lf = 0;
        for (int i = tid * 16; i < tid * 16 + 16; i++) {
            unsigned char v = m[i];
            int pos = i & 3;
            if (pos == 3 && v == 0x3f) lf = 1;
            if (pos != 0 && v != 0) lb = 1;
        }
        if (lb) atomicOr(&sb, 1);
        if (lf) atomicOr(&sf, 1);
        __syncthreads();
        int f = sf ? 2 : (sb ? 1 : 0);
#pragma unroll
        for (int b = 0; b < BATCH; b++) {
            int base = b * SEQ;
            int keep[8], lc = 0;
#pragma unroll
            for (int e = 0; e < 8; e++) {
                int i = base + tid * 8 + e;
                int mv;
                if (f == 0) mv = ((const int*)m)[i] != 0;
                else if (f == 1) mv = m[i] != 0;
                else mv = ((const float*)m)[i] != 0.0f;
                keep[e] = !mv;
                lc += keep[e];
            }
            scan[tid] = lc;
            __syncthreads();
            for (int s = 1; s < 256; s <<= 1) {
                int v = (tid >= s) ? scan[tid - s] : 0;
                __syncthreads();
                scan[tid] += v;
                __syncthreads();
            }
            int off = scan[tid] - lc;
            int total = scan[255];
            __syncthreads();  // scan reused next batch
#pragma unroll
            for (int e = 0; e < 8; e++)
                if (keep[e]) pack_idx[base + off++] = base + tid * 8 + e;
            if (tid == 0) cnt[b] = total;
            for (int j = tid; j < SEQ; j += 256)
                pbias[base + j] = (j < total) ? 0.0f : -1e30f;
        }
    } else if (bid <= 3072 + 1024) {
        const float* in;
        u16* oh;
        int N, t;
        float scale;
        if (bid <= 3072) { in = Wqkv; oh = Wth; N = 3072; t = bid - 1; scale = SCALE_XW; }
        else { in = Wo; oh = Woth; N = 1024; t = bid - 3073; scale = 1.0f; }
        const int K = 1024;
        int ntiles = N >> 5;
        int n0 = (t % ntiles) * 32, k0 = (t / ntiles) * 32;
        __shared__ float tt[32][33];
        int tx = tid & 31, ty = tid >> 5;
#pragma unroll
        for (int i = 0; i < 4; i++)
            tt[ty + 8 * i][tx] = in[(size_t)(k0 + ty + 8 * i) * N + n0 + tx];
        __syncthreads();
#pragma unroll
        for (int i = 0; i < 4; i++) {
            float v = tt[tx][ty + 8 * i] * scale;
            size_t o = (size_t)(n0 + ty + 8 * i) * K + k0 + tx;
            oh[o] = f2h(v);
        }
    } else {
        int cb = bid - 3073 - 1024;  // 0..1023
#pragma unroll
        for (int it = 0; it < 4; it++) {
            int i = ((cb + it * 1024) * 256 + tid) * 4;
            f32x4 v = *(const f32x4*)&qkv[i];
            u16x4 h;
#pragma unroll
            for (int e = 0; e < 4; e++) h[e] = f2h(v[e] * SCALE_XW);
            *(u16x4*)&Xh[i] = h;
        }
    }
}

// ------- GEMM1: Xh @ Wh fp16 1-PASS, BK=32, single-buf 16KB (R11-proven schedule) -------
__global__ __launch_bounds__(256, 3) void gemm_qkv(
    const u16* __restrict__ Xh,
    const u16* __restrict__ Wth,
    const float* __restrict__ bqkv,
    const int* __restrict__ pack_idx, const int* __restrict__ cnt,
    u16* __restrict__ qh,
    u16* __restrict__ kh,
    u16* __restrict__ vt) {
    __shared__ __align__(16) u16 SM[2][128 * 32];  // 16 KB single buffer (X, W)
    __shared__ __align__(16) u16 T[64 * 140];      // 17.5 KB V-transpose scratch
    int tid = threadIdx.x, lane = tid & 63, w = tid >> 6;
    int g = lane >> 4, q15 = lane & 15;
    int wm = w >> 1, wn = w & 1;
    int m0 = blockIdx.y * 128, n0 = blockIdx.x * 128;
    int part = n0 >> 10;
    int bb = m0 >> 11;
    int cb = cnt[bb];
    if (part != 0 && (m0 & 2047) >= cb) return;  // packed rows all beyond count

    int srcrow[2];
#pragma unroll
    for (int i = 0; i < 2; i++) {
        int r = m0 + ((i * 256 + tid) >> 2);
        srcrow[i] = (part == 0) ? r : (((r & 2047) < cb) ? pack_idx[r] : (bb << 11));
    }

    f32x4 acc[4][4];
#pragma unroll
    for (int i = 0; i < 4; i++)
#pragma unroll
        for (int j = 0; j < 4; j++) acc[i][j] = (f32x4){0.f, 0.f, 0.f, 0.f};

    auto STAGE = [&](int kt) {
        int k0 = kt * 32;
#pragma unroll
        for (int i = 0; i < 2; i++) {
            int c = i * 256 + tid;
            int row = c >> 2, slot = c & 3;
            int sg = slot ^ (row & 3);
            int dst = (c & ~63) * 8;
            size_t ga = (size_t)srcrow[i] * 1024 + k0 + sg * 8;
            size_t gb = (size_t)(n0 + row) * 1024 + k0 + sg * 8;
            gl_lds16(&Xh[ga], &SM[0][dst]);
            gl_lds16(&Wth[gb], &SM[1][dst]);
        }
    };

    STAGE(0);
    for (int kt = 0; kt < 32; kt++) {
        vm0_bar();  // stage for kt complete on all waves
        s16x8 a_h[4], b_h[4];
#pragma unroll
        for (int i = 0; i < 4; i++) {
            a_h[i] = lds_ld32r(SM[0], wm * 64 + i * 16 + q15, g);
            b_h[i] = lds_ld32r(SM[1], wn * 64 + i * 16 + q15, g);
        }
        __syncthreads();  // all waves' reads retired -> buffer reusable
        if (kt < 31) STAGE(kt + 1);
#pragma unroll
        for (int mi = 0; mi < 4; mi++)
#pragma unroll
            for (int ni = 0; ni < 4; ni++)
                acc[mi][ni] = mfmah(a_h[mi], b_h[ni], acc[mi][ni]);
    }

    if (part == 2) {
        const int TP = 140;
#pragma unroll
        for (int h2 = 0; h2 < 2; h2++) {
            __syncthreads();
            if (wn == h2) {
#pragma unroll
                for (int mi = 0; mi < 4; mi++)
#pragma unroll
                    for (int ni = 0; ni < 4; ni++) {
                        int lcol = ni * 16 + q15;  // 0..63 within half
#pragma unroll
                        for (int j = 0; j < 4; j++) {
                            int lrow = wm * 64 + mi * 16 + g * 4 + j;
                            T[lcol * TP + lrow] =
                                f2h(acc[mi][ni][j] * INV_PROJ + bqkv[n0 + h2 * 64 + lcol]);
                        }
                    }
            }
            __syncthreads();
            int lcol = tid >> 2;  // 0..63
            int seg = tid & 3;
            int c = n0 - 2048 + h2 * 64 + lcol;
            int h = c >> 6, d = c & 63;
            int b = m0 >> 11, sbase = m0 & 2047;
            size_t rowbase = ((size_t)(b * NH + h) * HD + d) * SEQ + sbase;
#pragma unroll
            for (int k = 0; k < 2; k++) {
                int slot = seg * 2 + k;  // 8 slots x 16 rows = 128
                *(s16x8*)&vt[rowbase + slot * 16 + 0] = *(const s16x8*)&T[lcol * TP + slot * 16 + 0];
                *(s16x8*)&vt[rowbase + slot * 16 + 8] = *(const s16x8*)&T[lcol * TP + slot * 16 + 8];
            }
        }
    } else {
#pragma unroll
        for (int mi = 0; mi < 4; mi++)
#pragma unroll
            for (int ni = 0; ni < 4; ni++) {
                int col = n0 + wn * 64 + ni * 16 + q15;
                float bias = bqkv[col];
                int cc = col & 1023, h = cc >> 6, d = cc & 63;
#pragma unroll
                for (int j = 0; j < 4; j++) {
                    int row = m0 + wm * 64 + mi * 16 + g * 4 + j;
                    int b = row >> 11, s = row & 2047;  // s: packed for K, true for Q
                    float v = acc[mi][ni][j] * INV_PROJ + bias;
                    v *= (part == 0) ? SCALE_Q : SCALE_K;
                    size_t o = (size_t)(b * NH + h) * SEQ * HD + (size_t)s * HD + d;
                    if (part == 0) qh[o] = f2h(v);
                    else kh[o] = f2h(v);
                }
            }
    }
}

// ------ flash attention over PACKED keys: 8 waves x 16 q-rows, 2-phase dbuf ------
// R17: 512-thread blocks -> 16 waves/CU (2x wave-level parallelism to interleave
// the per-wave QK->softmax->PV serial chain). Math identical to R16.
__global__ __launch_bounds__(512, 4) void attn_kernel(
    const u16* __restrict__ qh,
    const u16* __restrict__ kh,
    const u16* __restrict__ vt, const float* __restrict__ pbias,
    const int* __restrict__ cnt,
    u16* __restrict__ att) {
    __shared__ __align__(16) u16 Kh[2][4096], Vt[2][4096];  // 32 KB
    __shared__ __align__(16) float MskB[2][64];
    int tid = threadIdx.x, lane = tid & 63, w = tid >> 6;
    int g = lane >> 4, q15 = lane & 15;
    int bid = blockIdx.y * 16 + blockIdx.x;
    int swz = (bid & 7) * 64 + (bid >> 3);  // bijective: 512 % 8 == 0
    int qt = swz & 15, bh = swz >> 4;
    int b = bh >> 4, h = bh & 15;
    int q0 = qt * 128;
    int NT = (cnt[b] + 63) >> 6;  // packed key tiles
    size_t base = (size_t)bh * SEQ * HD;
    const u16* vbase = vt + (size_t)bh * HD * SEQ;
    const float* mrow = pbias + b * SEQ;

    // Q fragment, 16 rows per wave (k-map: k = k2*32 + g*8 + e)
    s16x8 aq[2];
#pragma unroll
    for (int k2 = 0; k2 < 2; k2++) {
        size_t o = base + (size_t)(q0 + w * 16 + q15) * HD + k2 * 32 + g * 8;
        aq[k2] = *(const s16x8*)&qh[o];
    }

    float m_ = -1e30f, l_ = 0.f;  // lane-partial l
    f32x4 o_[4];
#pragma unroll
    for (int df = 0; df < 4; df++) o_[df] = (f32x4){0.f, 0.f, 0.f, 0.f};

    auto STAGE = [&](int buf, int k0) {
        // 512 threads = 512 chunks: each thread 1 K-chunk + 1 V-chunk
        int row = tid >> 3, slot = tid & 7;
        int sg = slot ^ (row & 7);
        int dst = (tid & ~63) * 8;
        size_t gK = base + (size_t)(k0 + row) * HD + sg * 8;
        gl_lds16(&kh[gK], &Kh[buf][dst]);
        size_t gV = (size_t)row * SEQ + k0 + sg * 8;
        gl_lds16(&vbase[gV], &Vt[buf][dst]);
        if (tid < 16) gl_lds16(&mrow[k0 + tid * 4], &MskB[buf][0]);
    };

    STAGE(0, 0);
    __syncthreads();

    for (int kt = 0; kt < NT; kt++) {
        int cur = kt & 1;
        if (kt < NT - 1) STAGE(cur ^ 1, (kt + 1) * 64);

        // swapped QK^T: D[k][q], k = nf*16 + g*4 + j, q = q15.
        // C-in = mask bias (log2-domain scores direct from MFMA).
        f32x4 sc[4];
#pragma unroll
        for (int nf = 0; nf < 4; nf++)
            sc[nf] = *(const f32x4*)&MskB[cur][nf * 16 + g * 4];
#pragma unroll
        for (int nf = 0; nf < 4; nf++)
#pragma unroll
            for (int k2 = 0; k2 < 2; k2++) {
                int kb = k2 * 64 + g * 16;
                s16x8 kbh = lds_ld16(Kh[cur], nf * 16 + q15, kb);
                sc[nf] = mfmah(kbh, aq[k2], sc[nf]);
            }

        // per-lane softmax (row q = q15) with defer-max
        float pml = -1e30f;
#pragma unroll
        for (int nf = 0; nf < 4; nf++) {
            float a = fmaxf(sc[nf][0], sc[nf][1]);
            float bmx = fmaxf(sc[nf][2], sc[nf][3]);
            pml = fmaxf(pml, fmaxf(a, bmx));
        }
        if (!__all(pml - m_ <= DEFER_THR)) {
            float pm = fmaxf(pml, __shfl_xor(pml, 16));
            pm = fmaxf(pm, __shfl_xor(pm, 32));
            float mn = fmaxf(m_, pm);
            float scl = fexp2(m_ - mn);
            m_ = mn;
            l_ *= scl;
#pragma unroll
            for (int j = 0; j < 4; j++) {
                float sb = __shfl(scl, g * 4 + j);
#pragma unroll
                for (int df = 0; df < 4; df++) o_[df][j] *= sb;
            }
        }
        float p[4][4];
        float rs = 0.f;
#pragma unroll
        for (int nf = 0; nf < 4; nf++)
#pragma unroll
            for (int j = 0; j < 4; j++) {
                float pv = fexp2(sc[nf][j] - m_);
                p[nf][j] = pv;
                rs += pv;
            }
        l_ += rs;  // lane-partial
        // in-register P repack: pa[k2] elem e = P[q15][k2*32 + g*8 + e]
        s16x8 pa[2];
#pragma unroll
        for (int k2 = 0; k2 < 2; k2++) {
            u32 A0 = pkh(p[2 * k2][0], p[2 * k2][1]);
            u32 A1 = pkh(p[2 * k2][2], p[2 * k2][3]);
            u32 B0 = pkh(p[2 * k2 + 1][0], p[2 * k2 + 1][1]);
            u32 B1 = pkh(p[2 * k2 + 1][2], p[2 * k2 + 1][3]);
            u32 s0, s1, t0, t1, w0, w1, w2, w3;
            swap32(lane, A0, B0, s0, s1);
            swap16(lane, s0, s1, w0, w2);
            swap32(lane, A1, B1, t0, t1);
            swap16(lane, t0, t1, w1, w3);
            u32x4 words = {w0, w1, w2, w3};
            pa[k2] = __builtin_bit_cast(s16x8, words);
        }

        // PV: O[q][d] += P[q][k] * V^T[d][k]
#pragma unroll
        for (int k2 = 0; k2 < 2; k2++) {
            int kb = k2 * 64 + g * 16;
#pragma unroll
            for (int df = 0; df < 4; df++) {
                s16x8 vb = lds_ld16(Vt[cur], df * 16 + q15, kb);
                o_[df] = mfmah(pa[k2], vb, o_[df]);
            }
        }
        __syncthreads();
    }

    float lt = l_;
    lt += __shfl_xor(lt, 16);
    lt += __shfl_xor(lt, 32);
#pragma unroll
    for (int j = 0; j < 4; j++) {
        float lb = __shfl(lt, g * 4 + j);
        float linv = __builtin_amdgcn_rcpf(lb);
        int qrow = q0 + w * 16 + g * 4 + j;
        size_t srow = (size_t)(b * SEQ + qrow);
#pragma unroll
        for (int df = 0; df < 4; df++) {
            int col = h * HD + df * 16 + q15;
            att[srow * HID + col] = f2h(o_[df][j] * linv);
        }
    }
}

// ---------------- GEMM2: att fp16 @ Wo fp16 (1 pass), 64x128 tiles, BK=32 dbuf -----
__global__ __launch_bounds__(256, 4) void gemm_out(
    const u16* __restrict__ A, const u16* __restrict__ Bh0,
    const float* __restrict__ bo, float* __restrict__ out) {
    __shared__ __align__(16) u16 SMa[2][64 * 32], SMb[2][128 * 32];  // 24 KB
    int tid = threadIdx.x, lane = tid & 63, w = tid >> 6;
    int g = lane >> 4, q15 = lane & 15;
    int wm = w >> 1, wn = w & 1;
    int m0 = blockIdx.y * 64, n0 = blockIdx.x * 128;
    f32x4 acc[2][4];
#pragma unroll
    for (int i = 0; i < 2; i++)
#pragma unroll
        for (int j = 0; j < 4; j++) acc[i][j] = (f32x4){0.f, 0.f, 0.f, 0.f};

    auto STAGE = [&](int db, int kt) {
        int k0 = kt * 32;
        {
            int c = tid;
            int row = c >> 2, slot = c & 3;
            int sg = slot ^ (row & 3);
            int dst = (c & ~63) * 8;
            gl_lds16(&A[(size_t)(m0 + row) * 1024 + k0 + sg * 8], &SMa[db][dst]);
        }
#pragma unroll
        for (int i = 0; i < 2; i++) {
            int c = i * 256 + tid;
            int row = c >> 2, slot = c & 3;
            int sg = slot ^ (row & 3);
            int dst = (c & ~63) * 8;
            gl_lds16(&Bh0[(size_t)(n0 + row) * 1024 + k0 + sg * 8], &SMb[db][dst]);
        }
    };

    STAGE(0, 0);
    for (int kt = 0; kt < 32; kt++) {
        int cur = kt & 1;
        __syncthreads();
        if (kt < 31) STAGE(cur ^ 1, kt + 1);
        s16x8 a_[2], b_[4];
#pragma unroll
        for (int i = 0; i < 2; i++)
            a_[i] = lds_ld32r(SMa[cur], wm * 32 + i * 16 + q15, g);
#pragma unroll
        for (int i = 0; i < 4; i++)
            b_[i] = lds_ld32r(SMb[cur], wn * 64 + i * 16 + q15, g);
#pragma unroll
        for (int mi = 0; mi < 2; mi++)
#pragma unroll
            for (int ni = 0; ni < 4; ni++)
                acc[mi][ni] = mfmah(a_[mi], b_[ni], acc[mi][ni]);
    }
#pragma unroll
    for (int mi = 0; mi < 2; mi++)
#pragma unroll
        for (int ni = 0; ni < 4; ni++) {
            int col = n0 + wn * 64 + ni * 16 + q15;
            float bias = bo[col];
#pragma unroll
            for (int j = 0; j < 4; j++) {
                int row = m0 + wm * 32 + mi * 16 + g * 4 + j;
                out[(size_t)row * 1024 + col] = acc[mi][ni][j] + bias;
            }
        }
}

extern "C" void kernel_launch(void* const* d_in, const int* in_sizes, int n_in,
                              void* d_out, int out_size, void* d_ws, size_t ws_size,
                              hipStream_t stream) {
    const float* qkv = (const float*)d_in[0];
    const void* mask = d_in[1];
    const float* Wqkv = (const float*)d_in[2];
    const float* bqkv = (const float*)d_in[3];
    const float* Wo = (const float*)d_in[4];
    const float* bo = (const float*)d_in[5];
    float* out = (float*)d_out;

    const size_t SZ_X = (size_t)4096 * 1024 * 2;       // 8 MB
    const size_t SZ_W = (size_t)3072 * 1024 * 2;       // 6 MB
    const size_t SZ_WO = (size_t)1024 * 1024 * 2;      // 2 MB
    const size_t SZ_QKV = (size_t)32 * 2048 * 64 * 2;  // 8 MB
    const size_t SZ_ATT = (size_t)4096 * 1024 * 2;     // 8 MB

    char* p = (char*)d_ws;
    u16* Xh = (u16*)p; p += SZ_X;
    u16* Wth = (u16*)p; p += SZ_W;
    u16* Woth = (u16*)p; p += SZ_WO;
    u16* qh = (u16*)p; p += SZ_QKV;
    u16* kh = (u16*)p; p += SZ_QKV;
    u16* vt = (u16*)p; p += SZ_QKV;  // [bh][d][s_packed]
    u16* att = (u16*)p; p += SZ_ATT;
    float* pbias = (float*)p; p += BATCH * SEQ * 4;
    int* pack_idx = (int*)p; p += BATCH * SEQ * 4;
    int* cnt = (int*)p; p += 256;

    prep_all<<<1 + 3072 + 1024 + 1024, 256, 0, stream>>>(
        qkv, (const unsigned char*)mask, Wqkv, Wo, Xh, Wth, Woth, pbias, pack_idx, cnt);
    gemm_qkv<<<dim3(24, 32), 256, 0, stream>>>(Xh, Wth, bqkv, pack_idx, cnt, qh, kh, vt);
    attn_kernel<<<dim3(16, 32), 512, 0, stream>>>(qh, kh, vt, pbias, cnt, att);
    gemm_out<<<dim3(8, 64), 256, 0, stream>>>(att, Woth, bo, out);
}

// Round 19
// 97.486 us; speedup vs baseline: 1.4415x; 1.0223x over previous
//
#include <hip/hip_runtime.h>

#define DEV __device__ __forceinline__

typedef unsigned short u16;
typedef unsigned int u32;
typedef __attribute__((ext_vector_type(4))) float f32x4;
typedef __attribute__((ext_vector_type(8))) short s16x8;
typedef __attribute__((ext_vector_type(8))) _Float16 f16x8;
typedef __attribute__((ext_vector_type(4))) unsigned short u16x4;
typedef __attribute__((ext_vector_type(4))) unsigned int u32x4;

#define BATCH 2
#define SEQ 2048
#define HID 1024
#define NH 16
#define HD 64

// scaling:  X' = 64*X, W' = 64*W -> proj = acc/4096
//  q stored = proj_q * 8*log2e (log2-domain scores direct from MFMA), k stored = proj_k
//  mask bias enters as the QK MFMA C-in (no post-FMA pass)
#define SCALE_XW 64.0f
#define INV_PROJ (1.0f / 4096.0f)
#define SCALE_Q 11.541560327111707f
#define SCALE_K 1.0f
#define DEFER_THR 10.0f

DEV f32x4 mfmah(s16x8 a, s16x8 b, f32x4 c) {
    return __builtin_amdgcn_mfma_f32_16x16x32_f16(
        __builtin_bit_cast(f16x8, a), __builtin_bit_cast(f16x8, b), c, 0, 0, 0);
}

DEV u16 f2h(float x) { return __builtin_bit_cast(u16, (_Float16)x); }
DEV float h2f(u16 h) { return (float)__builtin_bit_cast(_Float16, h); }

DEV u32 pkh(float a, float b) {
#if __has_builtin(__builtin_amdgcn_cvt_pkrtz)
    auto r = __builtin_amdgcn_cvt_pkrtz(a, b);
    return __builtin_bit_cast(u32, r);
#else
    return (u32)f2h(a) | ((u32)f2h(b) << 16);
#endif
}

DEV float fexp2(float x) {
#if __has_builtin(__builtin_amdgcn_exp2f)
    return __builtin_amdgcn_exp2f(x);
#else
    return exp2f(x);
#endif
}

DEV void swap32(int lane, u32 a, u32 b, u32& o0, u32& o1) {
#if __has_builtin(__builtin_amdgcn_permlane32_swap)
    auto r = __builtin_amdgcn_permlane32_swap((int)a, (int)b, false, false);
    o0 = (u32)r[0]; o1 = (u32)r[1];
#else
    u32 ax = (u32)__shfl_xor((int)a, 32);
    u32 bx = (u32)__shfl_xor((int)b, 32);
    bool hi = (lane & 32) != 0;
    o0 = hi ? bx : a;
    o1 = hi ? b : ax;
#endif
}
DEV void swap16(int lane, u32 a, u32 b, u32& o0, u32& o1) {
#if __has_builtin(__builtin_amdgcn_permlane16_swap)
    auto r = __builtin_amdgcn_permlane16_swap((int)a, (int)b, false, false);
    o0 = (u32)r[0]; o1 = (u32)r[1];
#else
    u32 ax = (u32)__shfl_xor((int)a, 16);
    u32 bx = (u32)__shfl_xor((int)b, 16);
    bool hi = (lane & 16) != 0;
    o0 = hi ? bx : a;
    o1 = hi ? b : ax;
#endif
}

DEV void gl_lds16(const void* g, void* l) {
    __builtin_amdgcn_global_load_lds(
        (__attribute__((address_space(1))) void*)(void*)g,
        (__attribute__((address_space(3))) void*)l, 16, 0, 0);
}

// raw barrier pair (rule #18: sched_barrier fences around inline-asm waits)
DEV void vm0_bar() {
    __builtin_amdgcn_sched_barrier(0);
    asm volatile("s_waitcnt vmcnt(0)" ::: "memory");
    __builtin_amdgcn_s_barrier();
    __builtin_amdgcn_sched_barrier(0);
}

// rows of 128B, 16B slots XOR-swizzled by row&7
DEV s16x8 lds_ld16(const u16* base, int row, int kbyte) {
    return *(const s16x8*)((const char*)base + row * 128 + (kbyte ^ ((row & 7) << 4)));
}
// rows of 64B, 16B slots XOR-swizzled by row&3
DEV s16x8 lds_ld32r(const u16* base, int row, int g) {
    return *(const s16x8*)((const char*)base + row * 64 + ((g * 16) ^ ((row & 3) << 4)));
}

// ------- fused prep: mask scan/compaction + W transposes + X convert -------
__global__ __launch_bounds__(256) void prep_all(
    const float* __restrict__ qkv, const unsigned char* __restrict__ m,
    const float* __restrict__ Wqkv, const float* __restrict__ Wo,
    u16* __restrict__ Xh, u16* __restrict__ Wth, u16* __restrict__ Woth,
    float* __restrict__ pbias, int* __restrict__ pack_idx, int* __restrict__ cnt) {
    int bid = blockIdx.x;
    int tid = threadIdx.x;
    if (bid == 0) {
        __shared__ int sb, sf;
        __shared__ int scan[256];
        if (tid == 0) { sb = 0; sf = 0; }
        __syncthreads();
        int lb = 0, lf = 0;
        for (int i = tid * 16; i < tid * 16 + 16; i++) {
            unsigned char v = m[i];
            int pos = i & 3;
            if (pos == 3 && v == 0x3f) lf = 1;
            if (pos != 0 && v != 0) lb = 1;
        }
        if (lb) atomicOr(&sb, 1);
        if (lf) atomicOr(&sf, 1);
        __syncthreads();
        int f = sf ? 2 : (sb ? 1 : 0);
#pragma unroll
        for (int b = 0; b < BATCH; b++) {
            int base = b * SEQ;
            int keep[8], lc = 0;
#pragma unroll
            for (int e = 0; e < 8; e++) {
                int i = base + tid * 8 + e;
                int mv;
                if (f == 0) mv = ((const int*)m)[i] != 0;
                else if (f == 1) mv = m[i] != 0;
                else mv = ((const float*)m)[i] != 0.0f;
                keep[e] = !mv;
                lc += keep[e];
            }
            scan[tid] = lc;
            __syncthreads();
            for (int s = 1; s < 256; s <<= 1) {
                int v = (tid >= s) ? scan[tid - s] : 0;
                __syncthreads();
                scan[tid] += v;
                __syncthreads();
            }
            int off = scan[tid] - lc;
            int total = scan[255];
            __syncthreads();  // scan reused next batch
#pragma unroll
            for (int e = 0; e < 8; e++)
                if (keep[e]) pack_idx[base + off++] = base + tid * 8 + e;
            if (tid == 0) cnt[b] = total;
            for (int j = tid; j < SEQ; j += 256)
                pbias[base + j] = (j < total) ? 0.0f : -1e30f;
        }
    } else if (bid <= 3072 + 1024) {
        const float* in;
        u16* oh;
        int N, t;
        float scale;
        if (bid <= 3072) { in = Wqkv; oh = Wth; N = 3072; t = bid - 1; scale = SCALE_XW; }
        else { in = Wo; oh = Woth; N = 1024; t = bid - 3073; scale = 1.0f; }
        const int K = 1024;
        int ntiles = N >> 5;
        int n0 = (t % ntiles) * 32, k0 = (t / ntiles) * 32;
        __shared__ float tt[32][33];
        int tx = tid & 31, ty = tid >> 5;
#pragma unroll
        for (int i = 0; i < 4; i++)
            tt[ty + 8 * i][tx] = in[(size_t)(k0 + ty + 8 * i) * N + n0 + tx];
        __syncthreads();
#pragma unroll
        for (int i = 0; i < 4; i++) {
            float v = tt[tx][ty + 8 * i] * scale;
            size_t o = (size_t)(n0 + ty + 8 * i) * K + k0 + tx;
            oh[o] = f2h(v);
        }
    } else {
        int cb = bid - 3073 - 1024;  // 0..1023
#pragma unroll
        for (int it = 0; it < 4; it++) {
            int i = ((cb + it * 1024) * 256 + tid) * 4;
            f32x4 v = *(const f32x4*)&qkv[i];
            u16x4 h;
#pragma unroll
            for (int e = 0; e < 4; e++) h[e] = f2h(v[e] * SCALE_XW);
            *(u16x4*)&Xh[i] = h;
        }
    }
}

// ------- GEMM1: Xh @ Wh fp16 1-PASS, BK=64 (R18: half the barrier rounds),
// single-buf 32KB, R11-proven vm0_bar schedule. K/V parts in PACKED key space. -------
__global__ __launch_bounds__(256, 3) void gemm_qkv(
    const u16* __restrict__ Xh,
    const u16* __restrict__ Wth,
    const float* __restrict__ bqkv,
    const int* __restrict__ pack_idx, const int* __restrict__ cnt,
    u16* __restrict__ qh,
    u16* __restrict__ kh,
    u16* __restrict__ vt) {
    __shared__ __align__(16) u16 SM[2][128 * 64];  // 32 KB: [X, W] planes, BK=64
    int tid = threadIdx.x, lane = tid & 63, w = tid >> 6;
    int g = lane >> 4, q15 = lane & 15;
    int wm = w >> 1, wn = w & 1;
    int m0 = blockIdx.y * 128, n0 = blockIdx.x * 128;
    int part = n0 >> 10;
    int bb = m0 >> 11;
    int cb = cnt[bb];
    if (part != 0 && (m0 & 2047) >= cb) return;  // packed rows all beyond count

    // per-thread source rows: 4 staged rows/thread (row = (i*256+tid)>>3)
    int srcrow[4];
#pragma unroll
    for (int i = 0; i < 4; i++) {
        int r = m0 + ((i * 256 + tid) >> 3);
        srcrow[i] = (part == 0) ? r : (((r & 2047) < cb) ? pack_idx[r] : (bb << 11));
    }

    f32x4 acc[4][4];
#pragma unroll
    for (int i = 0; i < 4; i++)
#pragma unroll
        for (int j = 0; j < 4; j++) acc[i][j] = (f32x4){0.f, 0.f, 0.f, 0.f};

    auto STAGE = [&](int kt) {
        int k0 = kt * 64;
#pragma unroll
        for (int i = 0; i < 4; i++) {
            int c = i * 256 + tid;
            int row = c >> 3, slot = c & 7;       // 128 rows x 8 slots (64 k)
            int sg = slot ^ (row & 7);
            int dst = (c & ~63) * 8;
            size_t ga = (size_t)srcrow[i] * 1024 + k0 + sg * 8;
            size_t gb = (size_t)(n0 + row) * 1024 + k0 + sg * 8;
            gl_lds16(&Xh[ga], &SM[0][dst]);
            gl_lds16(&Wth[gb], &SM[1][dst]);
        }
    };

    STAGE(0);
    for (int kt = 0; kt < 16; kt++) {
        vm0_bar();  // stage for kt complete on all waves
        s16x8 a_h[2][4], b_h[2][4];
#pragma unroll
        for (int k2 = 0; k2 < 2; k2++) {
            int kb = k2 * 64 + g * 16;
#pragma unroll
            for (int i = 0; i < 4; i++) {
                a_h[k2][i] = lds_ld16(SM[0], wm * 64 + i * 16 + q15, kb);
                b_h[k2][i] = lds_ld16(SM[1], wn * 64 + i * 16 + q15, kb);
            }
        }
        __syncthreads();  // all waves' reads retired -> buffer reusable
        if (kt < 15) STAGE(kt + 1);
#pragma unroll
        for (int k2 = 0; k2 < 2; k2++)
#pragma unroll
            for (int mi = 0; mi < 4; mi++)
#pragma unroll
                for (int ni = 0; ni < 4; ni++)
                    acc[mi][ni] = mfmah(a_h[k2][mi], b_h[k2][ni], acc[mi][ni]);
    }

    if (part == 2) {
        u16* T = (u16*)SM;  // 32KB >= 64*140*2 = 17.9KB
        const int TP = 140;
#pragma unroll
        for (int h2 = 0; h2 < 2; h2++) {
            __syncthreads();
            if (wn == h2) {
#pragma unroll
                for (int mi = 0; mi < 4; mi++)
#pragma unroll
                    for (int ni = 0; ni < 4; ni++) {
                        int lcol = ni * 16 + q15;  // 0..63 within half
#pragma unroll
                        for (int j = 0; j < 4; j++) {
                            int lrow = wm * 64 + mi * 16 + g * 4 + j;
                            T[lcol * TP + lrow] =
                                f2h(acc[mi][ni][j] * INV_PROJ + bqkv[n0 + h2 * 64 + lcol]);
                        }
                    }
            }
            __syncthreads();
            int lcol = tid >> 2;  // 0..63
            int seg = tid & 3;
            int c = n0 - 2048 + h2 * 64 + lcol;
            int h = c >> 6, d = c & 63;
            int b = m0 >> 11, sbase = m0 & 2047;
            size_t rowbase = ((size_t)(b * NH + h) * HD + d) * SEQ + sbase;
#pragma unroll
            for (int k = 0; k < 2; k++) {
                int slot = seg * 2 + k;  // 8 slots x 16 rows = 128
                *(s16x8*)&vt[rowbase + slot * 16 + 0] = *(const s16x8*)&T[lcol * TP + slot * 16 + 0];
                *(s16x8*)&vt[rowbase + slot * 16 + 8] = *(const s16x8*)&T[lcol * TP + slot * 16 + 8];
            }
        }
    } else {
#pragma unroll
        for (int mi = 0; mi < 4; mi++)
#pragma unroll
            for (int ni = 0; ni < 4; ni++) {
                int col = n0 + wn * 64 + ni * 16 + q15;
                float bias = bqkv[col];
                int cc = col & 1023, h = cc >> 6, d = cc & 63;
#pragma unroll
                for (int j = 0; j < 4; j++) {
                    int row = m0 + wm * 64 + mi * 16 + g * 4 + j;
                    int b = row >> 11, s = row & 2047;  // s: packed for K, true for Q
                    float v = acc[mi][ni][j] * INV_PROJ + bias;
                    v *= (part == 0) ? SCALE_Q : SCALE_K;
                    size_t o = (size_t)(b * NH + h) * SEQ * HD + (size_t)s * HD + d;
                    if (part == 0) qh[o] = f2h(v);
                    else kh[o] = f2h(v);
                }
            }
    }
}

// ------ flash attention over PACKED keys: 8 waves x 16 q-rows, 2-phase dbuf ------
__global__ __launch_bounds__(512, 4) void attn_kernel(
    const u16* __restrict__ qh,
    const u16* __restrict__ kh,
    const u16* __restrict__ vt, const float* __restrict__ pbias,
    const int* __restrict__ cnt,
    u16* __restrict__ att) {
    __shared__ __align__(16) u16 Kh[2][4096], Vt[2][4096];  // 32 KB
    __shared__ __align__(16) float MskB[2][64];
    int tid = threadIdx.x, lane = tid & 63, w = tid >> 6;
    int g = lane >> 4, q15 = lane & 15;
    int bid = blockIdx.y * 16 + blockIdx.x;
    int swz = (bid & 7) * 64 + (bid >> 3);  // bijective: 512 % 8 == 0
    int qt = swz & 15, bh = swz >> 4;
    int b = bh >> 4, h = bh & 15;
    int q0 = qt * 128;
    int NT = (cnt[b] + 63) >> 6;  // packed key tiles
    size_t base = (size_t)bh * SEQ * HD;
    const u16* vbase = vt + (size_t)bh * HD * SEQ;
    const float* mrow = pbias + b * SEQ;

    // Q fragment, 16 rows per wave (k-map: k = k2*32 + g*8 + e)
    s16x8 aq[2];
#pragma unroll
    for (int k2 = 0; k2 < 2; k2++) {
        size_t o = base + (size_t)(q0 + w * 16 + q15) * HD + k2 * 32 + g * 8;
        aq[k2] = *(const s16x8*)&qh[o];
    }

    float m_ = -1e30f, l_ = 0.f;  // lane-partial l
    f32x4 o_[4];
#pragma unroll
    for (int df = 0; df < 4; df++) o_[df] = (f32x4){0.f, 0.f, 0.f, 0.f};

    auto STAGE = [&](int buf, int k0) {
        int row = tid >> 3, slot = tid & 7;
        int sg = slot ^ (row & 7);
        int dst = (tid & ~63) * 8;
        size_t gK = base + (size_t)(k0 + row) * HD + sg * 8;
        gl_lds16(&kh[gK], &Kh[buf][dst]);
        size_t gV = (size_t)row * SEQ + k0 + sg * 8;
        gl_lds16(&vbase[gV], &Vt[buf][dst]);
        if (tid < 16) gl_lds16(&mrow[k0 + tid * 4], &MskB[buf][0]);
    };

    STAGE(0, 0);
    __syncthreads();

    for (int kt = 0; kt < NT; kt++) {
        int cur = kt & 1;
        if (kt < NT - 1) STAGE(cur ^ 1, (kt + 1) * 64);

        // swapped QK^T: D[k][q]; C-in = mask bias (log2-domain scores from MFMA)
        f32x4 sc[4];
#pragma unroll
        for (int nf = 0; nf < 4; nf++)
            sc[nf] = *(const f32x4*)&MskB[cur][nf * 16 + g * 4];
#pragma unroll
        for (int nf = 0; nf < 4; nf++)
#pragma unroll
            for (int k2 = 0; k2 < 2; k2++) {
                int kb = k2 * 64 + g * 16;
                s16x8 kbh = lds_ld16(Kh[cur], nf * 16 + q15, kb);
                sc[nf] = mfmah(kbh, aq[k2], sc[nf]);
            }

        // per-lane softmax (row q = q15) with defer-max
        float pml = -1e30f;
#pragma unroll
        for (int nf = 0; nf < 4; nf++) {
            float a = fmaxf(sc[nf][0], sc[nf][1]);
            float bmx = fmaxf(sc[nf][2], sc[nf][3]);
            pml = fmaxf(pml, fmaxf(a, bmx));
        }
        if (!__all(pml - m_ <= DEFER_THR)) {
            float pm = fmaxf(pml, __shfl_xor(pml, 16));
            pm = fmaxf(pm, __shfl_xor(pm, 32));
            float mn = fmaxf(m_, pm);
            float scl = fexp2(m_ - mn);
            m_ = mn;
            l_ *= scl;
#pragma unroll
            for (int j = 0; j < 4; j++) {
                float sb = __shfl(scl, g * 4 + j);
#pragma unroll
                for (int df = 0; df < 4; df++) o_[df][j] *= sb;
            }
        }
        float p[4][4];
        float rs = 0.f;
#pragma unroll
        for (int nf = 0; nf < 4; nf++)
#pragma unroll
            for (int j = 0; j < 4; j++) {
                float pv = fexp2(sc[nf][j] - m_);
                p[nf][j] = pv;
                rs += pv;
            }
        l_ += rs;  // lane-partial
        // in-register P repack: pa[k2] elem e = P[q15][k2*32 + g*8 + e]
        s16x8 pa[2];
#pragma unroll
        for (int k2 = 0; k2 < 2; k2++) {
            u32 A0 = pkh(p[2 * k2][0], p[2 * k2][1]);
            u32 A1 = pkh(p[2 * k2][2], p[2 * k2][3]);
            u32 B0 = pkh(p[2 * k2 + 1][0], p[2 * k2 + 1][1]);
            u32 B1 = pkh(p[2 * k2 + 1][2], p[2 * k2 + 1][3]);
            u32 s0, s1, t0, t1, w0, w1, w2, w3;
            swap32(lane, A0, B0, s0, s1);
            swap16(lane, s0, s1, w0, w2);
            swap32(lane, A1, B1, t0, t1);
            swap16(lane, t0, t1, w1, w3);
            u32x4 words = {w0, w1, w2, w3};
            pa[k2] = __builtin_bit_cast(s16x8, words);
        }

        // PV: O[q][d] += P[q][k] * V^T[d][k]
#pragma unroll
        for (int k2 = 0; k2 < 2; k2++) {
            int kb = k2 * 64 + g * 16;
#pragma unroll
            for (int df = 0; df < 4; df++) {
                s16x8 vb = lds_ld16(Vt[cur], df * 16 + q15, kb);
                o_[df] = mfmah(pa[k2], vb, o_[df]);
            }
        }
        __syncthreads();
    }

    float lt = l_;
    lt += __shfl_xor(lt, 16);
    lt += __shfl_xor(lt, 32);
#pragma unroll
    for (int j = 0; j < 4; j++) {
        float lb = __shfl(lt, g * 4 + j);
        float linv = __builtin_amdgcn_rcpf(lb);
        int qrow = q0 + w * 16 + g * 4 + j;
        size_t srow = (size_t)(b * SEQ + qrow);
#pragma unroll
        for (int df = 0; df < 4; df++) {
            int col = h * HD + df * 16 + q15;
            att[srow * HID + col] = f2h(o_[df][j] * linv);
        }
    }
}

// ---------------- GEMM2: att fp16 @ Wo fp16 (1 pass), 64x128 tiles, BK=32 dbuf -----
__global__ __launch_bounds__(256, 4) void gemm_out(
    const u16* __restrict__ A, const u16* __restrict__ Bh0,
    const float* __restrict__ bo, float* __restrict__ out) {
    __shared__ __align__(16) u16 SMa[2][64 * 32], SMb[2][128 * 32];  // 24 KB
    int tid = threadIdx.x, lane = tid & 63, w = tid >> 6;
    int g = lane >> 4, q15 = lane & 15;
    int wm = w >> 1, wn = w & 1;
    int m0 = blockIdx.y * 64, n0 = blockIdx.x * 128;
    f32x4 acc[2][4];
#pragma unroll
    for (int i = 0; i < 2; i++)
#pragma unroll
        for (int j = 0; j < 4; j++) acc[i][j] = (f32x4){0.f, 0.f, 0.f, 0.f};

    auto STAGE = [&](int db, int kt) {
        int k0 = kt * 32;
        {
            int c = tid;
            int row = c >> 2, slot = c & 3;
            int sg = slot ^ (row & 3);
            int dst = (c & ~63) * 8;
            gl_lds16(&A[(size_t)(m0 + row) * 1024 + k0 + sg * 8], &SMa[db][dst]);
        }
#pragma unroll
        for (int i = 0; i < 2; i++) {
            int c = i * 256 + tid;
            int row = c >> 2, slot = c & 3;
            int sg = slot ^ (row & 3);
            int dst = (c & ~63) * 8;
            gl_lds16(&Bh0[(size_t)(n0 + row) * 1024 + k0 + sg * 8], &SMb[db][dst]);
        }
    };

    STAGE(0, 0);
    for (int kt = 0; kt < 32; kt++) {
        int cur = kt & 1;
        __syncthreads();
        if (kt < 31) STAGE(cur ^ 1, kt + 1);
        s16x8 a_[2], b_[4];
#pragma unroll
        for (int i = 0; i < 2; i++)
            a_[i] = lds_ld32r(SMa[cur], wm * 32 + i * 16 + q15, g);
#pragma unroll
        for (int i = 0; i < 4; i++)
            b_[i] = lds_ld32r(SMb[cur], wn * 64 + i * 16 + q15, g);
#pragma unroll
        for (int mi = 0; mi < 2; mi++)
#pragma unroll
            for (int ni = 0; ni < 4; ni++)
                acc[mi][ni] = mfmah(a_[mi], b_[ni], acc[mi][ni]);
    }
#pragma unroll
    for (int mi = 0; mi < 2; mi++)
#pragma unroll
        for (int ni = 0; ni < 4; ni++) {
            int col = n0 + wn * 64 + ni * 16 + q15;
            float bias = bo[col];
#pragma unroll
            for (int j = 0; j < 4; j++) {
                int row = m0 + wm * 32 + mi * 16 + g * 4 + j;
                out[(size_t)row * 1024 + col] = acc[mi][ni][j] + bias;
            }
        }
}

extern "C" void kernel_launch(void* const* d_in, const int* in_sizes, int n_in,
                              void* d_out, int out_size, void* d_ws, size_t ws_size,
                              hipStream_t stream) {
    const float* qkv = (const float*)d_in[0];
    const void* mask = d_in[1];
    const float* Wqkv = (const float*)d_in[2];
    const float* bqkv = (const float*)d_in[3];
    const float* Wo = (const float*)d_in[4];
    const float* bo = (const float*)d_in[5];
    float* out = (float*)d_out;

    const size_t SZ_X = (size_t)4096 * 1024 * 2;       // 8 MB
    const size_t SZ_W = (size_t)3072 * 1024 * 2;       // 6 MB
    const size_t SZ_WO = (size_t)1024 * 1024 * 2;      // 2 MB
    const size_t SZ_QKV = (size_t)32 * 2048 * 64 * 2;  // 8 MB
    const size_t SZ_ATT = (size_t)4096 * 1024 * 2;     // 8 MB

    char* p = (char*)d_ws;
    u16* Xh = (u16*)p; p += SZ_X;
    u16* Wth = (u16*)p; p += SZ_W;
    u16* Woth = (u16*)p; p += SZ_WO;
    u16* qh = (u16*)p; p += SZ_QKV;
    u16* kh = (u16*)p; p += SZ_QKV;
    u16* vt = (u16*)p; p += SZ_QKV;  // [bh][d][s_packed]
    u16* att = (u16*)p; p += SZ_ATT;
    float* pbias = (float*)p; p += BATCH * SEQ * 4;
    int* pack_idx = (int*)p; p += BATCH * SEQ * 4;
    int* cnt = (int*)p; p += 256;

    prep_all<<<1 + 3072 + 1024 + 1024, 256, 0, stream>>>(
        qkv, (const unsigned char*)mask, Wqkv, Wo, Xh, Wth, Woth, pbias, pack_idx, cnt);
    gemm_qkv<<<dim3(24, 32), 256, 0, stream>>>(Xh, Wth, bqkv, pack_idx, cnt, qh, kh, vt);
    attn_kernel<<<dim3(16, 32), 512, 0, stream>>>(qh, kh, vt, pbias, cnt, att);
    gemm_out<<<dim3(8, 64), 256, 0, stream>>>(att, Woth, bo, out);
}

// Round 20
// 97.159 us; speedup vs baseline: 1.4464x; 1.0034x over previous
//
#include <hip/hip_runtime.h>

#define DEV __device__ __forceinline__

typedef unsigned short u16;
typedef unsigned int u32;
typedef __attribute__((ext_vector_type(4))) float f32x4;
typedef __attribute__((ext_vector_type(8))) short s16x8;
typedef __attribute__((ext_vector_type(8))) _Float16 f16x8;
typedef __attribute__((ext_vector_type(4))) unsigned short u16x4;
typedef __attribute__((ext_vector_type(4))) unsigned int u32x4;

#define BATCH 2
#define SEQ 2048
#define HID 1024
#define NH 16
#define HD 64

// scaling:  X' = 64*X, W' = 64*W -> proj = acc/4096
//  q stored = proj_q * 8*log2e (log2-domain scores direct from MFMA), k stored = proj_k
//  mask bias enters as the QK MFMA C-in (no post-FMA pass)
#define SCALE_XW 64.0f
#define INV_PROJ (1.0f / 4096.0f)
#define SCALE_Q 11.541560327111707f
#define SCALE_K 1.0f
#define DEFER_THR 10.0f

DEV f32x4 mfmah(s16x8 a, s16x8 b, f32x4 c) {
    return __builtin_amdgcn_mfma_f32_16x16x32_f16(
        __builtin_bit_cast(f16x8, a), __builtin_bit_cast(f16x8, b), c, 0, 0, 0);
}

DEV u16 f2h(float x) { return __builtin_bit_cast(u16, (_Float16)x); }
DEV float h2f(u16 h) { return (float)__builtin_bit_cast(_Float16, h); }

DEV u32 pkh(float a, float b) {
#if __has_builtin(__builtin_amdgcn_cvt_pkrtz)
    auto r = __builtin_amdgcn_cvt_pkrtz(a, b);
    return __builtin_bit_cast(u32, r);
#else
    return (u32)f2h(a) | ((u32)f2h(b) << 16);
#endif
}

DEV float fexp2(float x) {
#if __has_builtin(__builtin_amdgcn_exp2f)
    return __builtin_amdgcn_exp2f(x);
#else
    return exp2f(x);
#endif
}

DEV void swap32(int lane, u32 a, u32 b, u32& o0, u32& o1) {
#if __has_builtin(__builtin_amdgcn_permlane32_swap)
    auto r = __builtin_amdgcn_permlane32_swap((int)a, (int)b, false, false);
    o0 = (u32)r[0]; o1 = (u32)r[1];
#else
    u32 ax = (u32)__shfl_xor((int)a, 32);
    u32 bx = (u32)__shfl_xor((int)b, 32);
    bool hi = (lane & 32) != 0;
    o0 = hi ? bx : a;
    o1 = hi ? b : ax;
#endif
}
DEV void swap16(int lane, u32 a, u32 b, u32& o0, u32& o1) {
#if __has_builtin(__builtin_amdgcn_permlane16_swap)
    auto r = __builtin_amdgcn_permlane16_swap((int)a, (int)b, false, false);
    o0 = (u32)r[0]; o1 = (u32)r[1];
#else
    u32 ax = (u32)__shfl_xor((int)a, 16);
    u32 bx = (u32)__shfl_xor((int)b, 16);
    bool hi = (lane & 16) != 0;
    o0 = hi ? bx : a;
    o1 = hi ? b : ax;
#endif
}

DEV void gl_lds16(const void* g, void* l) {
    __builtin_amdgcn_global_load_lds(
        (__attribute__((address_space(1))) void*)(void*)g,
        (__attribute__((address_space(3))) void*)l, 16, 0, 0);
}

// raw barrier pair (rule #18: sched_barrier fences around inline-asm waits)
DEV void vm0_bar() {
    __builtin_amdgcn_sched_barrier(0);
    asm volatile("s_waitcnt vmcnt(0)" ::: "memory");
    __builtin_amdgcn_s_barrier();
    __builtin_amdgcn_sched_barrier(0);
}

// rows of 128B, 16B slots XOR-swizzled by row&7
DEV s16x8 lds_ld16(const u16* base, int row, int kbyte) {
    return *(const s16x8*)((const char*)base + row * 128 + (kbyte ^ ((row & 7) << 4)));
}
// rows of 256B, 16B slots XOR-swizzled by row&7 (V tiles at KVBLK=128)
DEV s16x8 lds_ld16v(const u16* base, int row, int kbyte) {
    return *(const s16x8*)((const char*)base + row * 256 + (kbyte ^ ((row & 7) << 4)));
}
// rows of 64B, 16B slots XOR-swizzled by row&3
DEV s16x8 lds_ld32r(const u16* base, int row, int g) {
    return *(const s16x8*)((const char*)base + row * 64 + ((g * 16) ^ ((row & 3) << 4)));
}

// ------- fused prep: mask scan/compaction + W transposes + X convert -------
__global__ __launch_bounds__(256) void prep_all(
    const float* __restrict__ qkv, const unsigned char* __restrict__ m,
    const float* __restrict__ Wqkv, const float* __restrict__ Wo,
    u16* __restrict__ Xh, u16* __restrict__ Wth, u16* __restrict__ Woth,
    float* __restrict__ pbias, int* __restrict__ pack_idx, int* __restrict__ cnt) {
    int bid = blockIdx.x;
    int tid = threadIdx.x;
    if (bid == 0) {
        __shared__ int sb, sf;
        __shared__ int scan[256];
        if (tid == 0) { sb = 0; sf = 0; }
        __syncthreads();
        int lb = 0, lf = 0;
        for (int i = tid * 16; i < tid * 16 + 16; i++) {
            unsigned char v = m[i];
            int pos = i & 3;
            if (pos == 3 && v == 0x3f) lf = 1;
            if (pos != 0 && v != 0) lb = 1;
        }
        if (lb) atomicOr(&sb, 1);
        if (lf) atomicOr(&sf, 1);
        __syncthreads();
        int f = sf ? 2 : (sb ? 1 : 0);
#pragma unroll
        for (int b = 0; b < BATCH; b++) {
            int base = b * SEQ;
            int keep[8], lc = 0;
#pragma unroll
            for (int e = 0; e < 8; e++) {
                int i = base + tid * 8 + e;
                int mv;
                if (f == 0) mv = ((const int*)m)[i] != 0;
                else if (f == 1) mv = m[i] != 0;
                else mv = ((const float*)m)[i] != 0.0f;
                keep[e] = !mv;
                lc += keep[e];
            }
            scan[tid] = lc;
            __syncthreads();
            for (int s = 1; s < 256; s <<= 1) {
                int v = (tid >= s) ? scan[tid - s] : 0;
                __syncthreads();
                scan[tid] += v;
                __syncthreads();
            }
            int off = scan[tid] - lc;
            int total = scan[255];
            __syncthreads();  // scan reused next batch
#pragma unroll
            for (int e = 0; e < 8; e++)
                if (keep[e]) pack_idx[base + off++] = base + tid * 8 + e;
            if (tid == 0) cnt[b] = total;
            for (int j = tid; j < SEQ; j += 256)
                pbias[base + j] = (j < total) ? 0.0f : -1e30f;
        }
    } else if (bid <= 3072 + 1024) {
        const float* in;
        u16* oh;
        int N, t;
        float scale;
        if (bid <= 3072) { in = Wqkv; oh = Wth; N = 3072; t = bid - 1; scale = SCALE_XW; }
        else { in = Wo; oh = Woth; N = 1024; t = bid - 3073; scale = 1.0f; }
        const int K = 1024;
        int ntiles = N >> 5;
        int n0 = (t % ntiles) * 32, k0 = (t / ntiles) * 32;
        __shared__ float tt[32][33];
        int tx = tid & 31, ty = tid >> 5;
#pragma unroll
        for (int i = 0; i < 4; i++)
            tt[ty + 8 * i][tx] = in[(size_t)(k0 + ty + 8 * i) * N + n0 + tx];
        __syncthreads();
#pragma unroll
        for (int i = 0; i < 4; i++) {
            float v = tt[tx][ty + 8 * i] * scale;
            size_t o = (size_t)(n0 + ty + 8 * i) * K + k0 + tx;
            oh[o] = f2h(v);
        }
    } else {
        int cb = bid - 3073 - 1024;  // 0..1023
#pragma unroll
        for (int it = 0; it < 4; it++) {
            int i = ((cb + it * 1024) * 256 + tid) * 4;
            f32x4 v = *(const f32x4*)&qkv[i];
            u16x4 h;
#pragma unroll
            for (int e = 0; e < 4; e++) h[e] = f2h(v[e] * SCALE_XW);
            *(u16x4*)&Xh[i] = h;
        }
    }
}

// ------- GEMM1: Xh @ Wh fp16 1-PASS, BK=64, single-buf 32KB (R18-proven) -------
__global__ __launch_bounds__(256, 3) void gemm_qkv(
    const u16* __restrict__ Xh,
    const u16* __restrict__ Wth,
    const float* __restrict__ bqkv,
    const int* __restrict__ pack_idx, const int* __restrict__ cnt,
    u16* __restrict__ qh,
    u16* __restrict__ kh,
    u16* __restrict__ vt) {
    __shared__ __align__(16) u16 SM[2][128 * 64];  // 32 KB: [X, W] planes, BK=64
    int tid = threadIdx.x, lane = tid & 63, w = tid >> 6;
    int g = lane >> 4, q15 = lane & 15;
    int wm = w >> 1, wn = w & 1;
    int m0 = blockIdx.y * 128, n0 = blockIdx.x * 128;
    int part = n0 >> 10;
    int bb = m0 >> 11;
    int cb = cnt[bb];
    if (part != 0 && (m0 & 2047) >= cb) return;  // packed rows all beyond count

    int srcrow[4];
#pragma unroll
    for (int i = 0; i < 4; i++) {
        int r = m0 + ((i * 256 + tid) >> 3);
        srcrow[i] = (part == 0) ? r : (((r & 2047) < cb) ? pack_idx[r] : (bb << 11));
    }

    f32x4 acc[4][4];
#pragma unroll
    for (int i = 0; i < 4; i++)
#pragma unroll
        for (int j = 0; j < 4; j++) acc[i][j] = (f32x4){0.f, 0.f, 0.f, 0.f};

    auto STAGE = [&](int kt) {
        int k0 = kt * 64;
#pragma unroll
        for (int i = 0; i < 4; i++) {
            int c = i * 256 + tid;
            int row = c >> 3, slot = c & 7;  // 128 rows x 8 slots (64 k)
            int sg = slot ^ (row & 7);
            int dst = (c & ~63) * 8;
            size_t ga = (size_t)srcrow[i] * 1024 + k0 + sg * 8;
            size_t gb = (size_t)(n0 + row) * 1024 + k0 + sg * 8;
            gl_lds16(&Xh[ga], &SM[0][dst]);
            gl_lds16(&Wth[gb], &SM[1][dst]);
        }
    };

    STAGE(0);
    for (int kt = 0; kt < 16; kt++) {
        vm0_bar();  // stage for kt complete on all waves
        s16x8 a_h[2][4], b_h[2][4];
#pragma unroll
        for (int k2 = 0; k2 < 2; k2++) {
            int kb = k2 * 64 + g * 16;
#pragma unroll
            for (int i = 0; i < 4; i++) {
                a_h[k2][i] = lds_ld16(SM[0], wm * 64 + i * 16 + q15, kb);
                b_h[k2][i] = lds_ld16(SM[1], wn * 64 + i * 16 + q15, kb);
            }
        }
        __syncthreads();  // all waves' reads retired -> buffer reusable
        if (kt < 15) STAGE(kt + 1);
#pragma unroll
        for (int k2 = 0; k2 < 2; k2++)
#pragma unroll
            for (int mi = 0; mi < 4; mi++)
#pragma unroll
                for (int ni = 0; ni < 4; ni++)
                    acc[mi][ni] = mfmah(a_h[k2][mi], b_h[k2][ni], acc[mi][ni]);
    }

    if (part == 2) {
        u16* T = (u16*)SM;
        const int TP = 140;
#pragma unroll
        for (int h2 = 0; h2 < 2; h2++) {
            __syncthreads();
            if (wn == h2) {
#pragma unroll
                for (int mi = 0; mi < 4; mi++)
#pragma unroll
                    for (int ni = 0; ni < 4; ni++) {
                        int lcol = ni * 16 + q15;  // 0..63 within half
#pragma unroll
                        for (int j = 0; j < 4; j++) {
                            int lrow = wm * 64 + mi * 16 + g * 4 + j;
                            T[lcol * TP + lrow] =
                                f2h(acc[mi][ni][j] * INV_PROJ + bqkv[n0 + h2 * 64 + lcol]);
                        }
                    }
            }
            __syncthreads();
            int lcol = tid >> 2;  // 0..63
            int seg = tid & 3;
            int c = n0 - 2048 + h2 * 64 + lcol;
            int h = c >> 6, d = c & 63;
            int b = m0 >> 11, sbase = m0 & 2047;
            size_t rowbase = ((size_t)(b * NH + h) * HD + d) * SEQ + sbase;
#pragma unroll
            for (int k = 0; k < 2; k++) {
                int slot = seg * 2 + k;  // 8 slots x 16 rows = 128
                *(s16x8*)&vt[rowbase + slot * 16 + 0] = *(const s16x8*)&T[lcol * TP + slot * 16 + 0];
                *(s16x8*)&vt[rowbase + slot * 16 + 8] = *(const s16x8*)&T[lcol * TP + slot * 16 + 8];
            }
        }
    } else {
#pragma unroll
        for (int mi = 0; mi < 4; mi++)
#pragma unroll
            for (int ni = 0; ni < 4; ni++) {
                int col = n0 + wn * 64 + ni * 16 + q15;
                float bias = bqkv[col];
                int cc = col & 1023, h = cc >> 6, d = cc & 63;
#pragma unroll
                for (int j = 0; j < 4; j++) {
                    int row = m0 + wm * 64 + mi * 16 + g * 4 + j;
                    int b = row >> 11, s = row & 2047;  // s: packed for K, true for Q
                    float v = acc[mi][ni][j] * INV_PROJ + bias;
                    v *= (part == 0) ? SCALE_Q : SCALE_K;
                    size_t o = (size_t)(b * NH + h) * SEQ * HD + (size_t)s * HD + d;
                    if (part == 0) qh[o] = f2h(v);
                    else kh[o] = f2h(v);
                }
            }
    }
}

// ------ flash attention over PACKED keys: 8 waves x 16 q-rows, KVBLK=128 ------
// R19: 128-key tiles halve the barrier rounds (R18's amortization lever applied
// to attn). Key-processing order identical to R18 -> same math.
__global__ __launch_bounds__(512, 2) void attn_kernel(
    const u16* __restrict__ qh,
    const u16* __restrict__ kh,
    const u16* __restrict__ vt, const float* __restrict__ pbias,
    const int* __restrict__ cnt,
    u16* __restrict__ att) {
    __shared__ __align__(16) u16 Kh[2][8192], Vt[2][8192];  // 64 KB
    __shared__ __align__(16) float MskB[2][128];            // 1 KB
    int tid = threadIdx.x, lane = tid & 63, w = tid >> 6;
    int g = lane >> 4, q15 = lane & 15;
    int bid = blockIdx.y * 16 + blockIdx.x;
    int swz = (bid & 7) * 64 + (bid >> 3);  // bijective: 512 % 8 == 0
    int qt = swz & 15, bh = swz >> 4;
    int b = bh >> 4, h = bh & 15;
    int q0 = qt * 128;
    int NT = (cnt[b] + 127) >> 7;  // packed key tiles of 128
    size_t base = (size_t)bh * SEQ * HD;
    const u16* vbase = vt + (size_t)bh * HD * SEQ;
    const float* mrow = pbias + b * SEQ;

    // Q fragment, 16 rows per wave (k-map: k = k2*32 + g*8 + e)
    s16x8 aq[2];
#pragma unroll
    for (int k2 = 0; k2 < 2; k2++) {
        size_t o = base + (size_t)(q0 + w * 16 + q15) * HD + k2 * 32 + g * 8;
        aq[k2] = *(const s16x8*)&qh[o];
    }

    float m_ = -1e30f, l_ = 0.f;  // lane-partial l
    f32x4 o_[4];
#pragma unroll
    for (int df = 0; df < 4; df++) o_[df] = (f32x4){0.f, 0.f, 0.f, 0.f};

    auto STAGE = [&](int buf, int k0) {
#pragma unroll
        for (int i = 0; i < 2; i++) {
            int c = i * 512 + tid;
            // K tile: 128 key-rows x 8 slots (128B rows)
            int row = c >> 3, slot = c & 7;
            int sg = slot ^ (row & 7);
            int dst = (c & ~63) * 8;
            size_t gK = base + (size_t)(k0 + row) * HD + sg * 8;
            gl_lds16(&kh[gK], &Kh[buf][dst]);
            // V tile: 64 d-rows x 16 slots (256B rows)
            int vrow = c >> 4, vslot = c & 15;
            int vsg = vslot ^ (vrow & 7);
            size_t gV = (size_t)vrow * SEQ + k0 + vsg * 8;
            gl_lds16(&vbase[gV], &Vt[buf][dst]);
        }
        if (tid < 32) gl_lds16(&mrow[k0 + tid * 4], &MskB[buf][0]);
    };

    STAGE(0, 0);
    __syncthreads();

    for (int kt = 0; kt < NT; kt++) {
        int cur = kt & 1;
        if (kt < NT - 1) STAGE(cur ^ 1, (kt + 1) * 128);

        // swapped QK^T: D[k][q], k = nf*16 + g*4 + j (nf 0..7 = 128 keys), q = q15.
        // C-in = mask bias (log2-domain scores direct from MFMA).
        f32x4 sc[8];
#pragma unroll
        for (int nf = 0; nf < 8; nf++)
            sc[nf] = *(const f32x4*)&MskB[cur][nf * 16 + g * 4];
#pragma unroll
        for (int nf = 0; nf < 8; nf++)
#pragma unroll
            for (int k2 = 0; k2 < 2; k2++) {
                int kb = k2 * 64 + g * 16;
                s16x8 kbh = lds_ld16(Kh[cur], nf * 16 + q15, kb);
                sc[nf] = mfmah(kbh, aq[k2], sc[nf]);
            }

        // per-lane softmax (row q = q15) with defer-max
        float pml = -1e30f;
#pragma unroll
        for (int nf = 0; nf < 8; nf++) {
            float a = fmaxf(sc[nf][0], sc[nf][1]);
            float bmx = fmaxf(sc[nf][2], sc[nf][3]);
            pml = fmaxf(pml, fmaxf(a, bmx));
        }
        if (!__all(pml - m_ <= DEFER_THR)) {
            float pm = fmaxf(pml, __shfl_xor(pml, 16));
            pm = fmaxf(pm, __shfl_xor(pm, 32));
            float mn = fmaxf(m_, pm);
            float scl = fexp2(m_ - mn);
            m_ = mn;
            l_ *= scl;
#pragma unroll
            for (int j = 0; j < 4; j++) {
                float sb = __shfl(scl, g * 4 + j);
#pragma unroll
                for (int df = 0; df < 4; df++) o_[df][j] *= sb;
            }
        }
        // exp + sum + in-register P repack, fused per nf-pair (low liveness).
        // pa[k2] elem e = P[q15][k2*32 + g*8 + e], k2 = 0..3
        float rs = 0.f;
        s16x8 pa[4];
#pragma unroll
        for (int k2 = 0; k2 < 4; k2++) {
            float p0[4], p1[4];
#pragma unroll
            for (int j = 0; j < 4; j++) {
                p0[j] = fexp2(sc[2 * k2][j] - m_);
                p1[j] = fexp2(sc[2 * k2 + 1][j] - m_);
                rs += p0[j] + p1[j];
            }
            u32 A0 = pkh(p0[0], p0[1]);
            u32 A1 = pkh(p0[2], p0[3]);
            u32 B0 = pkh(p1[0], p1[1]);
            u32 B1 = pkh(p1[2], p1[3]);
            u32 s0, s1, t0, t1, w0, w1, w2, w3;
            swap32(lane, A0, B0, s0, s1);
            swap16(lane, s0, s1, w0, w2);
            swap32(lane, A1, B1, t0, t1);
            swap16(lane, t0, t1, w1, w3);
            u32x4 words = {w0, w1, w2, w3};
            pa[k2] = __builtin_bit_cast(s16x8, words);
        }
        l_ += rs;  // lane-partial

        // PV: O[q][d] += P[q][k] * V^T[d][k], k over 128 keys (4 blocks of 32)
#pragma unroll
        for (int k2 = 0; k2 < 4; k2++) {
            int kb = k2 * 64 + g * 16;
#pragma unroll
            for (int df = 0; df < 4; df++) {
                s16x8 vb = lds_ld16v(Vt[cur], df * 16 + q15, kb);
                o_[df] = mfmah(pa[k2], vb, o_[df]);
            }
        }
        __syncthreads();
    }

    float lt = l_;
    lt += __shfl_xor(lt, 16);
    lt += __shfl_xor(lt, 32);
#pragma unroll
    for (int j = 0; j < 4; j++) {
        float lb = __shfl(lt, g * 4 + j);
        float linv = __builtin_amdgcn_rcpf(lb);
        int qrow = q0 + w * 16 + g * 4 + j;
        size_t srow = (size_t)(b * SEQ + qrow);
#pragma unroll
        for (int df = 0; df < 4; df++) {
            int col = h * HD + df * 16 + q15;
            att[srow * HID + col] = f2h(o_[df][j] * linv);
        }
    }
}

// ---------------- GEMM2: att fp16 @ Wo fp16 (1 pass), 64x128 tiles, BK=32 dbuf -----
__global__ __launch_bounds__(256, 4) void gemm_out(
    const u16* __restrict__ A, const u16* __restrict__ Bh0,
    const float* __restrict__ bo, float* __restrict__ out) {
    __shared__ __align__(16) u16 SMa[2][64 * 32], SMb[2][128 * 32];  // 24 KB
    int tid = threadIdx.x, lane = tid & 63, w = tid >> 6;
    int g = lane >> 4, q15 = lane & 15;
    int wm = w >> 1, wn = w & 1;
    int m0 = blockIdx.y * 64, n0 = blockIdx.x * 128;
    f32x4 acc[2][4];
#pragma unroll
    for (int i = 0; i < 2; i++)
#pragma unroll
        for (int j = 0; j < 4; j++) acc[i][j] = (f32x4){0.f, 0.f, 0.f, 0.f};

    auto STAGE = [&](int db, int kt) {
        int k0 = kt * 32;
        {
            int c = tid;
            int row = c >> 2, slot = c & 3;
            int sg = slot ^ (row & 3);
            int dst = (c & ~63) * 8;
            gl_lds16(&A[(size_t)(m0 + row) * 1024 + k0 + sg * 8], &SMa[db][dst]);
        }
#pragma unroll
        for (int i = 0; i < 2; i++) {
            int c = i * 256 + tid;
            int row = c >> 2, slot = c & 3;
            int sg = slot ^ (row & 3);
            int dst = (c & ~63) * 8;
            gl_lds16(&Bh0[(size_t)(n0 + row) * 1024 + k0 + sg * 8], &SMb[db][dst]);
        }
    };

    STAGE(0, 0);
    for (int kt = 0; kt < 32; kt++) {
        int cur = kt & 1;
        __syncthreads();
        if (kt < 31) STAGE(cur ^ 1, kt + 1);
        s16x8 a_[2], b_[4];
#pragma unroll
        for (int i = 0; i < 2; i++)
            a_[i] = lds_ld32r(SMa[cur], wm * 32 + i * 16 + q15, g);
#pragma unroll
        for (int i = 0; i < 4; i++)
            b_[i] = lds_ld32r(SMb[cur], wn * 64 + i * 16 + q15, g);
#pragma unroll
        for (int mi = 0; mi < 2; mi++)
#pragma unroll
            for (int ni = 0; ni < 4; ni++)
                acc[mi][ni] = mfmah(a_[mi], b_[ni], acc[mi][ni]);
    }
#pragma unroll
    for (int mi = 0; mi < 2; mi++)
#pragma unroll
        for (int ni = 0; ni < 4; ni++) {
            int col = n0 + wn * 64 + ni * 16 + q15;
            float bias = bo[col];
#pragma unroll
            for (int j = 0; j < 4; j++) {
                int row = m0 + wm * 32 + mi * 16 + g * 4 + j;
                out[(size_t)row * 1024 + col] = acc[mi][ni][j] + bias;
            }
        }
}

extern "C" void kernel_launch(void* const* d_in, const int* in_sizes, int n_in,
                              void* d_out, int out_size, void* d_ws, size_t ws_size,
                              hipStream_t stream) {
    const float* qkv = (const float*)d_in[0];
    const void* mask = d_in[1];
    const float* Wqkv = (const float*)d_in[2];
    const float* bqkv = (const float*)d_in[3];
    const float* Wo = (const float*)d_in[4];
    const float* bo = (const float*)d_in[5];
    float* out = (float*)d_out;

    const size_t SZ_X = (size_t)4096 * 1024 * 2;       // 8 MB
    const size_t SZ_W = (size_t)3072 * 1024 * 2;       // 6 MB
    const size_t SZ_WO = (size_t)1024 * 1024 * 2;      // 2 MB
    const size_t SZ_QKV = (size_t)32 * 2048 * 64 * 2;  // 8 MB
    const size_t SZ_ATT = (size_t)4096 * 1024 * 2;     // 8 MB

    char* p = (char*)d_ws;
    u16* Xh = (u16*)p; p += SZ_X;
    u16* Wth = (u16*)p; p += SZ_W;
    u16* Woth = (u16*)p; p += SZ_WO;
    u16* qh = (u16*)p; p += SZ_QKV;
    u16* kh = (u16*)p; p += SZ_QKV;
    u16* vt = (u16*)p; p += SZ_QKV;  // [bh][d][s_packed]
    u16* att = (u16*)p; p += SZ_ATT;
    float* pbias = (float*)p; p += BATCH * SEQ * 4;
    int* pack_idx = (int*)p; p += BATCH * SEQ * 4;
    int* cnt = (int*)p; p += 256;

    prep_all<<<1 + 3072 + 1024 + 1024, 256, 0, stream>>>(
        qkv, (const unsigned char*)mask, Wqkv, Wo, Xh, Wth, Woth, pbias, pack_idx, cnt);
    gemm_qkv<<<dim3(24, 32), 256, 0, stream>>>(Xh, Wth, bqkv, pack_idx, cnt, qh, kh, vt);
    attn_kernel<<<dim3(16, 32), 512, 0, stream>>>(qh, kh, vt, pbias, cnt, att);
    gemm_out<<<dim3(8, 64), 256, 0, stream>>>(att, Woth, bo, out);
}

// Round 21
// 92.819 us; speedup vs baseline: 1.5140x; 1.0468x over previous
//
#include <hip/hip_runtime.h>

#define DEV __device__ __forceinline__

typedef unsigned short u16;
typedef unsigned int u32;
typedef __attribute__((ext_vector_type(4))) float f32x4;
typedef __attribute__((ext_vector_type(8))) short s16x8;
typedef __attribute__((ext_vector_type(8))) _Float16 f16x8;
typedef __attribute__((ext_vector_type(4))) unsigned short u16x4;
typedef __attribute__((ext_vector_type(4))) unsigned int u32x4;

#define BATCH 2
#define SEQ 2048
#define HID 1024
#define NH 16
#define HD 64

// scaling:  X' = 64*X, W' = 64*W -> proj = acc/4096
//  q stored = proj_q * 8*log2e (log2-domain scores direct from MFMA), k stored = proj_k
//  mask bias enters as the QK MFMA C-in (no post-FMA pass)
#define SCALE_XW 64.0f
#define INV_PROJ (1.0f / 4096.0f)
#define SCALE_Q 11.541560327111707f
#define SCALE_K 1.0f
#define DEFER_THR 10.0f

DEV f32x4 mfmah(s16x8 a, s16x8 b, f32x4 c) {
    return __builtin_amdgcn_mfma_f32_16x16x32_f16(
        __builtin_bit_cast(f16x8, a), __builtin_bit_cast(f16x8, b), c, 0, 0, 0);
}

DEV u16 f2h(float x) { return __builtin_bit_cast(u16, (_Float16)x); }
DEV float h2f(u16 h) { return (float)__builtin_bit_cast(_Float16, h); }

DEV u32 pkh(float a, float b) {
#if __has_builtin(__builtin_amdgcn_cvt_pkrtz)
    auto r = __builtin_amdgcn_cvt_pkrtz(a, b);
    return __builtin_bit_cast(u32, r);
#else
    return (u32)f2h(a) | ((u32)f2h(b) << 16);
#endif
}

DEV float fexp2(float x) {
#if __has_builtin(__builtin_amdgcn_exp2f)
    return __builtin_amdgcn_exp2f(x);
#else
    return exp2f(x);
#endif
}

DEV void swap32(int lane, u32 a, u32 b, u32& o0, u32& o1) {
#if __has_builtin(__builtin_amdgcn_permlane32_swap)
    auto r = __builtin_amdgcn_permlane32_swap((int)a, (int)b, false, false);
    o0 = (u32)r[0]; o1 = (u32)r[1];
#else
    u32 ax = (u32)__shfl_xor((int)a, 32);
    u32 bx = (u32)__shfl_xor((int)b, 32);
    bool hi = (lane & 32) != 0;
    o0 = hi ? bx : a;
    o1 = hi ? b : ax;
#endif
}
DEV void swap16(int lane, u32 a, u32 b, u32& o0, u32& o1) {
#if __has_builtin(__builtin_amdgcn_permlane16_swap)
    auto r = __builtin_amdgcn_permlane16_swap((int)a, (int)b, false, false);
    o0 = (u32)r[0]; o1 = (u32)r[1];
#else
    u32 ax = (u32)__shfl_xor((int)a, 16);
    u32 bx = (u32)__shfl_xor((int)b, 16);
    bool hi = (lane & 16) != 0;
    o0 = hi ? bx : a;
    o1 = hi ? b : ax;
#endif
}

DEV void gl_lds16(const void* g, void* l) {
    __builtin_amdgcn_global_load_lds(
        (__attribute__((address_space(1))) void*)(void*)g,
        (__attribute__((address_space(3))) void*)l, 16, 0, 0);
}

// raw barrier pair (rule #18: sched_barrier fences around inline-asm waits)
DEV void vm0_bar() {
    __builtin_amdgcn_sched_barrier(0);
    asm volatile("s_waitcnt vmcnt(0)" ::: "memory");
    __builtin_amdgcn_s_barrier();
    __builtin_amdgcn_sched_barrier(0);
}

// rows of 128B, 16B slots XOR-swizzled by row&7
DEV s16x8 lds_ld16(const u16* base, int row, int kbyte) {
    return *(const s16x8*)((const char*)base + row * 128 + (kbyte ^ ((row & 7) << 4)));
}
// rows of 256B, 16B slots XOR-swizzled by row&7 (V tiles at KVBLK=128)
DEV s16x8 lds_ld16v(const u16* base, int row, int kbyte) {
    return *(const s16x8*)((const char*)base + row * 256 + (kbyte ^ ((row & 7) << 4)));
}

// ------- fused prep: mask scan/compaction + W transposes + X convert -------
__global__ __launch_bounds__(256) void prep_all(
    const float* __restrict__ qkv, const unsigned char* __restrict__ m,
    const float* __restrict__ Wqkv, const float* __restrict__ Wo,
    u16* __restrict__ Xh, u16* __restrict__ Wth, u16* __restrict__ Woth,
    float* __restrict__ pbias, int* __restrict__ pack_idx, int* __restrict__ cnt) {
    int bid = blockIdx.x;
    int tid = threadIdx.x;
    if (bid == 0) {
        __shared__ int sb, sf;
        __shared__ int scan[256];
        if (tid == 0) { sb = 0; sf = 0; }
        __syncthreads();
        int lb = 0, lf = 0;
        for (int i = tid * 16; i < tid * 16 + 16; i++) {
            unsigned char v = m[i];
            int pos = i & 3;
            if (pos == 3 && v == 0x3f) lf = 1;
            if (pos != 0 && v != 0) lb = 1;
        }
        if (lb) atomicOr(&sb, 1);
        if (lf) atomicOr(&sf, 1);
        __syncthreads();
        int f = sf ? 2 : (sb ? 1 : 0);
#pragma unroll
        for (int b = 0; b < BATCH; b++) {
            int base = b * SEQ;
            int keep[8], lc = 0;
#pragma unroll
            for (int e = 0; e < 8; e++) {
                int i = base + tid * 8 + e;
                int mv;
                if (f == 0) mv = ((const int*)m)[i] != 0;
                else if (f == 1) mv = m[i] != 0;
                else mv = ((const float*)m)[i] != 0.0f;
                keep[e] = !mv;
                lc += keep[e];
            }
            scan[tid] = lc;
            __syncthreads();
            for (int s = 1; s < 256; s <<= 1) {
                int v = (tid >= s) ? scan[tid - s] : 0;
                __syncthreads();
                scan[tid] += v;
                __syncthreads();
            }
            int off = scan[tid] - lc;
            int total = scan[255];
            __syncthreads();  // scan reused next batch
#pragma unroll
            for (int e = 0; e < 8; e++)
                if (keep[e]) pack_idx[base + off++] = base + tid * 8 + e;
            if (tid == 0) cnt[b] = total;
            for (int j = tid; j < SEQ; j += 256)
                pbias[base + j] = (j < total) ? 0.0f : -1e30f;
        }
    } else if (bid <= 3072 + 1024) {
        const float* in;
        u16* oh;
        int N, t;
        float scale;
        if (bid <= 3072) { in = Wqkv; oh = Wth; N = 3072; t = bid - 1; scale = SCALE_XW; }
        else { in = Wo; oh = Woth; N = 1024; t = bid - 3073; scale = 1.0f; }
        const int K = 1024;
        int ntiles = N >> 5;
        int n0 = (t % ntiles) * 32, k0 = (t / ntiles) * 32;
        __shared__ float tt[32][33];
        int tx = tid & 31, ty = tid >> 5;
#pragma unroll
        for (int i = 0; i < 4; i++)
            tt[ty + 8 * i][tx] = in[(size_t)(k0 + ty + 8 * i) * N + n0 + tx];
        __syncthreads();
#pragma unroll
        for (int i = 0; i < 4; i++) {
            float v = tt[tx][ty + 8 * i] * scale;
            size_t o = (size_t)(n0 + ty + 8 * i) * K + k0 + tx;
            oh[o] = f2h(v);
        }
    } else {
        int cb = bid - 3073 - 1024;  // 0..1023
#pragma unroll
        for (int it = 0; it < 4; it++) {
            int i = ((cb + it * 1024) * 256 + tid) * 4;
            f32x4 v = *(const f32x4*)&qkv[i];
            u16x4 h;
#pragma unroll
            for (int e = 0; e < 4; e++) h[e] = f2h(v[e] * SCALE_XW);
            *(u16x4*)&Xh[i] = h;
        }
    }
}

// ------- GEMM1: Xh @ Wh fp16 1-PASS, BK=64, single-buf 32KB (R18-proven) -------
__global__ __launch_bounds__(256, 3) void gemm_qkv(
    const u16* __restrict__ Xh,
    const u16* __restrict__ Wth,
    const float* __restrict__ bqkv,
    const int* __restrict__ pack_idx, const int* __restrict__ cnt,
    u16* __restrict__ qh,
    u16* __restrict__ kh,
    u16* __restrict__ vt) {
    __shared__ __align__(16) u16 SM[2][128 * 64];  // 32 KB: [X, W] planes, BK=64
    int tid = threadIdx.x, lane = tid & 63, w = tid >> 6;
    int g = lane >> 4, q15 = lane & 15;
    int wm = w >> 1, wn = w & 1;
    int m0 = blockIdx.y * 128, n0 = blockIdx.x * 128;
    int part = n0 >> 10;
    int bb = m0 >> 11;
    int cb = cnt[bb];
    if (part != 0 && (m0 & 2047) >= cb) return;  // packed rows all beyond count

    int srcrow[4];
#pragma unroll
    for (int i = 0; i < 4; i++) {
        int r = m0 + ((i * 256 + tid) >> 3);
        srcrow[i] = (part == 0) ? r : (((r & 2047) < cb) ? pack_idx[r] : (bb << 11));
    }

    f32x4 acc[4][4];
#pragma unroll
    for (int i = 0; i < 4; i++)
#pragma unroll
        for (int j = 0; j < 4; j++) acc[i][j] = (f32x4){0.f, 0.f, 0.f, 0.f};

    auto STAGE = [&](int kt) {
        int k0 = kt * 64;
#pragma unroll
        for (int i = 0; i < 4; i++) {
            int c = i * 256 + tid;
            int row = c >> 3, slot = c & 7;  // 128 rows x 8 slots (64 k)
            int sg = slot ^ (row & 7);
            int dst = (c & ~63) * 8;
            size_t ga = (size_t)srcrow[i] * 1024 + k0 + sg * 8;
            size_t gb = (size_t)(n0 + row) * 1024 + k0 + sg * 8;
            gl_lds16(&Xh[ga], &SM[0][dst]);
            gl_lds16(&Wth[gb], &SM[1][dst]);
        }
    };

    STAGE(0);
    for (int kt = 0; kt < 16; kt++) {
        vm0_bar();  // stage for kt complete on all waves
        s16x8 a_h[2][4], b_h[2][4];
#pragma unroll
        for (int k2 = 0; k2 < 2; k2++) {
            int kb = k2 * 64 + g * 16;
#pragma unroll
            for (int i = 0; i < 4; i++) {
                a_h[k2][i] = lds_ld16(SM[0], wm * 64 + i * 16 + q15, kb);
                b_h[k2][i] = lds_ld16(SM[1], wn * 64 + i * 16 + q15, kb);
            }
        }
        __syncthreads();  // all waves' reads retired -> buffer reusable
        if (kt < 15) STAGE(kt + 1);
#pragma unroll
        for (int k2 = 0; k2 < 2; k2++)
#pragma unroll
            for (int mi = 0; mi < 4; mi++)
#pragma unroll
                for (int ni = 0; ni < 4; ni++)
                    acc[mi][ni] = mfmah(a_h[k2][mi], b_h[k2][ni], acc[mi][ni]);
    }

    if (part == 2) {
        u16* T = (u16*)SM;
        const int TP = 140;
#pragma unroll
        for (int h2 = 0; h2 < 2; h2++) {
            __syncthreads();
            if (wn == h2) {
#pragma unroll
                for (int mi = 0; mi < 4; mi++)
#pragma unroll
                    for (int ni = 0; ni < 4; ni++) {
                        int lcol = ni * 16 + q15;  // 0..63 within half
#pragma unroll
                        for (int j = 0; j < 4; j++) {
                            int lrow = wm * 64 + mi * 16 + g * 4 + j;
                            T[lcol * TP + lrow] =
                                f2h(acc[mi][ni][j] * INV_PROJ + bqkv[n0 + h2 * 64 + lcol]);
                        }
                    }
            }
            __syncthreads();
            int lcol = tid >> 2;  // 0..63
            int seg = tid & 3;
            int c = n0 - 2048 + h2 * 64 + lcol;
            int h = c >> 6, d = c & 63;
            int b = m0 >> 11, sbase = m0 & 2047;
            size_t rowbase = ((size_t)(b * NH + h) * HD + d) * SEQ + sbase;
#pragma unroll
            for (int k = 0; k < 2; k++) {
                int slot = seg * 2 + k;  // 8 slots x 16 rows = 128
                *(s16x8*)&vt[rowbase + slot * 16 + 0] = *(const s16x8*)&T[lcol * TP + slot * 16 + 0];
                *(s16x8*)&vt[rowbase + slot * 16 + 8] = *(const s16x8*)&T[lcol * TP + slot * 16 + 8];
            }
        }
    } else {
#pragma unroll
        for (int mi = 0; mi < 4; mi++)
#pragma unroll
            for (int ni = 0; ni < 4; ni++) {
                int col = n0 + wn * 64 + ni * 16 + q15;
                float bias = bqkv[col];
                int cc = col & 1023, h = cc >> 6, d = cc & 63;
#pragma unroll
                for (int j = 0; j < 4; j++) {
                    int row = m0 + wm * 64 + mi * 16 + g * 4 + j;
                    int b = row >> 11, s = row & 2047;  // s: packed for K, true for Q
                    float v = acc[mi][ni][j] * INV_PROJ + bias;
                    v *= (part == 0) ? SCALE_Q : SCALE_K;
                    size_t o = (size_t)(b * NH + h) * SEQ * HD + (size_t)s * HD + d;
                    if (part == 0) qh[o] = f2h(v);
                    else kh[o] = f2h(v);
                }
            }
    }
}

// ------ flash attention over PACKED keys: 8 waves x 16 q-rows, KVBLK=128 ------
__global__ __launch_bounds__(512, 2) void attn_kernel(
    const u16* __restrict__ qh,
    const u16* __restrict__ kh,
    const u16* __restrict__ vt, const float* __restrict__ pbias,
    const int* __restrict__ cnt,
    u16* __restrict__ att) {
    __shared__ __align__(16) u16 Kh[2][8192], Vt[2][8192];  // 64 KB
    __shared__ __align__(16) float MskB[2][128];            // 1 KB
    int tid = threadIdx.x, lane = tid & 63, w = tid >> 6;
    int g = lane >> 4, q15 = lane & 15;
    int bid = blockIdx.y * 16 + blockIdx.x;
    int swz = (bid & 7) * 64 + (bid >> 3);  // bijective: 512 % 8 == 0
    int qt = swz & 15, bh = swz >> 4;
    int b = bh >> 4, h = bh & 15;
    int q0 = qt * 128;
    int NT = (cnt[b] + 127) >> 7;  // packed key tiles of 128
    size_t base = (size_t)bh * SEQ * HD;
    const u16* vbase = vt + (size_t)bh * HD * SEQ;
    const float* mrow = pbias + b * SEQ;

    // Q fragment, 16 rows per wave (k-map: k = k2*32 + g*8 + e)
    s16x8 aq[2];
#pragma unroll
    for (int k2 = 0; k2 < 2; k2++) {
        size_t o = base + (size_t)(q0 + w * 16 + q15) * HD + k2 * 32 + g * 8;
        aq[k2] = *(const s16x8*)&qh[o];
    }

    float m_ = -1e30f, l_ = 0.f;  // lane-partial l
    f32x4 o_[4];
#pragma unroll
    for (int df = 0; df < 4; df++) o_[df] = (f32x4){0.f, 0.f, 0.f, 0.f};

    auto STAGE = [&](int buf, int k0) {
#pragma unroll
        for (int i = 0; i < 2; i++) {
            int c = i * 512 + tid;
            // K tile: 128 key-rows x 8 slots (128B rows)
            int row = c >> 3, slot = c & 7;
            int sg = slot ^ (row & 7);
            int dst = (c & ~63) * 8;
            size_t gK = base + (size_t)(k0 + row) * HD + sg * 8;
            gl_lds16(&kh[gK], &Kh[buf][dst]);
            // V tile: 64 d-rows x 16 slots (256B rows)
            int vrow = c >> 4, vslot = c & 15;
            int vsg = vslot ^ (vrow & 7);
            size_t gV = (size_t)vrow * SEQ + k0 + vsg * 8;
            gl_lds16(&vbase[gV], &Vt[buf][dst]);
        }
        if (tid < 32) gl_lds16(&mrow[k0 + tid * 4], &MskB[buf][0]);
    };

    STAGE(0, 0);
    __syncthreads();

    for (int kt = 0; kt < NT; kt++) {
        int cur = kt & 1;
        if (kt < NT - 1) STAGE(cur ^ 1, (kt + 1) * 128);

        // swapped QK^T: D[k][q], k = nf*16 + g*4 + j (nf 0..7 = 128 keys), q = q15.
        f32x4 sc[8];
#pragma unroll
        for (int nf = 0; nf < 8; nf++)
            sc[nf] = *(const f32x4*)&MskB[cur][nf * 16 + g * 4];
#pragma unroll
        for (int nf = 0; nf < 8; nf++)
#pragma unroll
            for (int k2 = 0; k2 < 2; k2++) {
                int kb = k2 * 64 + g * 16;
                s16x8 kbh = lds_ld16(Kh[cur], nf * 16 + q15, kb);
                sc[nf] = mfmah(kbh, aq[k2], sc[nf]);
            }

        // per-lane softmax (row q = q15) with defer-max
        float pml = -1e30f;
#pragma unroll
        for (int nf = 0; nf < 8; nf++) {
            float a = fmaxf(sc[nf][0], sc[nf][1]);
            float bmx = fmaxf(sc[nf][2], sc[nf][3]);
            pml = fmaxf(pml, fmaxf(a, bmx));
        }
        if (!__all(pml - m_ <= DEFER_THR)) {
            float pm = fmaxf(pml, __shfl_xor(pml, 16));
            pm = fmaxf(pm, __shfl_xor(pm, 32));
            float mn = fmaxf(m_, pm);
            float scl = fexp2(m_ - mn);
            m_ = mn;
            l_ *= scl;
#pragma unroll
            for (int j = 0; j < 4; j++) {
                float sb = __shfl(scl, g * 4 + j);
#pragma unroll
                for (int df = 0; df < 4; df++) o_[df][j] *= sb;
            }
        }
        // exp + sum + in-register P repack, fused per nf-pair
        float rs = 0.f;
        s16x8 pa[4];
#pragma unroll
        for (int k2 = 0; k2 < 4; k2++) {
            float p0[4], p1[4];
#pragma unroll
            for (int j = 0; j < 4; j++) {
                p0[j] = fexp2(sc[2 * k2][j] - m_);
                p1[j] = fexp2(sc[2 * k2 + 1][j] - m_);
                rs += p0[j] + p1[j];
            }
            u32 A0 = pkh(p0[0], p0[1]);
            u32 A1 = pkh(p0[2], p0[3]);
            u32 B0 = pkh(p1[0], p1[1]);
            u32 B1 = pkh(p1[2], p1[3]);
            u32 s0, s1, t0, t1, w0, w1, w2, w3;
            swap32(lane, A0, B0, s0, s1);
            swap16(lane, s0, s1, w0, w2);
            swap32(lane, A1, B1, t0, t1);
            swap16(lane, t0, t1, w1, w3);
            u32x4 words = {w0, w1, w2, w3};
            pa[k2] = __builtin_bit_cast(s16x8, words);
        }
        l_ += rs;  // lane-partial

        // PV: O[q][d] += P[q][k] * V^T[d][k], k over 128 keys (4 blocks of 32)
#pragma unroll
        for (int k2 = 0; k2 < 4; k2++) {
            int kb = k2 * 64 + g * 16;
#pragma unroll
            for (int df = 0; df < 4; df++) {
                s16x8 vb = lds_ld16v(Vt[cur], df * 16 + q15, kb);
                o_[df] = mfmah(pa[k2], vb, o_[df]);
            }
        }
        __syncthreads();
    }

    float lt = l_;
    lt += __shfl_xor(lt, 16);
    lt += __shfl_xor(lt, 32);
#pragma unroll
    for (int j = 0; j < 4; j++) {
        float lb = __shfl(lt, g * 4 + j);
        float linv = __builtin_amdgcn_rcpf(lb);
        int qrow = q0 + w * 16 + g * 4 + j;
        size_t srow = (size_t)(b * SEQ + qrow);
#pragma unroll
        for (int df = 0; df < 4; df++) {
            int col = h * HD + df * 16 + q15;
            att[srow * HID + col] = f2h(o_[df][j] * linv);
        }
    }
}

// ------- GEMM2: att fp16 @ Wo fp16 (1 pass), 64x128 tiles, BK=64 single-buf -------
// R20: 16 rounds of 16 MFMA (was 32 of 8) — R18-proven barrier amortization.
// LDS 24 KB single buffer, vm0_bar schedule, 4 blocks/CU.
__global__ __launch_bounds__(256, 4) void gemm_out(
    const u16* __restrict__ A, const u16* __restrict__ Bh0,
    const float* __restrict__ bo, float* __restrict__ out) {
    __shared__ __align__(16) u16 SMa[64 * 64], SMb[128 * 64];  // 8 + 16 KB
    int tid = threadIdx.x, lane = tid & 63, w = tid >> 6;
    int g = lane >> 4, q15 = lane & 15;
    int wm = w >> 1, wn = w & 1;
    int m0 = blockIdx.y * 64, n0 = blockIdx.x * 128;
    f32x4 acc[2][4];
#pragma unroll
    for (int i = 0; i < 2; i++)
#pragma unroll
        for (int j = 0; j < 4; j++) acc[i][j] = (f32x4){0.f, 0.f, 0.f, 0.f};

    auto STAGE = [&](int kt) {
        int k0 = kt * 64;
#pragma unroll
        for (int i = 0; i < 2; i++) {  // A: 64 rows x 8 slots = 512 chunks
            int c = i * 256 + tid;
            int row = c >> 3, slot = c & 7;
            int sg = slot ^ (row & 7);
            int dst = (c & ~63) * 8;
            gl_lds16(&A[(size_t)(m0 + row) * 1024 + k0 + sg * 8], &SMa[dst]);
        }
#pragma unroll
        for (int i = 0; i < 4; i++) {  // B: 128 rows x 8 slots = 1024 chunks
            int c = i * 256 + tid;
            int row = c >> 3, slot = c & 7;
            int sg = slot ^ (row & 7);
            int dst = (c & ~63) * 8;
            gl_lds16(&Bh0[(size_t)(n0 + row) * 1024 + k0 + sg * 8], &SMb[dst]);
        }
    };

    STAGE(0);
    for (int kt = 0; kt < 16; kt++) {
        vm0_bar();  // stage for kt complete on all waves
        s16x8 a_[2][2], b_[2][4];
#pragma unroll
        for (int k2 = 0; k2 < 2; k2++) {
            int kb = k2 * 64 + g * 16;
#pragma unroll
            for (int i = 0; i < 2; i++)
                a_[k2][i] = lds_ld16(SMa, wm * 32 + i * 16 + q15, kb);
#pragma unroll
            for (int i = 0; i < 4; i++)
                b_[k2][i] = lds_ld16(SMb, wn * 64 + i * 16 + q15, kb);
        }
        __syncthreads();  // all waves' reads retired -> buffer reusable
        if (kt < 15) STAGE(kt + 1);
#pragma unroll
        for (int k2 = 0; k2 < 2; k2++)
#pragma unroll
            for (int mi = 0; mi < 2; mi++)
#pragma unroll
                for (int ni = 0; ni < 4; ni++)
                    acc[mi][ni] = mfmah(a_[k2][mi], b_[k2][ni], acc[mi][ni]);
    }
#pragma unroll
    for (int mi = 0; mi < 2; mi++)
#pragma unroll
        for (int ni = 0; ni < 4; ni++) {
            int col = n0 + wn * 64 + ni * 16 + q15;
            float bias = bo[col];
#pragma unroll
            for (int j = 0; j < 4; j++) {
                int row = m0 + wm * 32 + mi * 16 + g * 4 + j;
                out[(size_t)row * 1024 + col] = acc[mi][ni][j] + bias;
            }
        }
}

extern "C" void kernel_launch(void* const* d_in, const int* in_sizes, int n_in,
                              void* d_out, int out_size, void* d_ws, size_t ws_size,
                              hipStream_t stream) {
    const float* qkv = (const float*)d_in[0];
    const void* mask = d_in[1];
    const float* Wqkv = (const float*)d_in[2];
    const float* bqkv = (const float*)d_in[3];
    const float* Wo = (const float*)d_in[4];
    const float* bo = (const float*)d_in[5];
    float* out = (float*)d_out;

    const size_t SZ_X = (size_t)4096 * 1024 * 2;       // 8 MB
    const size_t SZ_W = (size_t)3072 * 1024 * 2;       // 6 MB
    const size_t SZ_WO = (size_t)1024 * 1024 * 2;      // 2 MB
    const size_t SZ_QKV = (size_t)32 * 2048 * 64 * 2;  // 8 MB
    const size_t SZ_ATT = (size_t)4096 * 1024 * 2;     // 8 MB

    char* p = (char*)d_ws;
    u16* Xh = (u16*)p; p += SZ_X;
    u16* Wth = (u16*)p; p += SZ_W;
    u16* Woth = (u16*)p; p += SZ_WO;
    u16* qh = (u16*)p; p += SZ_QKV;
    u16* kh = (u16*)p; p += SZ_QKV;
    u16* vt = (u16*)p; p += SZ_QKV;  // [bh][d][s_packed]
    u16* att = (u16*)p; p += SZ_ATT;
    float* pbias = (float*)p; p += BATCH * SEQ * 4;
    int* pack_idx = (int*)p; p += BATCH * SEQ * 4;
    int* cnt = (int*)p; p += 256;

    prep_all<<<1 + 3072 + 1024 + 1024, 256, 0, stream>>>(
        qkv, (const unsigned char*)mask, Wqkv, Wo, Xh, Wth, Woth, pbias, pack_idx, cnt);
    gemm_qkv<<<dim3(24, 32), 256, 0, stream>>>(Xh, Wth, bqkv, pack_idx, cnt, qh, kh, vt);
    attn_kernel<<<dim3(16, 32), 512, 0, stream>>>(qh, kh, vt, pbias, cnt, att);
    gemm_out<<<dim3(8, 64), 256, 0, stream>>>(att, Woth, bo, out);
}